// Round 2
// baseline (6138.970 us; speedup 1.0000x reference)
//
#include <hip/hip_runtime.h>
#include <cstdint>
#include <cstddef>

typedef __bf16 bf16;
typedef __bf16 bf16x8 __attribute__((ext_vector_type(8)));
typedef __bf16 bf16x4 __attribute__((ext_vector_type(4)));
typedef float f32x4 __attribute__((ext_vector_type(4)));

static constexpr int D = 4096;
static constexpr int S = 4096;
static constexpr int T = 256;
static constexpr int H = 32;
static constexpr int F = 16384;

__device__ __forceinline__ void gload16(const void* g, void* l) {
  __builtin_amdgcn_global_load_lds((const __attribute__((address_space(1))) void*)g,
                                   (__attribute__((address_space(3))) void*)l, 16, 0, 0);
}

// ---------------- elementwise f32 -> bf16 ----------------
__global__ __launch_bounds__(256) void k_cvt(const float* __restrict__ in, bf16* __restrict__ out, int n) {
  int i = (blockIdx.x * 256 + threadIdx.x) * 4;
  if (i >= n) return;
  float4 v = *(const float4*)(in + i);
  bf16x4 o = { (bf16)v.x, (bf16)v.y, (bf16)v.z, (bf16)v.w };
  *(bf16x4*)(out + i) = o;
}

// ---------------- transpose+cvt: f32 [R][C] -> bf16 [C][R] ----------------
__global__ __launch_bounds__(256) void k_tc(const float* __restrict__ in, bf16* __restrict__ out, int R, int C) {
  __shared__ float tile[32][33];
  int c0 = blockIdx.x * 32, r0 = blockIdx.y * 32;
  int x = threadIdx.x, y = threadIdx.y;
  #pragma unroll
  for (int yy = y; yy < 32; yy += 8)
    tile[yy][x] = in[(size_t)(r0 + yy) * C + c0 + x];
  __syncthreads();
  #pragma unroll
  for (int yy = y; yy < 32; yy += 8)
    out[(size_t)(c0 + yy) * R + r0 + x] = (bf16)tile[x][yy];
}

// ---------------- transpose bf16 [R][C] -> [C][R] ----------------
__global__ __launch_bounds__(256) void k_tb(const bf16* __restrict__ in, bf16* __restrict__ out, int R, int C) {
  __shared__ bf16 tile[32][33];
  int c0 = blockIdx.x * 32, r0 = blockIdx.y * 32;
  int x = threadIdx.x, y = threadIdx.y;
  #pragma unroll
  for (int yy = y; yy < 32; yy += 8)
    tile[yy][x] = in[(size_t)(r0 + yy) * C + c0 + x];
  __syncthreads();
  #pragma unroll
  for (int yy = y; yy < 32; yy += 8)
    out[(size_t)(c0 + yy) * R + r0 + x] = tile[x][yy];
}

// ---------------- rmsnorm over 4096, f32 in -> bf16 out ----------------
__global__ __launch_bounds__(256) void k_rms(const float* __restrict__ in, const float* __restrict__ w,
                                             bf16* __restrict__ out) {
  const int row = blockIdx.x, t = threadIdx.x;
  const float* x = in + (size_t)row * 4096;
  float4 v[4];
  float ss = 0.f;
  #pragma unroll
  for (int i = 0; i < 4; i++) {
    v[i] = *(const float4*)(x + t * 4 + i * 1024);
    ss += v[i].x * v[i].x + v[i].y * v[i].y + v[i].z * v[i].z + v[i].w * v[i].w;
  }
  #pragma unroll
  for (int off = 1; off < 64; off <<= 1) ss += __shfl_xor(ss, off, 64);
  __shared__ float red[4];
  if ((t & 63) == 0) red[t >> 6] = ss;
  __syncthreads();
  float rms = rsqrtf((red[0] + red[1] + red[2] + red[3]) * (1.f / 4096.f) + 1e-6f);
  #pragma unroll
  for (int i = 0; i < 4; i++) {
    const float4 wv = *(const float4*)(w + t * 4 + i * 1024);
    bf16x4 ov = { (bf16)(v[i].x * rms * wv.x), (bf16)(v[i].y * rms * wv.y),
                  (bf16)(v[i].z * rms * wv.z), (bf16)(v[i].w * rms * wv.w) };
    *(bf16x4*)(out + (size_t)row * 4096 + t * 4 + i * 1024) = ov;
  }
}

// ---------------- GEMM: C[M,N] = A[M,K](bf16) @ BT[N,K](bf16) ----------------
// MODE 0: f32 out; 1: bf16 out; 2: f32 out + residual add
template <int MODE>
__global__ __launch_bounds__(256) void k_gemm(const bf16* __restrict__ A, const bf16* __restrict__ BT,
                                              float* __restrict__ Cf, bf16* __restrict__ Cb,
                                              const float* __restrict__ res,
                                              int M, int N, int K) {
  __shared__ bf16 As[128 * 32];
  __shared__ bf16 Bs[128 * 32];
  const int t = threadIdx.x;
  const int lane = t & 63, w = t >> 6;
  const int wr = w >> 1, wc = w & 1;
  const int g = lane >> 4, r15 = lane & 15;
  const size_t m0 = (size_t)blockIdx.y * 128, n0 = (size_t)blockIdx.x * 128;
  f32x4 acc[4][4] = {};
  const int c0 = t, c1 = t + 256;
  const int ar0 = c0 >> 2, as0 = c0 & 3, ar1 = c1 >> 2, as1 = c1 & 3;
  const bf16* Ab = A + m0 * K;
  const bf16* Bb = BT + n0 * K;
  for (int k0 = 0; k0 < K; k0 += 32) {
    __syncthreads();
    gload16(Ab + (size_t)ar0 * K + k0 + ((as0 ^ (ar0 & 3)) << 3), &As[c0 * 8]);
    gload16(Ab + (size_t)ar1 * K + k0 + ((as1 ^ (ar1 & 3)) << 3), &As[c1 * 8]);
    gload16(Bb + (size_t)ar0 * K + k0 + ((as0 ^ (ar0 & 3)) << 3), &Bs[c0 * 8]);
    gload16(Bb + (size_t)ar1 * K + k0 + ((as1 ^ (ar1 & 3)) << 3), &Bs[c1 * 8]);
    __syncthreads();
    bf16x8 af[4], bfr[4];
    #pragma unroll
    for (int mi = 0; mi < 4; mi++) {
      int row = wr * 64 + mi * 16 + r15;
      af[mi] = *(const bf16x8*)&As[row * 32 + ((g ^ (row & 3)) << 3)];
    }
    #pragma unroll
    for (int ni = 0; ni < 4; ni++) {
      int row = wc * 64 + ni * 16 + r15;
      bfr[ni] = *(const bf16x8*)&Bs[row * 32 + ((g ^ (row & 3)) << 3)];
    }
    #pragma unroll
    for (int mi = 0; mi < 4; mi++)
      #pragma unroll
      for (int ni = 0; ni < 4; ni++)
        acc[mi][ni] = __builtin_amdgcn_mfma_f32_16x16x32_bf16(af[mi], bfr[ni], acc[mi][ni], 0, 0, 0);
  }
  #pragma unroll
  for (int mi = 0; mi < 4; mi++)
    #pragma unroll
    for (int ni = 0; ni < 4; ni++) {
      size_t col = n0 + wc * 64 + ni * 16 + r15;
      #pragma unroll
      for (int rr = 0; rr < 4; rr++) {
        size_t row = m0 + wr * 64 + mi * 16 + g * 4 + rr;
        size_t idx = row * (size_t)N + col;
        float v = acc[mi][ni][rr];
        if (MODE == 0) Cf[idx] = v;
        else if (MODE == 1) Cb[idx] = (bf16)v;
        else Cf[idx] = v + res[idx];
      }
    }
}

// ---------------- GEGLU GEMM: G[M,N] = (A@BTv) * gelu_tanh(A@BTg), BT=[2N][K] ----------------
__global__ __launch_bounds__(256) void k_geglu_gemm(const bf16* __restrict__ A, const bf16* __restrict__ BT,
                                                    bf16* __restrict__ G, int M, int N, int K) {
  __shared__ bf16 As[128 * 32];
  __shared__ bf16 Bv[128 * 32];
  __shared__ bf16 Bg[128 * 32];
  const int t = threadIdx.x;
  const int lane = t & 63, w = t >> 6;
  const int wr = w >> 1, wc = w & 1;
  const int g = lane >> 4, r15 = lane & 15;
  const size_t m0 = (size_t)blockIdx.y * 128, n0 = (size_t)blockIdx.x * 128;
  f32x4 av[4][4] = {}, ag[4][4] = {};
  const int c0 = t, c1 = t + 256;
  const int ar0 = c0 >> 2, as0 = c0 & 3, ar1 = c1 >> 2, as1 = c1 & 3;
  const bf16* Ab = A + m0 * K;
  const bf16* Bvb = BT + n0 * K;
  const bf16* Bgb = BT + ((size_t)N + n0) * K;
  for (int k0 = 0; k0 < K; k0 += 32) {
    __syncthreads();
    gload16(Ab  + (size_t)ar0 * K + k0 + ((as0 ^ (ar0 & 3)) << 3), &As[c0 * 8]);
    gload16(Ab  + (size_t)ar1 * K + k0 + ((as1 ^ (ar1 & 3)) << 3), &As[c1 * 8]);
    gload16(Bvb + (size_t)ar0 * K + k0 + ((as0 ^ (ar0 & 3)) << 3), &Bv[c0 * 8]);
    gload16(Bvb + (size_t)ar1 * K + k0 + ((as1 ^ (ar1 & 3)) << 3), &Bv[c1 * 8]);
    gload16(Bgb + (size_t)ar0 * K + k0 + ((as0 ^ (ar0 & 3)) << 3), &Bg[c0 * 8]);
    gload16(Bgb + (size_t)ar1 * K + k0 + ((as1 ^ (ar1 & 3)) << 3), &Bg[c1 * 8]);
    __syncthreads();
    bf16x8 af[4];
    #pragma unroll
    for (int mi = 0; mi < 4; mi++) {
      int row = wr * 64 + mi * 16 + r15;
      af[mi] = *(const bf16x8*)&As[row * 32 + ((g ^ (row & 3)) << 3)];
    }
    #pragma unroll
    for (int ni = 0; ni < 4; ni++) {
      int row = wc * 64 + ni * 16 + r15;
      bf16x8 bv = *(const bf16x8*)&Bv[row * 32 + ((g ^ (row & 3)) << 3)];
      bf16x8 bg = *(const bf16x8*)&Bg[row * 32 + ((g ^ (row & 3)) << 3)];
      #pragma unroll
      for (int mi = 0; mi < 4; mi++) {
        av[mi][ni] = __builtin_amdgcn_mfma_f32_16x16x32_bf16(af[mi], bv, av[mi][ni], 0, 0, 0);
        ag[mi][ni] = __builtin_amdgcn_mfma_f32_16x16x32_bf16(af[mi], bg, ag[mi][ni], 0, 0, 0);
      }
    }
  }
  #pragma unroll
  for (int mi = 0; mi < 4; mi++)
    #pragma unroll
    for (int ni = 0; ni < 4; ni++) {
      size_t col = n0 + wc * 64 + ni * 16 + r15;
      #pragma unroll
      for (int rr = 0; rr < 4; rr++) {
        size_t row = m0 + wr * 64 + mi * 16 + g * 4 + rr;
        float val = av[mi][ni][rr], gt = ag[mi][ni][rr];
        float z = 1.595769122f * gt + 0.0713548162f * gt * gt * gt;  // 2*0.79788456*(x+0.044715x^3)
        float gel = gt / (1.f + __expf(-z));                         // x*sigmoid(2t) == x*0.5*(1+tanh(t))
        G[row * (size_t)N + col] = (bf16)(val * gel);
      }
    }
}

// ---------------- flash attention: Q[S,D] x K[Skv,D] x VT[D,Skv] -> O[S,D] ----------------
// grid: (S/64, H); 4 waves x 16 q-rows. Online softmax, 32-key tiles staged to LDS.
__global__ __launch_bounds__(256) void k_attn(const bf16* __restrict__ Q, const bf16* __restrict__ Kb,
                                              const bf16* __restrict__ VT, bf16* __restrict__ O,
                                              int Skv) {
  __shared__ bf16 Kt[32 * 128];   // [key][d], slot-swizzled (16 slots/row)
  __shared__ bf16 Vt[128 * 32];   // [d][key], slot-swizzled (4 slots/row)
  __shared__ bf16 Pt[4][16 * 32]; // per-wave P tile, swizzled
  const int h = blockIdx.y;
  const int t = threadIdx.x, w = t >> 6, lane = t & 63;
  const int g = lane >> 4, r15 = lane & 15;
  const int q0 = blockIdx.x * 64 + w * 16;
  bf16x8 qf[4];
  #pragma unroll
  for (int c = 0; c < 4; c++)
    qf[c] = *(const bf16x8*)(Q + (size_t)(q0 + r15) * D + h * 128 + c * 32 + g * 8);
  f32x4 o[8] = {};
  float m_[4] = { -1e30f, -1e30f, -1e30f, -1e30f };
  float l_[4] = { 0.f, 0.f, 0.f, 0.f };
  const float scale = 0.08838834764831845f;  // 1/sqrt(128)
  for (int kt = 0; kt < Skv; kt += 32) {
    __syncthreads();
    #pragma unroll
    for (int cc = 0; cc < 2; cc++) {
      int c = t + cc * 256;
      int kr = c >> 4, ks = c & 15;
      gload16(Kb + (size_t)(kt + kr) * D + h * 128 + ((ks ^ (kr & 15)) << 3), &Kt[c * 8]);
      int vr = c >> 2, vs = c & 3;
      gload16(VT + (size_t)(h * 128 + vr) * Skv + kt + ((vs ^ (vr & 3)) << 3), &Vt[c * 8]);
    }
    __syncthreads();
    f32x4 s0 = {}, s1 = {};
    #pragma unroll
    for (int c = 0; c < 4; c++) {
      int row0 = r15, row1 = 16 + r15;
      bf16x8 kf0 = *(const bf16x8*)&Kt[row0 * 128 + (((4 * c + g) ^ (row0 & 15)) << 3)];
      bf16x8 kf1 = *(const bf16x8*)&Kt[row1 * 128 + (((4 * c + g) ^ (row1 & 15)) << 3)];
      s0 = __builtin_amdgcn_mfma_f32_16x16x32_bf16(qf[c], kf0, s0, 0, 0, 0);
      s1 = __builtin_amdgcn_mfma_f32_16x16x32_bf16(qf[c], kf1, s1, 0, 0, 0);
    }
    float al[4];
    #pragma unroll
    for (int rr = 0; rr < 4; rr++) {
      float v0 = s0[rr] * scale, v1 = s1[rr] * scale;
      float mx = fmaxf(v0, v1);
      #pragma unroll
      for (int off = 1; off < 16; off <<= 1) mx = fmaxf(mx, __shfl_xor(mx, off, 16));
      float mn = fmaxf(m_[rr], mx);
      al[rr] = __expf(m_[rr] - mn);
      float p0 = __expf(v0 - mn), p1 = __expf(v1 - mn);
      float sm = p0 + p1;
      #pragma unroll
      for (int off = 1; off < 16; off <<= 1) sm += __shfl_xor(sm, off, 16);
      l_[rr] = l_[rr] * al[rr] + sm;
      m_[rr] = mn;
      int prow = g * 4 + rr;
      int sl0 = r15 >> 3, sl1 = 2 + (r15 >> 3);
      Pt[w][prow * 32 + ((sl0 ^ (prow & 3)) << 3) + (r15 & 7)] = (bf16)p0;
      Pt[w][prow * 32 + ((sl1 ^ (prow & 3)) << 3) + (r15 & 7)] = (bf16)p1;
    }
    #pragma unroll
    for (int d = 0; d < 8; d++)
      #pragma unroll
      for (int rr = 0; rr < 4; rr++) o[d][rr] *= al[rr];
    bf16x8 pa = *(const bf16x8*)&Pt[w][r15 * 32 + ((g ^ (r15 & 3)) << 3)];
    #pragma unroll
    for (int d = 0; d < 8; d++) {
      int vrow = d * 16 + r15;
      bf16x8 vbf = *(const bf16x8*)&Vt[vrow * 32 + ((g ^ (vrow & 3)) << 3)];
      o[d] = __builtin_amdgcn_mfma_f32_16x16x32_bf16(pa, vbf, o[d], 0, 0, 0);
    }
  }
  #pragma unroll
  for (int rr = 0; rr < 4; rr++) {
    float inv = 1.f / l_[rr];
    #pragma unroll
    for (int d = 0; d < 8; d++)
      O[(size_t)(q0 + g * 4 + rr) * D + h * 128 + d * 16 + r15] = (bf16)(o[d][rr] * inv);
  }
}

extern "C" void kernel_launch(void* const* d_in, const int* in_sizes, int n_in,
                              void* d_out, int out_size, void* d_ws, size_t ws_size,
                              hipStream_t stream) {
  (void)in_sizes; (void)n_in; (void)out_size; (void)ws_size;
  const float* video = (const float*)d_in[0];
  const float* text  = (const float*)d_in[1];
  const float* wq    = (const float*)d_in[2];
  const float* wk    = (const float*)d_in[3];
  const float* wv    = (const float*)d_in[4];
  const float* wo    = (const float*)d_in[5];
  const float* qnw   = (const float*)d_in[6];
  const float* knw   = (const float*)d_in[7];
  const float* cwq   = (const float*)d_in[8];
  const float* cwk   = (const float*)d_in[9];
  const float* cwv   = (const float*)d_in[10];
  const float* cwo   = (const float*)d_in[11];
  const float* cqnw  = (const float*)d_in[12];
  const float* cknw  = (const float*)d_in[13];
  const float* ffp   = (const float*)d_in[14];
  const float* ffd   = (const float*)d_in[15];
  float* out = (float*)d_out;

  // ---- workspace layout (lifetime-aliased; ~602MB total) ----
  // slab[0 .. 268MB): transposed weights. DxD weights use only first 32MB;
  //   ffp uses all 268MB (by then vb/vt/pre are dead); ffd uses first 134MB.
  // vb  at slab+64MB  (32MB bf16)   — dead before ffp load
  // vt  at slab+96MB  (32MB bf16)   — dead before ffp load
  // pre at slab+128MB (64MB f32)    — dead before ffp load
  // gbuf at slab+268MB (134MB bf16) — coexists only with ffd
  char* slab = (char*)d_ws;
  const size_t MB = 1024 * 1024;
  bf16*  wbuf = (bf16*)slab;
  bf16*  vb   = (bf16*)(slab + 64 * MB);
  bf16*  vt   = (bf16*)(slab + 96 * MB);
  float* pre  = (float*)(slab + 128 * MB);
  bf16*  gbuf = (bf16*)(slab + 268 * MB);
  char* p = slab + 402 * MB;
  auto take = [&](size_t bytes) { char* r = p; p += (bytes + 255) & ~(size_t)255; return r; };
  bf16* xb   = (bf16*)take((size_t)S * D * 2);
  bf16* qb   = (bf16*)take((size_t)S * D * 2);
  bf16* kb   = (bf16*)take((size_t)S * D * 2);
  bf16* ab   = (bf16*)take((size_t)S * D * 2);
  float* h1  = (float*)take((size_t)S * D * 4);
  bf16* tbuf = (bf16*)take((size_t)T * D * 2);
  bf16* ckb  = (bf16*)take((size_t)T * D * 2);
  bf16* cvb  = (bf16*)take((size_t)T * D * 2);
  bf16* cvt_ = (bf16*)take((size_t)T * D * 2);
  float* h2  = out;  // d_out doubles as the second residual buffer

  dim3 b256(256), btc(32, 8);

  // ---- self-attention ----
  k_cvt<<<(S * D) / 1024, b256, 0, stream>>>(video, xb, S * D);
  k_tc<<<dim3(D / 32, D / 32), btc, 0, stream>>>(wq, wbuf, D, D);
  k_gemm<0><<<dim3(D / 128, S / 128), b256, 0, stream>>>(xb, wbuf, pre, nullptr, nullptr, S, D, D);
  k_rms<<<S, b256, 0, stream>>>(pre, qnw, qb);
  k_tc<<<dim3(D / 32, D / 32), btc, 0, stream>>>(wk, wbuf, D, D);
  k_gemm<0><<<dim3(D / 128, S / 128), b256, 0, stream>>>(xb, wbuf, pre, nullptr, nullptr, S, D, D);
  k_rms<<<S, b256, 0, stream>>>(pre, knw, kb);
  k_tc<<<dim3(D / 32, D / 32), btc, 0, stream>>>(wv, wbuf, D, D);
  k_gemm<1><<<dim3(D / 128, S / 128), b256, 0, stream>>>(xb, wbuf, nullptr, vb, nullptr, S, D, D);
  k_tb<<<dim3(D / 32, S / 32), btc, 0, stream>>>(vb, vt, S, D);
  k_attn<<<dim3(S / 64, H), b256, 0, stream>>>(qb, kb, vt, ab, S);
  k_tc<<<dim3(D / 32, D / 32), btc, 0, stream>>>(wo, wbuf, D, D);
  k_gemm<2><<<dim3(D / 128, S / 128), b256, 0, stream>>>(ab, wbuf, h1, nullptr, video, S, D, D);

  // ---- cross-attention ----
  k_cvt<<<(S * D) / 1024, b256, 0, stream>>>(h1, xb, S * D);
  k_tc<<<dim3(D / 32, D / 32), btc, 0, stream>>>(cwq, wbuf, D, D);
  k_gemm<0><<<dim3(D / 128, S / 128), b256, 0, stream>>>(xb, wbuf, pre, nullptr, nullptr, S, D, D);
  k_rms<<<S, b256, 0, stream>>>(pre, cqnw, qb);
  k_cvt<<<(T * D) / 1024, b256, 0, stream>>>(text, tbuf, T * D);
  k_tc<<<dim3(D / 32, D / 32), btc, 0, stream>>>(cwk, wbuf, D, D);
  k_gemm<0><<<dim3(D / 128, T / 128), b256, 0, stream>>>(tbuf, wbuf, pre, nullptr, nullptr, T, D, D);
  k_rms<<<T, b256, 0, stream>>>(pre, cknw, ckb);
  k_tc<<<dim3(D / 32, D / 32), btc, 0, stream>>>(cwv, wbuf, D, D);
  k_gemm<1><<<dim3(D / 128, T / 128), b256, 0, stream>>>(tbuf, wbuf, nullptr, cvb, nullptr, T, D, D);
  k_tb<<<dim3(D / 32, T / 32), btc, 0, stream>>>(cvb, cvt_, T, D);
  k_attn<<<dim3(S / 64, H), b256, 0, stream>>>(qb, ckb, cvt_, ab, T);
  k_tc<<<dim3(D / 32, D / 32), btc, 0, stream>>>(cwo, wbuf, D, D);
  k_gemm<2><<<dim3(D / 128, S / 128), b256, 0, stream>>>(ab, wbuf, h2, nullptr, h1, S, D, D);

  // ---- GEGLU FFN ----
  k_cvt<<<(S * D) / 1024, b256, 0, stream>>>(h2, xb, S * D);
  k_tc<<<dim3((2 * F) / 32, D / 32), btc, 0, stream>>>(ffp, wbuf, D, 2 * F);
  k_geglu_gemm<<<dim3(F / 128, S / 128), b256, 0, stream>>>(xb, wbuf, gbuf, S, F, D);
  k_tc<<<dim3(D / 32, F / 32), btc, 0, stream>>>(ffd, wbuf, F, D);
  k_gemm<2><<<dim3(D / 128, S / 128), b256, 0, stream>>>(gbuf, wbuf, out, nullptr, h2, S, D, F);
}

// Round 3
// 5905.862 us; speedup vs baseline: 1.0395x; 1.0395x over previous
//
#include <hip/hip_runtime.h>
#include <cstdint>
#include <cstddef>

typedef __bf16 bf16;
typedef __bf16 bf16x8 __attribute__((ext_vector_type(8)));
typedef __bf16 bf16x4 __attribute__((ext_vector_type(4)));
typedef float f32x4 __attribute__((ext_vector_type(4)));

static constexpr int D = 4096;
static constexpr int S = 4096;
static constexpr int T = 256;
static constexpr int H = 32;
static constexpr int F = 16384;

__device__ __forceinline__ void gload16(const void* g, void* l) {
  __builtin_amdgcn_global_load_lds((const __attribute__((address_space(1))) void*)g,
                                   (__attribute__((address_space(3))) void*)l, 16, 0, 0);
}

// ---------------- elementwise f32 -> bf16 ----------------
__global__ __launch_bounds__(256) void k_cvt(const float* __restrict__ in, bf16* __restrict__ out, int n) {
  int i = (blockIdx.x * 256 + threadIdx.x) * 4;
  if (i >= n) return;
  float4 v = *(const float4*)(in + i);
  bf16x4 o = { (bf16)v.x, (bf16)v.y, (bf16)v.z, (bf16)v.w };
  *(bf16x4*)(out + i) = o;
}

// ---------------- transpose+cvt: f32 [R][C] (row stride ldin) -> bf16 [C][R] ----------------
__global__ __launch_bounds__(256) void k_tc(const float* __restrict__ in, bf16* __restrict__ out,
                                            int R, int C, int ldin) {
  __shared__ float tile[32][33];
  int c0 = blockIdx.x * 32, r0 = blockIdx.y * 32;
  int x = threadIdx.x, y = threadIdx.y;
  #pragma unroll
  for (int yy = y; yy < 32; yy += 8)
    tile[yy][x] = in[(size_t)(r0 + yy) * ldin + c0 + x];
  __syncthreads();
  #pragma unroll
  for (int yy = y; yy < 32; yy += 8)
    out[(size_t)(c0 + yy) * R + r0 + x] = (bf16)tile[x][yy];
}

// ---------------- transpose bf16 [R][C] -> [C][R] ----------------
__global__ __launch_bounds__(256) void k_tb(const bf16* __restrict__ in, bf16* __restrict__ out, int R, int C) {
  __shared__ bf16 tile[32][33];
  int c0 = blockIdx.x * 32, r0 = blockIdx.y * 32;
  int x = threadIdx.x, y = threadIdx.y;
  #pragma unroll
  for (int yy = y; yy < 32; yy += 8)
    tile[yy][x] = in[(size_t)(r0 + yy) * C + c0 + x];
  __syncthreads();
  #pragma unroll
  for (int yy = y; yy < 32; yy += 8)
    out[(size_t)(c0 + yy) * R + r0 + x] = tile[x][yy];
}

// ---------------- rmsnorm over 4096, f32 in -> bf16 out ----------------
__global__ __launch_bounds__(256) void k_rms(const float* __restrict__ in, const float* __restrict__ w,
                                             bf16* __restrict__ out) {
  const int row = blockIdx.x, t = threadIdx.x;
  const float* x = in + (size_t)row * 4096;
  float4 v[4];
  float ss = 0.f;
  #pragma unroll
  for (int i = 0; i < 4; i++) {
    v[i] = *(const float4*)(x + t * 4 + i * 1024);
    ss += v[i].x * v[i].x + v[i].y * v[i].y + v[i].z * v[i].z + v[i].w * v[i].w;
  }
  #pragma unroll
  for (int off = 1; off < 64; off <<= 1) ss += __shfl_xor(ss, off, 64);
  __shared__ float red[4];
  if ((t & 63) == 0) red[t >> 6] = ss;
  __syncthreads();
  float rms = rsqrtf((red[0] + red[1] + red[2] + red[3]) * (1.f / 4096.f) + 1e-6f);
  #pragma unroll
  for (int i = 0; i < 4; i++) {
    const float4 wv = *(const float4*)(w + t * 4 + i * 1024);
    bf16x4 ov = { (bf16)(v[i].x * rms * wv.x), (bf16)(v[i].y * rms * wv.y),
                  (bf16)(v[i].z * rms * wv.z), (bf16)(v[i].w * rms * wv.w) };
    *(bf16x4*)(out + (size_t)row * 4096 + t * 4 + i * 1024) = ov;
  }
}

// ================= 256x256 8-phase GEMM: C[M,N] = A[M,K] @ BT[N,K] =================
// 8 waves (2Mx4N), BK=64, double-buffered LDS, seg^(row&7) XOR swizzle, counted-drain
// (one vmcnt(0) per K-tile; prefetch loads stay in flight across phase barriers).
// MODE 0: f32 out; 1: bf16 out; 2: f32 out + f32 residual; 3: bf16 out = mul * gelu(acc)
template <int MODE>
__global__ __launch_bounds__(512, 2) void k_gemm2(const bf16* __restrict__ A, const bf16* __restrict__ BT,
                                                  float* __restrict__ Cf, bf16* __restrict__ Cb,
                                                  const float* __restrict__ res, const bf16* __restrict__ mul,
                                                  int M, int N, int K, int gx) {
  __shared__ bf16 LA[2][2][128 * 64];
  __shared__ bf16 LB[2][2][128 * 64];
  // bijective XCD swizzle (m204) on linear block id
  const int nwg = gridDim.x;
  const int orig = blockIdx.x;
  const int q8 = nwg >> 3, r8 = nwg & 7;
  const int xcd = orig & 7, oidx = orig >> 3;
  const int swz = (xcd < r8 ? xcd * (q8 + 1) : r8 * (q8 + 1) + (xcd - r8) * q8) + oidx;
  const int bx = swz % gx, by = swz / gx;
  const size_t m0 = (size_t)by * 256, n0 = (size_t)bx * 256;
  const int t = threadIdx.x;
  const int w = t >> 6, lane = t & 63;
  const int wm = w >> 2, wn = w & 3;
  const int g = lane >> 4, r15 = lane & 15;
  // staging: thread covers segments s0=t and s1=t+512 of each 128x64 half-tile
  const int s0 = t, s1 = t + 512;
  const int srow0 = s0 >> 3, srow1 = s1 >> 3;
  const int c0 = (((s0 & 7) ^ (srow0 & 7)) << 3);  // pre-swizzled global col (rule 21)
  const int c1 = (((s1 & 7) ^ (srow1 & 7)) << 3);
  f32x4 acc[8][4] = {};
  const int nt = K >> 6;

  auto stageA = [&](int d, int h, int kt) {
    const bf16* src = A + (m0 + (size_t)h * 128) * K + (size_t)kt * 64;
    gload16(src + (size_t)srow0 * K + c0, &LA[d][h][s0 * 8]);
    gload16(src + (size_t)srow1 * K + c1, &LA[d][h][s1 * 8]);
  };
  auto stageB = [&](int d, int h, int kt) {
    const bf16* src = BT + (n0 + (size_t)h * 128) * K + (size_t)kt * 64;
    gload16(src + (size_t)srow0 * K + c0, &LB[d][h][s0 * 8]);
    gload16(src + (size_t)srow1 * K + c1, &LB[d][h][s1 * 8]);
  };

  // prologue: tile 0 -> buf 0
  stageA(0, 0, 0); stageA(0, 1, 0); stageB(0, 0, 0); stageB(0, 1, 0);

  for (int tt = 0; tt < nt; ++tt) {
    const int d = tt & 1;
    asm volatile("s_waitcnt vmcnt(0)" ::: "memory");  // tile tt's 8 loads landed
    __builtin_amdgcn_s_barrier();
    #pragma unroll
    for (int ph = 0; ph < 4; ++ph) {
      if (tt + 1 < nt) {  // stage one half of tile tt+1 into buf d^1
        if (ph == 0) stageA(d ^ 1, 0, tt + 1);
        else if (ph == 1) stageA(d ^ 1, 1, tt + 1);
        else if (ph == 2) stageB(d ^ 1, 0, tt + 1);
        else stageB(d ^ 1, 1, tt + 1);
      }
      const int qm = ph >> 1, qn = ph & 1;
      bf16x8 af[4][2], bfp[2][2];
      #pragma unroll
      for (int i = 0; i < 4; ++i) {
        const int arow = (qm * 4 + i) * 16 + r15;
        #pragma unroll
        for (int ks = 0; ks < 2; ++ks)
          af[i][ks] = *(const bf16x8*)&LA[d][wm][arow * 64 + ((((ks * 4 + g)) ^ (arow & 7)) << 3)];
      }
      #pragma unroll
      for (int j = 0; j < 2; ++j) {
        const int bcol = wn * 64 + (qn * 2 + j) * 16 + r15;  // within 256
        const int bh = bcol >> 7, brow = bcol & 127;
        #pragma unroll
        for (int ks = 0; ks < 2; ++ks)
          bfp[j][ks] = *(const bf16x8*)&LB[d][bh][brow * 64 + ((((ks * 4 + g)) ^ (brow & 7)) << 3)];
      }
      __builtin_amdgcn_s_setprio(1);
      #pragma unroll
      for (int i = 0; i < 4; ++i)
        #pragma unroll
        for (int j = 0; j < 2; ++j) {
          acc[qm * 4 + i][qn * 2 + j] =
              __builtin_amdgcn_mfma_f32_16x16x32_bf16(af[i][0], bfp[j][0], acc[qm * 4 + i][qn * 2 + j], 0, 0, 0);
          acc[qm * 4 + i][qn * 2 + j] =
              __builtin_amdgcn_mfma_f32_16x16x32_bf16(af[i][1], bfp[j][1], acc[qm * 4 + i][qn * 2 + j], 0, 0, 0);
        }
      __builtin_amdgcn_s_setprio(0);
      __builtin_amdgcn_s_barrier();
    }
  }

  // epilogue
  #pragma unroll
  for (int mf = 0; mf < 8; ++mf)
    #pragma unroll
    for (int nf = 0; nf < 4; ++nf) {
      const size_t col = n0 + wn * 64 + nf * 16 + r15;
      #pragma unroll
      for (int rr = 0; rr < 4; ++rr) {
        const size_t row = m0 + wm * 128 + mf * 16 + g * 4 + rr;
        const size_t idx = row * (size_t)N + col;
        const float v = acc[mf][nf][rr];
        if (MODE == 0) Cf[idx] = v;
        else if (MODE == 1) Cb[idx] = (bf16)v;
        else if (MODE == 2) Cf[idx] = v + res[idx];
        else {
          const float z = 1.595769122f * v + 0.0713548162f * v * v * v;
          const float gel = v / (1.f + __expf(-z));
          Cb[idx] = (bf16)((float)mul[idx] * gel);
        }
      }
    }
}

// ---------------- 128x128 GEMM (m97 structure) for M=256 cases ----------------
// MODE 0: f32 out; 1: bf16 out
template <int MODE>
__global__ __launch_bounds__(256) void k_gemm128(const bf16* __restrict__ A, const bf16* __restrict__ BT,
                                                 float* __restrict__ Cf, bf16* __restrict__ Cb,
                                                 int M, int N, int K) {
  __shared__ bf16 As[128 * 32];
  __shared__ bf16 Bs[128 * 32];
  const int t = threadIdx.x;
  const int lane = t & 63, w = t >> 6;
  const int wr = w >> 1, wc = w & 1;
  const int g = lane >> 4, r15 = lane & 15;
  const size_t m0 = (size_t)blockIdx.y * 128, n0 = (size_t)blockIdx.x * 128;
  f32x4 acc[4][4] = {};
  const int c0 = t, c1 = t + 256;
  const int ar0 = c0 >> 2, as0 = c0 & 3, ar1 = c1 >> 2, as1 = c1 & 3;
  const bf16* Ab = A + m0 * K;
  const bf16* Bb = BT + n0 * K;
  for (int k0 = 0; k0 < K; k0 += 32) {
    __syncthreads();
    gload16(Ab + (size_t)ar0 * K + k0 + ((as0 ^ (ar0 & 3)) << 3), &As[c0 * 8]);
    gload16(Ab + (size_t)ar1 * K + k0 + ((as1 ^ (ar1 & 3)) << 3), &As[c1 * 8]);
    gload16(Bb + (size_t)ar0 * K + k0 + ((as0 ^ (ar0 & 3)) << 3), &Bs[c0 * 8]);
    gload16(Bb + (size_t)ar1 * K + k0 + ((as1 ^ (ar1 & 3)) << 3), &Bs[c1 * 8]);
    __syncthreads();
    bf16x8 af[4], bfr[4];
    #pragma unroll
    for (int mi = 0; mi < 4; mi++) {
      int row = wr * 64 + mi * 16 + r15;
      af[mi] = *(const bf16x8*)&As[row * 32 + ((g ^ (row & 3)) << 3)];
    }
    #pragma unroll
    for (int ni = 0; ni < 4; ni++) {
      int row = wc * 64 + ni * 16 + r15;
      bfr[ni] = *(const bf16x8*)&Bs[row * 32 + ((g ^ (row & 3)) << 3)];
    }
    #pragma unroll
    for (int mi = 0; mi < 4; mi++)
      #pragma unroll
      for (int ni = 0; ni < 4; ni++)
        acc[mi][ni] = __builtin_amdgcn_mfma_f32_16x16x32_bf16(af[mi], bfr[ni], acc[mi][ni], 0, 0, 0);
  }
  #pragma unroll
  for (int mi = 0; mi < 4; mi++)
    #pragma unroll
    for (int ni = 0; ni < 4; ni++) {
      size_t col = n0 + wc * 64 + ni * 16 + r15;
      #pragma unroll
      for (int rr = 0; rr < 4; rr++) {
        size_t row = m0 + wr * 64 + mi * 16 + g * 4 + rr;
        size_t idx = row * (size_t)N + col;
        float v = acc[mi][ni][rr];
        if (MODE == 0) Cf[idx] = v;
        else Cb[idx] = (bf16)v;
      }
    }
}

// ---------------- flash attention: Q[S,D] x K[Skv,D] x VT[D,Skv] -> O[S,D] ----------------
__global__ __launch_bounds__(256) void k_attn(const bf16* __restrict__ Q, const bf16* __restrict__ Kb,
                                              const bf16* __restrict__ VT, bf16* __restrict__ O,
                                              int Skv) {
  __shared__ bf16 Kt[32 * 128];
  __shared__ bf16 Vt[128 * 32];
  __shared__ bf16 Pt[4][16 * 32];
  const int h = blockIdx.y;
  const int t = threadIdx.x, w = t >> 6, lane = t & 63;
  const int g = lane >> 4, r15 = lane & 15;
  const int q0 = blockIdx.x * 64 + w * 16;
  bf16x8 qf[4];
  #pragma unroll
  for (int c = 0; c < 4; c++)
    qf[c] = *(const bf16x8*)(Q + (size_t)(q0 + r15) * D + h * 128 + c * 32 + g * 8);
  f32x4 o[8] = {};
  float m_[4] = { -1e30f, -1e30f, -1e30f, -1e30f };
  float l_[4] = { 0.f, 0.f, 0.f, 0.f };
  const float scale = 0.08838834764831845f;
  for (int kt = 0; kt < Skv; kt += 32) {
    __syncthreads();
    #pragma unroll
    for (int cc = 0; cc < 2; cc++) {
      int c = t + cc * 256;
      int kr = c >> 4, ks = c & 15;
      gload16(Kb + (size_t)(kt + kr) * D + h * 128 + ((ks ^ (kr & 15)) << 3), &Kt[c * 8]);
      int vr = c >> 2, vs = c & 3;
      gload16(VT + (size_t)(h * 128 + vr) * Skv + kt + ((vs ^ (vr & 3)) << 3), &Vt[c * 8]);
    }
    __syncthreads();
    f32x4 s0 = {}, s1 = {};
    #pragma unroll
    for (int c = 0; c < 4; c++) {
      int row0 = r15, row1 = 16 + r15;
      bf16x8 kf0 = *(const bf16x8*)&Kt[row0 * 128 + (((4 * c + g) ^ (row0 & 15)) << 3)];
      bf16x8 kf1 = *(const bf16x8*)&Kt[row1 * 128 + (((4 * c + g) ^ (row1 & 15)) << 3)];
      s0 = __builtin_amdgcn_mfma_f32_16x16x32_bf16(qf[c], kf0, s0, 0, 0, 0);
      s1 = __builtin_amdgcn_mfma_f32_16x16x32_bf16(qf[c], kf1, s1, 0, 0, 0);
    }
    float al[4];
    #pragma unroll
    for (int rr = 0; rr < 4; rr++) {
      float v0 = s0[rr] * scale, v1 = s1[rr] * scale;
      float mx = fmaxf(v0, v1);
      #pragma unroll
      for (int off = 1; off < 16; off <<= 1) mx = fmaxf(mx, __shfl_xor(mx, off, 16));
      float mn = fmaxf(m_[rr], mx);
      al[rr] = __expf(m_[rr] - mn);
      float p0 = __expf(v0 - mn), p1 = __expf(v1 - mn);
      float sm = p0 + p1;
      #pragma unroll
      for (int off = 1; off < 16; off <<= 1) sm += __shfl_xor(sm, off, 16);
      l_[rr] = l_[rr] * al[rr] + sm;
      m_[rr] = mn;
      int prow = g * 4 + rr;
      int sl0 = r15 >> 3, sl1 = 2 + (r15 >> 3);
      Pt[w][prow * 32 + ((sl0 ^ (prow & 3)) << 3) + (r15 & 7)] = (bf16)p0;
      Pt[w][prow * 32 + ((sl1 ^ (prow & 3)) << 3) + (r15 & 7)] = (bf16)p1;
    }
    #pragma unroll
    for (int d = 0; d < 8; d++)
      #pragma unroll
      for (int rr = 0; rr < 4; rr++) o[d][rr] *= al[rr];
    bf16x8 pa = *(const bf16x8*)&Pt[w][r15 * 32 + ((g ^ (r15 & 3)) << 3)];
    #pragma unroll
    for (int d = 0; d < 8; d++) {
      int vrow = d * 16 + r15;
      bf16x8 vbf = *(const bf16x8*)&Vt[vrow * 32 + ((g ^ (vrow & 3)) << 3)];
      o[d] = __builtin_amdgcn_mfma_f32_16x16x32_bf16(pa, vbf, o[d], 0, 0, 0);
    }
  }
  #pragma unroll
  for (int rr = 0; rr < 4; rr++) {
    float inv = 1.f / l_[rr];
    #pragma unroll
    for (int d = 0; d < 8; d++)
      O[(size_t)(q0 + g * 4 + rr) * D + h * 128 + d * 16 + r15] = (bf16)(o[d][rr] * inv);
  }
}

extern "C" void kernel_launch(void* const* d_in, const int* in_sizes, int n_in,
                              void* d_out, int out_size, void* d_ws, size_t ws_size,
                              hipStream_t stream) {
  (void)in_sizes; (void)n_in; (void)out_size; (void)ws_size;
  const float* video = (const float*)d_in[0];
  const float* text  = (const float*)d_in[1];
  const float* wq    = (const float*)d_in[2];
  const float* wk    = (const float*)d_in[3];
  const float* wv    = (const float*)d_in[4];
  const float* wo    = (const float*)d_in[5];
  const float* qnw   = (const float*)d_in[6];
  const float* knw   = (const float*)d_in[7];
  const float* cwq   = (const float*)d_in[8];
  const float* cwk   = (const float*)d_in[9];
  const float* cwv   = (const float*)d_in[10];
  const float* cwo   = (const float*)d_in[11];
  const float* cqnw  = (const float*)d_in[12];
  const float* cknw  = (const float*)d_in[13];
  const float* ffp   = (const float*)d_in[14];
  const float* ffd   = (const float*)d_in[15];
  float* out = (float*)d_out;

  // ---- workspace layout (lifetime-aliased, ~602MB) ----
  // wbuf  @0      134MB : transposed weights (DxD use 32MB; ffp-half/ffd use 134MB)
  // Hval  @134MB  134MB : FFN val activations; aliases vb/vt/pre (attn-phase only)
  // Hgate @268MB  134MB : FFN gate activations
  // tail  @402MB        : xb, qb, kb, ab, h1, small text buffers
  char* slab = (char*)d_ws;
  const size_t MB = 1024 * 1024;
  bf16*  wbuf  = (bf16*)slab;
  bf16*  Hval  = (bf16*)(slab + 134 * MB);
  bf16*  Hgate = (bf16*)(slab + 268 * MB);
  bf16*  vb    = (bf16*)(slab + 134 * MB);
  bf16*  vt    = (bf16*)(slab + 166 * MB);
  float* pre   = (float*)(slab + 198 * MB);
  char* p = slab + 402 * MB;
  auto take = [&](size_t bytes) { char* r = p; p += (bytes + 255) & ~(size_t)255; return r; };
  bf16* xb   = (bf16*)take((size_t)S * D * 2);
  bf16* qb   = (bf16*)take((size_t)S * D * 2);
  bf16* kb   = (bf16*)take((size_t)S * D * 2);
  bf16* ab   = (bf16*)take((size_t)S * D * 2);
  float* h1  = (float*)take((size_t)S * D * 4);
  bf16* tbuf = (bf16*)take((size_t)T * D * 2);
  bf16* ckb  = (bf16*)take((size_t)T * D * 2);
  bf16* cvb  = (bf16*)take((size_t)T * D * 2);
  bf16* cvt_ = (bf16*)take((size_t)T * D * 2);
  float* h2  = out;

  dim3 b256(256), b512(512), btc(32, 8);
  auto g2 = [](int M, int N) { return dim3((M / 256) * (N / 256)); };

  // ---- self-attention ----
  k_cvt<<<(S * D) / 1024, b256, 0, stream>>>(video, xb, S * D);
  k_tc<<<dim3(D / 32, D / 32), btc, 0, stream>>>(wq, wbuf, D, D, D);
  k_gemm2<0><<<g2(S, D), b512, 0, stream>>>(xb, wbuf, pre, nullptr, nullptr, nullptr, S, D, D, D / 256);
  k_rms<<<S, b256, 0, stream>>>(pre, qnw, qb);
  k_tc<<<dim3(D / 32, D / 32), btc, 0, stream>>>(wk, wbuf, D, D, D);
  k_gemm2<0><<<g2(S, D), b512, 0, stream>>>(xb, wbuf, pre, nullptr, nullptr, nullptr, S, D, D, D / 256);
  k_rms<<<S, b256, 0, stream>>>(pre, knw, kb);
  k_tc<<<dim3(D / 32, D / 32), btc, 0, stream>>>(wv, wbuf, D, D, D);
  k_gemm2<1><<<g2(S, D), b512, 0, stream>>>(xb, wbuf, nullptr, vb, nullptr, nullptr, S, D, D, D / 256);
  k_tb<<<dim3(D / 32, S / 32), btc, 0, stream>>>(vb, vt, S, D);
  k_attn<<<dim3(S / 64, H), b256, 0, stream>>>(qb, kb, vt, ab, S);
  k_tc<<<dim3(D / 32, D / 32), btc, 0, stream>>>(wo, wbuf, D, D, D);
  k_gemm2<2><<<g2(S, D), b512, 0, stream>>>(ab, wbuf, h1, nullptr, video, nullptr, S, D, D, D / 256);

  // ---- cross-attention ----
  k_cvt<<<(S * D) / 1024, b256, 0, stream>>>(h1, xb, S * D);
  k_tc<<<dim3(D / 32, D / 32), btc, 0, stream>>>(cwq, wbuf, D, D, D);
  k_gemm2<0><<<g2(S, D), b512, 0, stream>>>(xb, wbuf, pre, nullptr, nullptr, nullptr, S, D, D, D / 256);
  k_rms<<<S, b256, 0, stream>>>(pre, cqnw, qb);
  k_cvt<<<(T * D) / 1024, b256, 0, stream>>>(text, tbuf, T * D);
  k_tc<<<dim3(D / 32, D / 32), btc, 0, stream>>>(cwk, wbuf, D, D, D);
  k_gemm128<0><<<dim3(D / 128, T / 128), b256, 0, stream>>>(tbuf, wbuf, pre, nullptr, T, D, D);
  k_rms<<<T, b256, 0, stream>>>(pre, cknw, ckb);
  k_tc<<<dim3(D / 32, D / 32), btc, 0, stream>>>(cwv, wbuf, D, D, D);
  k_gemm128<1><<<dim3(D / 128, T / 128), b256, 0, stream>>>(tbuf, wbuf, nullptr, cvb, T, D, D);
  k_tb<<<dim3(D / 32, T / 32), btc, 0, stream>>>(cvb, cvt_, T, D);
  k_attn<<<dim3(S / 64, H), b256, 0, stream>>>(qb, ckb, cvt_, ab, T);
  k_tc<<<dim3(D / 32, D / 32), btc, 0, stream>>>(cwo, wbuf, D, D, D);
  k_gemm2<2><<<g2(S, D), b512, 0, stream>>>(ab, wbuf, h2, nullptr, h1, nullptr, S, D, D, D / 256);

  // ---- GEGLU FFN ----
  k_cvt<<<(S * D) / 1024, b256, 0, stream>>>(h2, xb, S * D);
  // val half: BT = ffp[:, 0:F]^T
  k_tc<<<dim3(F / 32, D / 32), btc, 0, stream>>>(ffp, wbuf, D, F, 2 * F);
  k_gemm2<1><<<g2(S, F), b512, 0, stream>>>(xb, wbuf, nullptr, Hval, nullptr, nullptr, S, F, D, F / 256);
  // gate half with fused GLU epilogue: Hval <- Hval * gelu(gate)
  k_tc<<<dim3(F / 32, D / 32), btc, 0, stream>>>(ffp + F, wbuf, D, F, 2 * F);
  k_gemm2<3><<<g2(S, F), b512, 0, stream>>>(xb, wbuf, nullptr, Hval, nullptr, Hval, S, F, D, F / 256);
  (void)Hgate;
  // down projection + residual
  k_tc<<<dim3(D / 32, F / 32), btc, 0, stream>>>(ffd, wbuf, F, D, D);
  k_gemm2<2><<<g2(S, D), b512, 0, stream>>>(Hval, wbuf, out, nullptr, h2, nullptr, S, D, F, D / 256);
}

// Round 4
// 5359.066 us; speedup vs baseline: 1.1455x; 1.1020x over previous
//
#include <hip/hip_runtime.h>
#include <cstdint>
#include <cstddef>

typedef __bf16 bf16;
typedef __bf16 bf16x8 __attribute__((ext_vector_type(8)));
typedef __bf16 bf16x4 __attribute__((ext_vector_type(4)));
typedef float f32x4 __attribute__((ext_vector_type(4)));

static constexpr int D = 4096;
static constexpr int S = 4096;
static constexpr int T = 256;
static constexpr int H = 32;
static constexpr int F = 16384;

__device__ __forceinline__ void gload16(const void* g, void* l) {
  __builtin_amdgcn_global_load_lds((const __attribute__((address_space(1))) void*)g,
                                   (__attribute__((address_space(3))) void*)l, 16, 0, 0);
}

#define MFMA16(a, b, c) __builtin_amdgcn_mfma_f32_16x16x32_bf16((a), (b), (c), 0, 0, 0)

// ---------------- elementwise f32 -> bf16 ----------------
__global__ __launch_bounds__(256) void k_cvt(const float* __restrict__ in, bf16* __restrict__ out, int n) {
  int i = (blockIdx.x * 256 + threadIdx.x) * 4;
  if (i >= n) return;
  float4 v = *(const float4*)(in + i);
  bf16x4 o = { (bf16)v.x, (bf16)v.y, (bf16)v.z, (bf16)v.w };
  *(bf16x4*)(out + i) = o;
}

// ---------------- transpose+cvt: f32 [R][C] (row stride ldin) -> bf16 [C][R] ----------------
__global__ __launch_bounds__(256) void k_tc(const float* __restrict__ in, bf16* __restrict__ out,
                                            int R, int C, int ldin) {
  __shared__ float tile[32][33];
  int c0 = blockIdx.x * 32, r0 = blockIdx.y * 32;
  int x = threadIdx.x, y = threadIdx.y;
  #pragma unroll
  for (int yy = y; yy < 32; yy += 8)
    tile[yy][x] = in[(size_t)(r0 + yy) * ldin + c0 + x];
  __syncthreads();
  #pragma unroll
  for (int yy = y; yy < 32; yy += 8)
    out[(size_t)(c0 + yy) * R + r0 + x] = (bf16)tile[x][yy];
}

// ---------------- transpose bf16 [R][C] -> [C][R] ----------------
__global__ __launch_bounds__(256) void k_tb(const bf16* __restrict__ in, bf16* __restrict__ out, int R, int C) {
  __shared__ bf16 tile[32][33];
  int c0 = blockIdx.x * 32, r0 = blockIdx.y * 32;
  int x = threadIdx.x, y = threadIdx.y;
  #pragma unroll
  for (int yy = y; yy < 32; yy += 8)
    tile[yy][x] = in[(size_t)(r0 + yy) * C + c0 + x];
  __syncthreads();
  #pragma unroll
  for (int yy = y; yy < 32; yy += 8)
    out[(size_t)(c0 + yy) * R + r0 + x] = tile[x][yy];
}

// ---------------- rmsnorm over 4096, f32 in -> bf16 out ----------------
__global__ __launch_bounds__(256) void k_rms(const float* __restrict__ in, const float* __restrict__ w,
                                             bf16* __restrict__ out) {
  const int row = blockIdx.x, t = threadIdx.x;
  const float* x = in + (size_t)row * 4096;
  float4 v[4];
  float ss = 0.f;
  #pragma unroll
  for (int i = 0; i < 4; i++) {
    v[i] = *(const float4*)(x + t * 4 + i * 1024);
    ss += v[i].x * v[i].x + v[i].y * v[i].y + v[i].z * v[i].z + v[i].w * v[i].w;
  }
  #pragma unroll
  for (int off = 1; off < 64; off <<= 1) ss += __shfl_xor(ss, off, 64);
  __shared__ float red[4];
  if ((t & 63) == 0) red[t >> 6] = ss;
  __syncthreads();
  float rms = rsqrtf((red[0] + red[1] + red[2] + red[3]) * (1.f / 4096.f) + 1e-6f);
  #pragma unroll
  for (int i = 0; i < 4; i++) {
    const float4 wv = *(const float4*)(w + t * 4 + i * 1024);
    bf16x4 ov = { (bf16)(v[i].x * rms * wv.x), (bf16)(v[i].y * rms * wv.y),
                  (bf16)(v[i].z * rms * wv.z), (bf16)(v[i].w * rms * wv.w) };
    *(bf16x4*)(out + (size_t)row * 4096 + t * 4 + i * 1024) = ov;
  }
}

// ================= 256x256 counted-vmcnt 4-phase GEMM: C[M,N] = A[M,K] @ BT[N,K] =================
// 8 waves (2Mx4N), BK=64 split into kh panels [256][32]; staging 2 tiles deep, never drains
// (vmcnt(10) twice per K-tile). Panel free order A0->B0->A1->B1 matches stage order.
// MODE 0: f32 out; 1: bf16 out; 2: f32 out + f32 residual; 3: bf16 out = mul * gelu(acc)
template <int MODE>
__global__ __launch_bounds__(512, 2) void k_gemm2(const bf16* __restrict__ A, const bf16* __restrict__ BT,
                                                  float* __restrict__ Cf, bf16* __restrict__ Cb,
                                                  const float* __restrict__ res, const bf16* __restrict__ mul,
                                                  int M, int N, int K, int gx) {
  __shared__ bf16 LA[2][2][256 * 32];  // [dbuf][kh][row*32+col]
  __shared__ bf16 LB[2][2][256 * 32];
  // bijective XCD swizzle (m204)
  const int nwg = gridDim.x;
  const int orig = blockIdx.x;
  const int q8 = nwg >> 3, r8 = nwg & 7;
  const int xcd = orig & 7, oidx = orig >> 3;
  const int swz = (xcd < r8 ? xcd * (q8 + 1) : r8 * (q8 + 1) + (xcd - r8) * q8) + oidx;
  const int bx = swz % gx, by = swz / gx;
  const size_t m0 = (size_t)by * 256, n0 = (size_t)bx * 256;
  const int t = threadIdx.x;
  const int w = t >> 6, lane = t & 63;
  const int wm = w >> 2, wn = w & 3;
  const int g = lane >> 4, r15 = lane & 15;
  const int nt = K >> 6;
  // staging: panel = [256 rows][32 bf16] (16KB); thread covers segs t and t+512.
  const int sr0 = t >> 2, ss0 = t & 3;
  const int sr1 = (t + 512) >> 2, ss1 = (t + 512) & 3;
  const int sc0 = ((ss0 ^ ((sr0 >> 1) & 3)) << 3);  // pre-swizzled global col (rule 21)
  const int sc1 = ((ss1 ^ ((sr1 >> 1) & 3)) << 3);
  f32x4 acc[8][4] = {};

  auto stA = [&](int db, int kh, int st) {
    const bf16* src = A + m0 * K + (size_t)st * 64 + kh * 32;
    gload16(src + (size_t)sr0 * K + sc0, &LA[db][kh][t * 8]);
    gload16(src + (size_t)sr1 * K + sc1, &LA[db][kh][(t + 512) * 8]);
  };
  auto stB = [&](int db, int kh, int st) {
    const bf16* src = BT + n0 * K + (size_t)st * 64 + kh * 32;
    gload16(src + (size_t)sr0 * K + sc0, &LB[db][kh][t * 8]);
    gload16(src + (size_t)sr1 * K + sc1, &LB[db][kh][(t + 512) * 8]);
  };

  // prologue: A0(0),B0(0),A1(0),B1(0),A0(1),B0(1),A1(1)  [14 loads/thread]
  stA(0, 0, 0); stB(0, 0, 0); stA(0, 1, 0); stB(0, 1, 0);
  stA(1, 0, 1); stB(1, 0, 1); stA(1, 1, 1);
  asm volatile("s_waitcnt vmcnt(10)" ::: "memory");  // A0(0),B0(0) landed
  __builtin_amdgcn_s_barrier();

  const int arow = wm * 128;
  for (int tt = 0; tt < nt; ++tt) {
    const int d = tt & 1, e = d ^ 1;
    const int t1 = (tt + 1 < nt) ? tt + 1 : nt - 1;
    const int t2 = (tt + 2 < nt) ? tt + 2 : nt - 1;
    bf16x8 af[8], b0, b1;

    // ---- phase 0: kh=0, nh=0 ----
    #pragma unroll
    for (int mf = 0; mf < 8; ++mf) {
      const int rr = arow + mf * 16 + r15;
      af[mf] = *(const bf16x8*)&LA[d][0][rr * 32 + ((g ^ ((rr >> 1) & 3)) << 3)];
    }
    {
      const int rb0 = wn * 64 + r15, rb1 = wn * 64 + 16 + r15;
      b0 = *(const bf16x8*)&LB[d][0][rb0 * 32 + ((g ^ ((rb0 >> 1) & 3)) << 3)];
      b1 = *(const bf16x8*)&LB[d][0][rb1 * 32 + ((g ^ ((rb1 >> 1) & 3)) << 3)];
    }
    stB(e, 1, t1);  // B1(t+1)
    __builtin_amdgcn_s_barrier();
    __builtin_amdgcn_s_setprio(1);
    #pragma unroll
    for (int mf = 0; mf < 8; ++mf) {
      acc[mf][0] = MFMA16(af[mf], b0, acc[mf][0]);
      acc[mf][1] = MFMA16(af[mf], b1, acc[mf][1]);
    }
    __builtin_amdgcn_s_setprio(0);
    __builtin_amdgcn_s_barrier();

    // ---- phase 1: kh=0, nh=1 (A regs reused) ----
    {
      const int rb0 = wn * 64 + 32 + r15, rb1 = wn * 64 + 48 + r15;
      b0 = *(const bf16x8*)&LB[d][0][rb0 * 32 + ((g ^ ((rb0 >> 1) & 3)) << 3)];
      b1 = *(const bf16x8*)&LB[d][0][rb1 * 32 + ((g ^ ((rb1 >> 1) & 3)) << 3)];
    }
    stA(d, 0, t2);  // A0(t+2)
    __builtin_amdgcn_s_barrier();
    __builtin_amdgcn_s_setprio(1);
    #pragma unroll
    for (int mf = 0; mf < 8; ++mf) {
      acc[mf][2] = MFMA16(af[mf], b0, acc[mf][2]);
      acc[mf][3] = MFMA16(af[mf], b1, acc[mf][3]);
    }
    __builtin_amdgcn_s_setprio(0);
    asm volatile("s_waitcnt vmcnt(10)" ::: "memory");  // A1(t),B1(t) landed
    __builtin_amdgcn_s_barrier();

    // ---- phase 2: kh=1, nh=0 ----
    #pragma unroll
    for (int mf = 0; mf < 8; ++mf) {
      const int rr = arow + mf * 16 + r15;
      af[mf] = *(const bf16x8*)&LA[d][1][rr * 32 + ((g ^ ((rr >> 1) & 3)) << 3)];
    }
    {
      const int rb0 = wn * 64 + r15, rb1 = wn * 64 + 16 + r15;
      b0 = *(const bf16x8*)&LB[d][1][rb0 * 32 + ((g ^ ((rb0 >> 1) & 3)) << 3)];
      b1 = *(const bf16x8*)&LB[d][1][rb1 * 32 + ((g ^ ((rb1 >> 1) & 3)) << 3)];
    }
    stB(d, 0, t2);  // B0(t+2)
    __builtin_amdgcn_s_barrier();
    __builtin_amdgcn_s_setprio(1);
    #pragma unroll
    for (int mf = 0; mf < 8; ++mf) {
      acc[mf][0] = MFMA16(af[mf], b0, acc[mf][0]);
      acc[mf][1] = MFMA16(af[mf], b1, acc[mf][1]);
    }
    __builtin_amdgcn_s_setprio(0);
    __builtin_amdgcn_s_barrier();

    // ---- phase 3: kh=1, nh=1 (A regs reused) ----
    {
      const int rb0 = wn * 64 + 32 + r15, rb1 = wn * 64 + 48 + r15;
      b0 = *(const bf16x8*)&LB[d][1][rb0 * 32 + ((g ^ ((rb0 >> 1) & 3)) << 3)];
      b1 = *(const bf16x8*)&LB[d][1][rb1 * 32 + ((g ^ ((rb1 >> 1) & 3)) << 3)];
    }
    stA(d, 1, t2);  // A1(t+2)
    __builtin_amdgcn_s_barrier();
    __builtin_amdgcn_s_setprio(1);
    #pragma unroll
    for (int mf = 0; mf < 8; ++mf) {
      acc[mf][2] = MFMA16(af[mf], b0, acc[mf][2]);
      acc[mf][3] = MFMA16(af[mf], b1, acc[mf][3]);
    }
    __builtin_amdgcn_s_setprio(0);
    asm volatile("s_waitcnt vmcnt(10)" ::: "memory");  // A0(t+1),B0(t+1) landed
    __builtin_amdgcn_s_barrier();
  }

  // epilogue
  #pragma unroll
  for (int mf = 0; mf < 8; ++mf)
    #pragma unroll
    for (int nf = 0; nf < 4; ++nf) {
      const size_t col = n0 + wn * 64 + nf * 16 + r15;
      #pragma unroll
      for (int rr = 0; rr < 4; ++rr) {
        const size_t row = m0 + wm * 128 + mf * 16 + g * 4 + rr;
        const size_t idx = row * (size_t)N + col;
        const float v = acc[mf][nf][rr];
        if (MODE == 0) Cf[idx] = v;
        else if (MODE == 1) Cb[idx] = (bf16)v;
        else if (MODE == 2) Cf[idx] = v + res[idx];
        else {
          const float z = 1.595769122f * v + 0.0713548162f * v * v * v;
          const float gel = v / (1.f + __expf(-z));
          Cb[idx] = (bf16)((float)mul[idx] * gel);
        }
      }
    }
}

// ---------------- 128x128 GEMM (m97 structure) for M=256 cases ----------------
template <int MODE>
__global__ __launch_bounds__(256) void k_gemm128(const bf16* __restrict__ A, const bf16* __restrict__ BT,
                                                 float* __restrict__ Cf, bf16* __restrict__ Cb,
                                                 int M, int N, int K) {
  __shared__ bf16 As[128 * 32];
  __shared__ bf16 Bs[128 * 32];
  const int t = threadIdx.x;
  const int lane = t & 63, w = t >> 6;
  const int wr = w >> 1, wc = w & 1;
  const int g = lane >> 4, r15 = lane & 15;
  const size_t m0 = (size_t)blockIdx.y * 128, n0 = (size_t)blockIdx.x * 128;
  f32x4 acc[4][4] = {};
  const int c0 = t, c1 = t + 256;
  const int ar0 = c0 >> 2, as0 = c0 & 3, ar1 = c1 >> 2, as1 = c1 & 3;
  const bf16* Ab = A + m0 * K;
  const bf16* Bb = BT + n0 * K;
  for (int k0 = 0; k0 < K; k0 += 32) {
    __syncthreads();
    gload16(Ab + (size_t)ar0 * K + k0 + ((as0 ^ (ar0 & 3)) << 3), &As[c0 * 8]);
    gload16(Ab + (size_t)ar1 * K + k0 + ((as1 ^ (ar1 & 3)) << 3), &As[c1 * 8]);
    gload16(Bb + (size_t)ar0 * K + k0 + ((as0 ^ (ar0 & 3)) << 3), &Bs[c0 * 8]);
    gload16(Bb + (size_t)ar1 * K + k0 + ((as1 ^ (ar1 & 3)) << 3), &Bs[c1 * 8]);
    __syncthreads();
    bf16x8 af[4], bfr[4];
    #pragma unroll
    for (int mi = 0; mi < 4; mi++) {
      int row = wr * 64 + mi * 16 + r15;
      af[mi] = *(const bf16x8*)&As[row * 32 + ((g ^ (row & 3)) << 3)];
    }
    #pragma unroll
    for (int ni = 0; ni < 4; ni++) {
      int row = wc * 64 + ni * 16 + r15;
      bfr[ni] = *(const bf16x8*)&Bs[row * 32 + ((g ^ (row & 3)) << 3)];
    }
    #pragma unroll
    for (int mi = 0; mi < 4; mi++)
      #pragma unroll
      for (int ni = 0; ni < 4; ni++)
        acc[mi][ni] = MFMA16(af[mi], bfr[ni], acc[mi][ni]);
  }
  #pragma unroll
  for (int mi = 0; mi < 4; mi++)
    #pragma unroll
    for (int ni = 0; ni < 4; ni++) {
      size_t col = n0 + wc * 64 + ni * 16 + r15;
      #pragma unroll
      for (int rr = 0; rr < 4; rr++) {
        size_t row = m0 + wr * 64 + mi * 16 + g * 4 + rr;
        size_t idx = row * (size_t)N + col;
        float v = acc[mi][ni][rr];
        if (MODE == 0) Cf[idx] = v;
        else Cb[idx] = (bf16)v;
      }
    }
}

// ---------------- flash attention: Q[S,D] x K[Skv,D] x VT[D,Skv] -> O[S,D] ----------------
__global__ __launch_bounds__(256) void k_attn(const bf16* __restrict__ Q, const bf16* __restrict__ Kb,
                                              const bf16* __restrict__ VT, bf16* __restrict__ O,
                                              int Skv) {
  __shared__ bf16 Kt[32 * 128];
  __shared__ bf16 Vt[128 * 32];
  __shared__ bf16 Pt[4][16 * 32];
  const int h = blockIdx.y;
  const int t = threadIdx.x, w = t >> 6, lane = t & 63;
  const int g = lane >> 4, r15 = lane & 15;
  const int q0 = blockIdx.x * 64 + w * 16;
  bf16x8 qf[4];
  #pragma unroll
  for (int c = 0; c < 4; c++)
    qf[c] = *(const bf16x8*)(Q + (size_t)(q0 + r15) * D + h * 128 + c * 32 + g * 8);
  f32x4 o[8] = {};
  float m_[4] = { -1e30f, -1e30f, -1e30f, -1e30f };
  float l_[4] = { 0.f, 0.f, 0.f, 0.f };
  const float scale = 0.08838834764831845f;
  for (int kt = 0; kt < Skv; kt += 32) {
    __syncthreads();
    #pragma unroll
    for (int cc = 0; cc < 2; cc++) {
      int c = t + cc * 256;
      int kr = c >> 4, ks = c & 15;
      gload16(Kb + (size_t)(kt + kr) * D + h * 128 + ((ks ^ (kr & 15)) << 3), &Kt[c * 8]);
      int vr = c >> 2, vs = c & 3;
      gload16(VT + (size_t)(h * 128 + vr) * Skv + kt + ((vs ^ (vr & 3)) << 3), &Vt[c * 8]);
    }
    __syncthreads();
    f32x4 s0 = {}, s1 = {};
    #pragma unroll
    for (int c = 0; c < 4; c++) {
      int row0 = r15, row1 = 16 + r15;
      bf16x8 kf0 = *(const bf16x8*)&Kt[row0 * 128 + (((4 * c + g) ^ (row0 & 15)) << 3)];
      bf16x8 kf1 = *(const bf16x8*)&Kt[row1 * 128 + (((4 * c + g) ^ (row1 & 15)) << 3)];
      s0 = MFMA16(qf[c], kf0, s0);
      s1 = MFMA16(qf[c], kf1, s1);
    }
    float al[4];
    #pragma unroll
    for (int rr = 0; rr < 4; rr++) {
      float v0 = s0[rr] * scale, v1 = s1[rr] * scale;
      float mx = fmaxf(v0, v1);
      #pragma unroll
      for (int off = 1; off < 16; off <<= 1) mx = fmaxf(mx, __shfl_xor(mx, off, 16));
      float mn = fmaxf(m_[rr], mx);
      al[rr] = __expf(m_[rr] - mn);
      float p0 = __expf(v0 - mn), p1 = __expf(v1 - mn);
      float sm = p0 + p1;
      #pragma unroll
      for (int off = 1; off < 16; off <<= 1) sm += __shfl_xor(sm, off, 16);
      l_[rr] = l_[rr] * al[rr] + sm;
      m_[rr] = mn;
      int prow = g * 4 + rr;
      int sl0 = r15 >> 3, sl1 = 2 + (r15 >> 3);
      Pt[w][prow * 32 + ((sl0 ^ (prow & 3)) << 3) + (r15 & 7)] = (bf16)p0;
      Pt[w][prow * 32 + ((sl1 ^ (prow & 3)) << 3) + (r15 & 7)] = (bf16)p1;
    }
    #pragma unroll
    for (int d = 0; d < 8; d++)
      #pragma unroll
      for (int rr = 0; rr < 4; rr++) o[d][rr] *= al[rr];
    bf16x8 pa = *(const bf16x8*)&Pt[w][r15 * 32 + ((g ^ (r15 & 3)) << 3)];
    #pragma unroll
    for (int d = 0; d < 8; d++) {
      int vrow = d * 16 + r15;
      bf16x8 vbf = *(const bf16x8*)&Vt[vrow * 32 + ((g ^ (vrow & 3)) << 3)];
      o[d] = MFMA16(pa, vbf, o[d]);
    }
  }
  #pragma unroll
  for (int rr = 0; rr < 4; rr++) {
    float inv = 1.f / l_[rr];
    #pragma unroll
    for (int d = 0; d < 8; d++)
      O[(size_t)(q0 + g * 4 + rr) * D + h * 128 + d * 16 + r15] = (bf16)(o[d][rr] * inv);
  }
}

extern "C" void kernel_launch(void* const* d_in, const int* in_sizes, int n_in,
                              void* d_out, int out_size, void* d_ws, size_t ws_size,
                              hipStream_t stream) {
  (void)in_sizes; (void)n_in; (void)out_size; (void)ws_size;
  const float* video = (const float*)d_in[0];
  const float* text  = (const float*)d_in[1];
  const float* wq    = (const float*)d_in[2];
  const float* wk    = (const float*)d_in[3];
  const float* wv    = (const float*)d_in[4];
  const float* wo    = (const float*)d_in[5];
  const float* qnw   = (const float*)d_in[6];
  const float* knw   = (const float*)d_in[7];
  const float* cwq   = (const float*)d_in[8];
  const float* cwk   = (const float*)d_in[9];
  const float* cwv   = (const float*)d_in[10];
  const float* cwo   = (const float*)d_in[11];
  const float* cqnw  = (const float*)d_in[12];
  const float* cknw  = (const float*)d_in[13];
  const float* ffp   = (const float*)d_in[14];
  const float* ffd   = (const float*)d_in[15];
  float* out = (float*)d_out;

  char* slab = (char*)d_ws;
  const size_t MB = 1024 * 1024;
  bf16*  wbuf  = (bf16*)slab;
  bf16*  Hval  = (bf16*)(slab + 134 * MB);
  bf16*  vb    = (bf16*)(slab + 134 * MB);
  bf16*  vt    = (bf16*)(slab + 166 * MB);
  float* pre   = (float*)(slab + 198 * MB);
  char* p = slab + 402 * MB;
  auto take = [&](size_t bytes) { char* r = p; p += (bytes + 255) & ~(size_t)255; return r; };
  bf16* xb   = (bf16*)take((size_t)S * D * 2);
  bf16* qb   = (bf16*)take((size_t)S * D * 2);
  bf16* kb   = (bf16*)take((size_t)S * D * 2);
  bf16* ab   = (bf16*)take((size_t)S * D * 2);
  float* h1  = (float*)take((size_t)S * D * 4);
  bf16* tbuf = (bf16*)take((size_t)T * D * 2);
  bf16* ckb  = (bf16*)take((size_t)T * D * 2);
  bf16* cvb  = (bf16*)take((size_t)T * D * 2);
  bf16* cvt_ = (bf16*)take((size_t)T * D * 2);
  float* h2  = out;

  dim3 b256(256), b512(512), btc(32, 8);
  auto g2 = [](int M, int N) { return dim3((M / 256) * (N / 256)); };

  // ---- self-attention ----
  k_cvt<<<(S * D) / 1024, b256, 0, stream>>>(video, xb, S * D);
  k_tc<<<dim3(D / 32, D / 32), btc, 0, stream>>>(wq, wbuf, D, D, D);
  k_gemm2<0><<<g2(S, D), b512, 0, stream>>>(xb, wbuf, pre, nullptr, nullptr, nullptr, S, D, D, D / 256);
  k_rms<<<S, b256, 0, stream>>>(pre, qnw, qb);
  k_tc<<<dim3(D / 32, D / 32), btc, 0, stream>>>(wk, wbuf, D, D, D);
  k_gemm2<0><<<g2(S, D), b512, 0, stream>>>(xb, wbuf, pre, nullptr, nullptr, nullptr, S, D, D, D / 256);
  k_rms<<<S, b256, 0, stream>>>(pre, knw, kb);
  k_tc<<<dim3(D / 32, D / 32), btc, 0, stream>>>(wv, wbuf, D, D, D);
  k_gemm2<1><<<g2(S, D), b512, 0, stream>>>(xb, wbuf, nullptr, vb, nullptr, nullptr, S, D, D, D / 256);
  k_tb<<<dim3(D / 32, S / 32), btc, 0, stream>>>(vb, vt, S, D);
  k_attn<<<dim3(S / 64, H), b256, 0, stream>>>(qb, kb, vt, ab, S);
  k_tc<<<dim3(D / 32, D / 32), btc, 0, stream>>>(wo, wbuf, D, D, D);
  k_gemm2<2><<<g2(S, D), b512, 0, stream>>>(ab, wbuf, h1, nullptr, video, nullptr, S, D, D, D / 256);

  // ---- cross-attention ----
  k_cvt<<<(S * D) / 1024, b256, 0, stream>>>(h1, xb, S * D);
  k_tc<<<dim3(D / 32, D / 32), btc, 0, stream>>>(cwq, wbuf, D, D, D);
  k_gemm2<0><<<g2(S, D), b512, 0, stream>>>(xb, wbuf, pre, nullptr, nullptr, nullptr, S, D, D, D / 256);
  k_rms<<<S, b256, 0, stream>>>(pre, cqnw, qb);
  k_cvt<<<(T * D) / 1024, b256, 0, stream>>>(text, tbuf, T * D);
  k_tc<<<dim3(D / 32, D / 32), btc, 0, stream>>>(cwk, wbuf, D, D, D);
  k_gemm128<0><<<dim3(D / 128, T / 128), b256, 0, stream>>>(tbuf, wbuf, pre, nullptr, T, D, D);
  k_rms<<<T, b256, 0, stream>>>(pre, cknw, ckb);
  k_tc<<<dim3(D / 32, D / 32), btc, 0, stream>>>(cwv, wbuf, D, D, D);
  k_gemm128<1><<<dim3(D / 128, T / 128), b256, 0, stream>>>(tbuf, wbuf, nullptr, cvb, T, D, D);
  k_tb<<<dim3(D / 32, T / 32), btc, 0, stream>>>(cvb, cvt_, T, D);
  k_attn<<<dim3(S / 64, H), b256, 0, stream>>>(qb, ckb, cvt_, ab, T);
  k_tc<<<dim3(D / 32, D / 32), btc, 0, stream>>>(cwo, wbuf, D, D, D);
  k_gemm2<2><<<g2(S, D), b512, 0, stream>>>(ab, wbuf, h2, nullptr, h1, nullptr, S, D, D, D / 256);

  // ---- GEGLU FFN ----
  k_cvt<<<(S * D) / 1024, b256, 0, stream>>>(h2, xb, S * D);
  k_tc<<<dim3(F / 32, D / 32), btc, 0, stream>>>(ffp, wbuf, D, F, 2 * F);
  k_gemm2<1><<<g2(S, F), b512, 0, stream>>>(xb, wbuf, nullptr, Hval, nullptr, nullptr, S, F, D, F / 256);
  k_tc<<<dim3(F / 32, D / 32), btc, 0, stream>>>(ffp + F, wbuf, D, F, 2 * F);
  k_gemm2<3><<<g2(S, F), b512, 0, stream>>>(xb, wbuf, nullptr, Hval, nullptr, Hval, S, F, D, F / 256);
  k_tc<<<dim3(D / 32, F / 32), btc, 0, stream>>>(ffd, wbuf, F, D, D);
  k_gemm2<2><<<g2(S, D), b512, 0, stream>>>(Hval, wbuf, out, nullptr, h2, nullptr, S, D, F, D / 256);
}

// Round 5
// 4888.498 us; speedup vs baseline: 1.2558x; 1.0963x over previous
//
#include <hip/hip_runtime.h>
#include <cstdint>
#include <cstddef>

typedef __bf16 bf16;
typedef __bf16 bf16x8 __attribute__((ext_vector_type(8)));
typedef __bf16 bf16x4 __attribute__((ext_vector_type(4)));
typedef float f32x4 __attribute__((ext_vector_type(4)));

static constexpr int D = 4096;
static constexpr int S = 4096;
static constexpr int T = 256;
static constexpr int H = 32;
static constexpr int F = 16384;

__device__ __forceinline__ void gload16(const void* g, void* l) {
  __builtin_amdgcn_global_load_lds((const __attribute__((address_space(1))) void*)g,
                                   (__attribute__((address_space(3))) void*)l, 16, 0, 0);
}

#define MFMA16(a, b, c) __builtin_amdgcn_mfma_f32_16x16x32_bf16((a), (b), (c), 0, 0, 0)

// ---------------- elementwise f32 -> bf16 ----------------
__global__ __launch_bounds__(256) void k_cvt(const float* __restrict__ in, bf16* __restrict__ out, int n) {
  int i = (blockIdx.x * 256 + threadIdx.x) * 4;
  if (i >= n) return;
  float4 v = *(const float4*)(in + i);
  bf16x4 o = { (bf16)v.x, (bf16)v.y, (bf16)v.z, (bf16)v.w };
  *(bf16x4*)(out + i) = o;
}

// ---------------- transpose+cvt: f32 [R][C] (row stride ldin) -> bf16 [C][R] ----------------
__global__ __launch_bounds__(256) void k_tc(const float* __restrict__ in, bf16* __restrict__ out,
                                            int R, int C, int ldin) {
  __shared__ float tile[32][33];
  int c0 = blockIdx.x * 32, r0 = blockIdx.y * 32;
  int x = threadIdx.x, y = threadIdx.y;
  #pragma unroll
  for (int yy = y; yy < 32; yy += 8)
    tile[yy][x] = in[(size_t)(r0 + yy) * ldin + c0 + x];
  __syncthreads();
  #pragma unroll
  for (int yy = y; yy < 32; yy += 8)
    out[(size_t)(c0 + yy) * R + r0 + x] = (bf16)tile[x][yy];
}

// ---------------- transpose bf16 [R][C] -> [C][R] ----------------
__global__ __launch_bounds__(256) void k_tb(const bf16* __restrict__ in, bf16* __restrict__ out, int R, int C) {
  __shared__ bf16 tile[32][33];
  int c0 = blockIdx.x * 32, r0 = blockIdx.y * 32;
  int x = threadIdx.x, y = threadIdx.y;
  #pragma unroll
  for (int yy = y; yy < 32; yy += 8)
    tile[yy][x] = in[(size_t)(r0 + yy) * C + c0 + x];
  __syncthreads();
  #pragma unroll
  for (int yy = y; yy < 32; yy += 8)
    out[(size_t)(c0 + yy) * R + r0 + x] = tile[x][yy];
}

// ---------------- rmsnorm over 4096, f32 in -> bf16 out ----------------
__global__ __launch_bounds__(256) void k_rms(const float* __restrict__ in, const float* __restrict__ w,
                                             bf16* __restrict__ out) {
  const int row = blockIdx.x, t = threadIdx.x;
  const float* x = in + (size_t)row * 4096;
  float4 v[4];
  float ss = 0.f;
  #pragma unroll
  for (int i = 0; i < 4; i++) {
    v[i] = *(const float4*)(x + t * 4 + i * 1024);
    ss += v[i].x * v[i].x + v[i].y * v[i].y + v[i].z * v[i].z + v[i].w * v[i].w;
  }
  #pragma unroll
  for (int off = 1; off < 64; off <<= 1) ss += __shfl_xor(ss, off, 64);
  __shared__ float red[4];
  if ((t & 63) == 0) red[t >> 6] = ss;
  __syncthreads();
  float rms = rsqrtf((red[0] + red[1] + red[2] + red[3]) * (1.f / 4096.f) + 1e-6f);
  #pragma unroll
  for (int i = 0; i < 4; i++) {
    const float4 wv = *(const float4*)(w + t * 4 + i * 1024);
    bf16x4 ov = { (bf16)(v[i].x * rms * wv.x), (bf16)(v[i].y * rms * wv.y),
                  (bf16)(v[i].z * rms * wv.z), (bf16)(v[i].w * rms * wv.w) };
    *(bf16x4*)(out + (size_t)row * 4096 + t * 4 + i * 1024) = ov;
  }
}

// supertile XCD mapping: XGM x (8/XGM) XCD grid; per-XCD oidx covers BYG rows x BXG cols
// by = (xcd%XGM)*BYG + oidx%BYG ; bx = (xcd/XGM)*BXG + oidx/BYG  (bijective)
__device__ __forceinline__ void xcd_map(int orig, int XGM, int BYG, int BXG, int& by, int& bx) {
  const int xcd = orig & 7, oidx = orig >> 3;
  by = (xcd % XGM) * BYG + oidx % BYG;
  bx = (xcd / XGM) * BXG + oidx / BYG;
}

// ================= 256x256 counted-vmcnt 4-phase GEMM: C[M,N] = A[M,K] @ BT[N,K] =================
// MODE 0: f32 out; 1: bf16 out; 2: f32 out + f32 residual
template <int MODE>
__global__ __launch_bounds__(512, 2) void k_gemm2(const bf16* __restrict__ A, const bf16* __restrict__ BT,
                                                  float* __restrict__ Cf, bf16* __restrict__ Cb,
                                                  const float* __restrict__ res,
                                                  int M, int N, int K, int XGM, int BYG, int BXG) {
  __shared__ bf16 LA[2][2][256 * 32];  // [dbuf][kh][row*32+col]
  __shared__ bf16 LB[2][2][256 * 32];
  int by, bx;
  xcd_map(blockIdx.x, XGM, BYG, BXG, by, bx);
  const size_t m0 = (size_t)by * 256, n0 = (size_t)bx * 256;
  const int t = threadIdx.x;
  const int w = t >> 6, lane = t & 63;
  const int wm = w >> 2, wn = w & 3;
  const int g = lane >> 4, r15 = lane & 15;
  const int nt = K >> 6;
  const int sr0 = t >> 2, ss0 = t & 3;
  const int sr1 = (t + 512) >> 2, ss1 = (t + 512) & 3;
  const int sc0 = ((ss0 ^ ((sr0 >> 1) & 3)) << 3);
  const int sc1 = ((ss1 ^ ((sr1 >> 1) & 3)) << 3);
  f32x4 acc[8][4] = {};

  auto stA = [&](int db, int kh, int st) {
    const bf16* src = A + m0 * K + (size_t)st * 64 + kh * 32;
    gload16(src + (size_t)sr0 * K + sc0, &LA[db][kh][t * 8]);
    gload16(src + (size_t)sr1 * K + sc1, &LA[db][kh][(t + 512) * 8]);
  };
  auto stB = [&](int db, int kh, int st) {
    const bf16* src = BT + n0 * K + (size_t)st * 64 + kh * 32;
    gload16(src + (size_t)sr0 * K + sc0, &LB[db][kh][t * 8]);
    gload16(src + (size_t)sr1 * K + sc1, &LB[db][kh][(t + 512) * 8]);
  };

  stA(0, 0, 0); stB(0, 0, 0); stA(0, 1, 0); stB(0, 1, 0);
  stA(1, 0, 1); stB(1, 0, 1); stA(1, 1, 1);
  asm volatile("s_waitcnt vmcnt(10)" ::: "memory");
  __builtin_amdgcn_s_barrier();

  const int arow = wm * 128;
  for (int tt = 0; tt < nt; ++tt) {
    const int d = tt & 1, e = d ^ 1;
    const int t1 = (tt + 1 < nt) ? tt + 1 : nt - 1;
    const int t2 = (tt + 2 < nt) ? tt + 2 : nt - 1;
    bf16x8 af[8], b0, b1;

    // phase 0: kh=0, nh=0
    #pragma unroll
    for (int mf = 0; mf < 8; ++mf) {
      const int rr = arow + mf * 16 + r15;
      af[mf] = *(const bf16x8*)&LA[d][0][rr * 32 + ((g ^ ((rr >> 1) & 3)) << 3)];
    }
    {
      const int rb0 = wn * 64 + r15, rb1 = wn * 64 + 16 + r15;
      b0 = *(const bf16x8*)&LB[d][0][rb0 * 32 + ((g ^ ((rb0 >> 1) & 3)) << 3)];
      b1 = *(const bf16x8*)&LB[d][0][rb1 * 32 + ((g ^ ((rb1 >> 1) & 3)) << 3)];
    }
    stB(e, 1, t1);
    __builtin_amdgcn_s_barrier();
    __builtin_amdgcn_s_setprio(1);
    #pragma unroll
    for (int mf = 0; mf < 8; ++mf) {
      acc[mf][0] = MFMA16(af[mf], b0, acc[mf][0]);
      acc[mf][1] = MFMA16(af[mf], b1, acc[mf][1]);
    }
    __builtin_amdgcn_s_setprio(0);
    __builtin_amdgcn_s_barrier();

    // phase 1: kh=0, nh=1
    {
      const int rb0 = wn * 64 + 32 + r15, rb1 = wn * 64 + 48 + r15;
      b0 = *(const bf16x8*)&LB[d][0][rb0 * 32 + ((g ^ ((rb0 >> 1) & 3)) << 3)];
      b1 = *(const bf16x8*)&LB[d][0][rb1 * 32 + ((g ^ ((rb1 >> 1) & 3)) << 3)];
    }
    stA(d, 0, t2);
    __builtin_amdgcn_s_barrier();
    __builtin_amdgcn_s_setprio(1);
    #pragma unroll
    for (int mf = 0; mf < 8; ++mf) {
      acc[mf][2] = MFMA16(af[mf], b0, acc[mf][2]);
      acc[mf][3] = MFMA16(af[mf], b1, acc[mf][3]);
    }
    __builtin_amdgcn_s_setprio(0);
    asm volatile("s_waitcnt vmcnt(10)" ::: "memory");
    __builtin_amdgcn_s_barrier();

    // phase 2: kh=1, nh=0
    #pragma unroll
    for (int mf = 0; mf < 8; ++mf) {
      const int rr = arow + mf * 16 + r15;
      af[mf] = *(const bf16x8*)&LA[d][1][rr * 32 + ((g ^ ((rr >> 1) & 3)) << 3)];
    }
    {
      const int rb0 = wn * 64 + r15, rb1 = wn * 64 + 16 + r15;
      b0 = *(const bf16x8*)&LB[d][1][rb0 * 32 + ((g ^ ((rb0 >> 1) & 3)) << 3)];
      b1 = *(const bf16x8*)&LB[d][1][rb1 * 32 + ((g ^ ((rb1 >> 1) & 3)) << 3)];
    }
    stB(d, 0, t2);
    __builtin_amdgcn_s_barrier();
    __builtin_amdgcn_s_setprio(1);
    #pragma unroll
    for (int mf = 0; mf < 8; ++mf) {
      acc[mf][0] = MFMA16(af[mf], b0, acc[mf][0]);
      acc[mf][1] = MFMA16(af[mf], b1, acc[mf][1]);
    }
    __builtin_amdgcn_s_setprio(0);
    __builtin_amdgcn_s_barrier();

    // phase 3: kh=1, nh=1
    {
      const int rb0 = wn * 64 + 32 + r15, rb1 = wn * 64 + 48 + r15;
      b0 = *(const bf16x8*)&LB[d][1][rb0 * 32 + ((g ^ ((rb0 >> 1) & 3)) << 3)];
      b1 = *(const bf16x8*)&LB[d][1][rb1 * 32 + ((g ^ ((rb1 >> 1) & 3)) << 3)];
    }
    stA(d, 1, t2);
    __builtin_amdgcn_s_barrier();
    __builtin_amdgcn_s_setprio(1);
    #pragma unroll
    for (int mf = 0; mf < 8; ++mf) {
      acc[mf][2] = MFMA16(af[mf], b0, acc[mf][2]);
      acc[mf][3] = MFMA16(af[mf], b1, acc[mf][3]);
    }
    __builtin_amdgcn_s_setprio(0);
    asm volatile("s_waitcnt vmcnt(10)" ::: "memory");
    __builtin_amdgcn_s_barrier();
  }

  #pragma unroll
  for (int mf = 0; mf < 8; ++mf)
    #pragma unroll
    for (int nf = 0; nf < 4; ++nf) {
      const size_t col = n0 + wn * 64 + nf * 16 + r15;
      #pragma unroll
      for (int rr = 0; rr < 4; ++rr) {
        const size_t row = m0 + wm * 128 + mf * 16 + g * 4 + rr;
        const size_t idx = row * (size_t)N + col;
        const float v = acc[mf][nf][rr];
        if (MODE == 0) Cf[idx] = v;
        else if (MODE == 1) Cb[idx] = (bf16)v;
        else Cf[idx] = v + res[idx];
      }
    }
}

// ================= fused GEGLU GEMM: G[M,N] = (A@BTv) * gelu(A@BTg), tile 256x128 =================
// BT = [2N][K] transposed ffp; val rows [0,N), gate rows [N,2N).
__global__ __launch_bounds__(512, 2) void k_geglu2(const bf16* __restrict__ A, const bf16* __restrict__ BT,
                                                   bf16* __restrict__ G, int N, int K,
                                                   int XGM, int BYG, int BXG) {
  __shared__ bf16 LA[2][2][256 * 32];
  __shared__ bf16 LBv[2][2][128 * 32];
  __shared__ bf16 LBg[2][2][128 * 32];
  int by, bx;
  xcd_map(blockIdx.x, XGM, BYG, BXG, by, bx);
  const size_t m0 = (size_t)by * 256, n0 = (size_t)bx * 128;
  const int t = threadIdx.x;
  const int w = t >> 6, lane = t & 63;
  const int wm = w >> 2, wn = w & 3;
  const int g = lane >> 4, r15 = lane & 15;
  const int nt = K >> 6;
  const int sr0 = t >> 2, ss0 = t & 3;
  const int sr1 = (t + 512) >> 2, ss1 = (t + 512) & 3;
  const int sc0 = ((ss0 ^ ((sr0 >> 1) & 3)) << 3);
  const int sc1 = ((ss1 ^ ((sr1 >> 1) & 3)) << 3);
  f32x4 av[8][2] = {}, ag[8][2] = {};

  auto stA = [&](int db, int kh, int st) {
    const bf16* src = A + m0 * K + (size_t)st * 64 + kh * 32;
    gload16(src + (size_t)sr0 * K + sc0, &LA[db][kh][t * 8]);
    gload16(src + (size_t)sr1 * K + sc1, &LA[db][kh][(t + 512) * 8]);
  };
  auto stBv = [&](int db, int kh, int st) {
    const bf16* src = BT + n0 * K + (size_t)st * 64 + kh * 32;
    gload16(src + (size_t)sr0 * K + sc0, &LBv[db][kh][t * 8]);
  };
  auto stBg = [&](int db, int kh, int st) {
    const bf16* src = BT + ((size_t)N + n0) * K + (size_t)st * 64 + kh * 32;
    gload16(src + (size_t)sr0 * K + sc0, &LBg[db][kh][t * 8]);
  };

  // prologue: tile0 full (A0,Bv0,Bg0,A1,Bv1,Bg1) + tile1 partial (A0,Bv0,Bg0,A1) = 14 loads/thread
  stA(0, 0, 0); stBv(0, 0, 0); stBg(0, 0, 0); stA(0, 1, 0); stBv(0, 1, 0); stBg(0, 1, 0);
  stA(1, 0, 1); stBv(1, 0, 1); stBg(1, 0, 1); stA(1, 1, 1);
  asm volatile("s_waitcnt vmcnt(10)" ::: "memory");  // A0(0),Bv0(0),Bg0(0) landed
  __builtin_amdgcn_s_barrier();

  const int arow = wm * 128;
  for (int tt = 0; tt < nt; ++tt) {
    const int d = tt & 1, e = d ^ 1;
    const int t1 = (tt + 1 < nt) ? tt + 1 : nt - 1;
    const int t2 = (tt + 2 < nt) ? tt + 2 : nt - 1;
    bf16x8 af[8], b0, b1;

    // phase 0: kh=0, val
    #pragma unroll
    for (int mf = 0; mf < 8; ++mf) {
      const int rr = arow + mf * 16 + r15;
      af[mf] = *(const bf16x8*)&LA[d][0][rr * 32 + ((g ^ ((rr >> 1) & 3)) << 3)];
    }
    {
      const int rb0 = wn * 32 + r15, rb1 = wn * 32 + 16 + r15;
      b0 = *(const bf16x8*)&LBv[d][0][rb0 * 32 + ((g ^ ((rb0 >> 1) & 3)) << 3)];
      b1 = *(const bf16x8*)&LBv[d][0][rb1 * 32 + ((g ^ ((rb1 >> 1) & 3)) << 3)];
    }
    stBv(e, 1, t1); stBg(e, 1, t1);
    __builtin_amdgcn_s_barrier();
    __builtin_amdgcn_s_setprio(1);
    #pragma unroll
    for (int mf = 0; mf < 8; ++mf) {
      av[mf][0] = MFMA16(af[mf], b0, av[mf][0]);
      av[mf][1] = MFMA16(af[mf], b1, av[mf][1]);
    }
    __builtin_amdgcn_s_setprio(0);
    __builtin_amdgcn_s_barrier();

    // phase 1: kh=0, gate (A regs reused)
    {
      const int rb0 = wn * 32 + r15, rb1 = wn * 32 + 16 + r15;
      b0 = *(const bf16x8*)&LBg[d][0][rb0 * 32 + ((g ^ ((rb0 >> 1) & 3)) << 3)];
      b1 = *(const bf16x8*)&LBg[d][0][rb1 * 32 + ((g ^ ((rb1 >> 1) & 3)) << 3)];
    }
    stA(d, 0, t2);
    __builtin_amdgcn_s_barrier();
    __builtin_amdgcn_s_setprio(1);
    #pragma unroll
    for (int mf = 0; mf < 8; ++mf) {
      ag[mf][0] = MFMA16(af[mf], b0, ag[mf][0]);
      ag[mf][1] = MFMA16(af[mf], b1, ag[mf][1]);
    }
    __builtin_amdgcn_s_setprio(0);
    asm volatile("s_waitcnt vmcnt(10)" ::: "memory");  // A1(t),Bv1(t),Bg1(t) landed
    __builtin_amdgcn_s_barrier();

    // phase 2: kh=1, val
    #pragma unroll
    for (int mf = 0; mf < 8; ++mf) {
      const int rr = arow + mf * 16 + r15;
      af[mf] = *(const bf16x8*)&LA[d][1][rr * 32 + ((g ^ ((rr >> 1) & 3)) << 3)];
    }
    {
      const int rb0 = wn * 32 + r15, rb1 = wn * 32 + 16 + r15;
      b0 = *(const bf16x8*)&LBv[d][1][rb0 * 32 + ((g ^ ((rb0 >> 1) & 3)) << 3)];
      b1 = *(const bf16x8*)&LBv[d][1][rb1 * 32 + ((g ^ ((rb1 >> 1) & 3)) << 3)];
    }
    stBv(d, 0, t2); stBg(d, 0, t2);
    __builtin_amdgcn_s_barrier();
    __builtin_amdgcn_s_setprio(1);
    #pragma unroll
    for (int mf = 0; mf < 8; ++mf) {
      av[mf][0] = MFMA16(af[mf], b0, av[mf][0]);
      av[mf][1] = MFMA16(af[mf], b1, av[mf][1]);
    }
    __builtin_amdgcn_s_setprio(0);
    __builtin_amdgcn_s_barrier();

    // phase 3: kh=1, gate
    {
      const int rb0 = wn * 32 + r15, rb1 = wn * 32 + 16 + r15;
      b0 = *(const bf16x8*)&LBg[d][1][rb0 * 32 + ((g ^ ((rb0 >> 1) & 3)) << 3)];
      b1 = *(const bf16x8*)&LBg[d][1][rb1 * 32 + ((g ^ ((rb1 >> 1) & 3)) << 3)];
    }
    stA(d, 1, t2);
    __builtin_amdgcn_s_barrier();
    __builtin_amdgcn_s_setprio(1);
    #pragma unroll
    for (int mf = 0; mf < 8; ++mf) {
      ag[mf][0] = MFMA16(af[mf], b0, ag[mf][0]);
      ag[mf][1] = MFMA16(af[mf], b1, ag[mf][1]);
    }
    __builtin_amdgcn_s_setprio(0);
    asm volatile("s_waitcnt vmcnt(10)" ::: "memory");  // A0(t+1),Bv0(t+1),Bg0(t+1) landed
    __builtin_amdgcn_s_barrier();
  }

  #pragma unroll
  for (int mf = 0; mf < 8; ++mf)
    #pragma unroll
    for (int nf = 0; nf < 2; ++nf) {
      const size_t col = n0 + wn * 32 + nf * 16 + r15;
      #pragma unroll
      for (int rr = 0; rr < 4; ++rr) {
        const size_t row = m0 + wm * 128 + mf * 16 + g * 4 + rr;
        const float val = av[mf][nf][rr], gt = ag[mf][nf][rr];
        const float z = 1.595769122f * gt + 0.0713548162f * gt * gt * gt;
        const float gel = gt / (1.f + __expf(-z));
        G[row * (size_t)N + col] = (bf16)(val * gel);
      }
    }
}

// ---------------- 128x128 GEMM (m97 structure) for M=256 cases ----------------
template <int MODE>
__global__ __launch_bounds__(256) void k_gemm128(const bf16* __restrict__ A, const bf16* __restrict__ BT,
                                                 float* __restrict__ Cf, bf16* __restrict__ Cb,
                                                 int M, int N, int K) {
  __shared__ bf16 As[128 * 32];
  __shared__ bf16 Bs[128 * 32];
  const int t = threadIdx.x;
  const int lane = t & 63, w = t >> 6;
  const int wr = w >> 1, wc = w & 1;
  const int g = lane >> 4, r15 = lane & 15;
  const size_t m0 = (size_t)blockIdx.y * 128, n0 = (size_t)blockIdx.x * 128;
  f32x4 acc[4][4] = {};
  const int c0 = t, c1 = t + 256;
  const int ar0 = c0 >> 2, as0 = c0 & 3, ar1 = c1 >> 2, as1 = c1 & 3;
  const bf16* Ab = A + m0 * K;
  const bf16* Bb = BT + n0 * K;
  for (int k0 = 0; k0 < K; k0 += 32) {
    __syncthreads();
    gload16(Ab + (size_t)ar0 * K + k0 + ((as0 ^ (ar0 & 3)) << 3), &As[c0 * 8]);
    gload16(Ab + (size_t)ar1 * K + k0 + ((as1 ^ (ar1 & 3)) << 3), &As[c1 * 8]);
    gload16(Bb + (size_t)ar0 * K + k0 + ((as0 ^ (ar0 & 3)) << 3), &Bs[c0 * 8]);
    gload16(Bb + (size_t)ar1 * K + k0 + ((as1 ^ (ar1 & 3)) << 3), &Bs[c1 * 8]);
    __syncthreads();
    bf16x8 af[4], bfr[4];
    #pragma unroll
    for (int mi = 0; mi < 4; mi++) {
      int row = wr * 64 + mi * 16 + r15;
      af[mi] = *(const bf16x8*)&As[row * 32 + ((g ^ (row & 3)) << 3)];
    }
    #pragma unroll
    for (int ni = 0; ni < 4; ni++) {
      int row = wc * 64 + ni * 16 + r15;
      bfr[ni] = *(const bf16x8*)&Bs[row * 32 + ((g ^ (row & 3)) << 3)];
    }
    #pragma unroll
    for (int mi = 0; mi < 4; mi++)
      #pragma unroll
      for (int ni = 0; ni < 4; ni++)
        acc[mi][ni] = MFMA16(af[mi], bfr[ni], acc[mi][ni]);
  }
  #pragma unroll
  for (int mi = 0; mi < 4; mi++)
    #pragma unroll
    for (int ni = 0; ni < 4; ni++) {
      size_t col = n0 + wc * 64 + ni * 16 + r15;
      #pragma unroll
      for (int rr = 0; rr < 4; rr++) {
        size_t row = m0 + wr * 64 + mi * 16 + g * 4 + rr;
        size_t idx = row * (size_t)N + col;
        float v = acc[mi][ni][rr];
        if (MODE == 0) Cf[idx] = v;
        else Cb[idx] = (bf16)v;
      }
    }
}

// ---------------- flash attention: Q[S,D] x K[Skv,D] x VT[D,Skv] -> O[S,D] ----------------
__global__ __launch_bounds__(256) void k_attn(const bf16* __restrict__ Q, const bf16* __restrict__ Kb,
                                              const bf16* __restrict__ VT, bf16* __restrict__ O,
                                              int Skv) {
  __shared__ bf16 Kt[32 * 128];
  __shared__ bf16 Vt[128 * 32];
  __shared__ bf16 Pt[4][16 * 32];
  const int h = blockIdx.y;
  const int t = threadIdx.x, w = t >> 6, lane = t & 63;
  const int g = lane >> 4, r15 = lane & 15;
  const int q0 = blockIdx.x * 64 + w * 16;
  bf16x8 qf[4];
  #pragma unroll
  for (int c = 0; c < 4; c++)
    qf[c] = *(const bf16x8*)(Q + (size_t)(q0 + r15) * D + h * 128 + c * 32 + g * 8);
  f32x4 o[8] = {};
  float m_[4] = { -1e30f, -1e30f, -1e30f, -1e30f };
  float l_[4] = { 0.f, 0.f, 0.f, 0.f };
  const float scale = 0.08838834764831845f;
  for (int kt = 0; kt < Skv; kt += 32) {
    __syncthreads();
    #pragma unroll
    for (int cc = 0; cc < 2; cc++) {
      int c = t + cc * 256;
      int kr = c >> 4, ks = c & 15;
      gload16(Kb + (size_t)(kt + kr) * D + h * 128 + ((ks ^ (kr & 15)) << 3), &Kt[c * 8]);
      int vr = c >> 2, vs = c & 3;
      gload16(VT + (size_t)(h * 128 + vr) * Skv + kt + ((vs ^ (vr & 3)) << 3), &Vt[c * 8]);
    }
    __syncthreads();
    f32x4 s0 = {}, s1 = {};
    #pragma unroll
    for (int c = 0; c < 4; c++) {
      int row0 = r15, row1 = 16 + r15;
      bf16x8 kf0 = *(const bf16x8*)&Kt[row0 * 128 + (((4 * c + g) ^ (row0 & 15)) << 3)];
      bf16x8 kf1 = *(const bf16x8*)&Kt[row1 * 128 + (((4 * c + g) ^ (row1 & 15)) << 3)];
      s0 = MFMA16(qf[c], kf0, s0);
      s1 = MFMA16(qf[c], kf1, s1);
    }
    float al[4];
    #pragma unroll
    for (int rr = 0; rr < 4; rr++) {
      float v0 = s0[rr] * scale, v1 = s1[rr] * scale;
      float mx = fmaxf(v0, v1);
      #pragma unroll
      for (int off = 1; off < 16; off <<= 1) mx = fmaxf(mx, __shfl_xor(mx, off, 16));
      float mn = fmaxf(m_[rr], mx);
      al[rr] = __expf(m_[rr] - mn);
      float p0 = __expf(v0 - mn), p1 = __expf(v1 - mn);
      float sm = p0 + p1;
      #pragma unroll
      for (int off = 1; off < 16; off <<= 1) sm += __shfl_xor(sm, off, 16);
      l_[rr] = l_[rr] * al[rr] + sm;
      m_[rr] = mn;
      int prow = g * 4 + rr;
      int sl0 = r15 >> 3, sl1 = 2 + (r15 >> 3);
      Pt[w][prow * 32 + ((sl0 ^ (prow & 3)) << 3) + (r15 & 7)] = (bf16)p0;
      Pt[w][prow * 32 + ((sl1 ^ (prow & 3)) << 3) + (r15 & 7)] = (bf16)p1;
    }
    #pragma unroll
    for (int d = 0; d < 8; d++)
      #pragma unroll
      for (int rr = 0; rr < 4; rr++) o[d][rr] *= al[rr];
    bf16x8 pa = *(const bf16x8*)&Pt[w][r15 * 32 + ((g ^ (r15 & 3)) << 3)];
    #pragma unroll
    for (int d = 0; d < 8; d++) {
      int vrow = d * 16 + r15;
      bf16x8 vbf = *(const bf16x8*)&Vt[vrow * 32 + ((g ^ (vrow & 3)) << 3)];
      o[d] = MFMA16(pa, vbf, o[d]);
    }
  }
  #pragma unroll
  for (int rr = 0; rr < 4; rr++) {
    float inv = 1.f / l_[rr];
    #pragma unroll
    for (int d = 0; d < 8; d++)
      O[(size_t)(q0 + g * 4 + rr) * D + h * 128 + d * 16 + r15] = (bf16)(o[d][rr] * inv);
  }
}

extern "C" void kernel_launch(void* const* d_in, const int* in_sizes, int n_in,
                              void* d_out, int out_size, void* d_ws, size_t ws_size,
                              hipStream_t stream) {
  (void)in_sizes; (void)n_in; (void)out_size; (void)ws_size;
  const float* video = (const float*)d_in[0];
  const float* text  = (const float*)d_in[1];
  const float* wq    = (const float*)d_in[2];
  const float* wk    = (const float*)d_in[3];
  const float* wv    = (const float*)d_in[4];
  const float* wo    = (const float*)d_in[5];
  const float* qnw   = (const float*)d_in[6];
  const float* knw   = (const float*)d_in[7];
  const float* cwq   = (const float*)d_in[8];
  const float* cwk   = (const float*)d_in[9];
  const float* cwv   = (const float*)d_in[10];
  const float* cwo   = (const float*)d_in[11];
  const float* cqnw  = (const float*)d_in[12];
  const float* cknw  = (const float*)d_in[13];
  const float* ffp   = (const float*)d_in[14];
  const float* ffd   = (const float*)d_in[15];
  float* out = (float*)d_out;

  // ---- workspace (lifetime-aliased) ----
  // wbuf@0: 268MB transposed weights (DxD phases use 32MB; FFN uses full 268MB for ffp, 134MB for ffd)
  // vb@64MB, vt@96MB, pre@128MB: attn-phase only (dead before FFN transposes)
  // Hval@268MB: 134MB ; tail@402MB
  char* slab = (char*)d_ws;
  const size_t MB = 1024 * 1024;
  bf16*  wbuf  = (bf16*)slab;
  bf16*  vb    = (bf16*)(slab + 64 * MB);
  bf16*  vt    = (bf16*)(slab + 96 * MB);
  float* pre   = (float*)(slab + 128 * MB);
  bf16*  Hval  = (bf16*)(slab + 268 * MB);
  char* p = slab + 402 * MB;
  auto take = [&](size_t bytes) { char* r = p; p += (bytes + 255) & ~(size_t)255; return r; };
  bf16* xb   = (bf16*)take((size_t)S * D * 2);
  bf16* qb   = (bf16*)take((size_t)S * D * 2);
  bf16* kb   = (bf16*)take((size_t)S * D * 2);
  bf16* ab   = (bf16*)take((size_t)S * D * 2);
  float* h1  = (float*)take((size_t)S * D * 4);
  bf16* tbuf = (bf16*)take((size_t)T * D * 2);
  bf16* ckb  = (bf16*)take((size_t)T * D * 2);
  bf16* cvb  = (bf16*)take((size_t)T * D * 2);
  bf16* cvt_ = (bf16*)take((size_t)T * D * 2);
  float* h2  = out;

  dim3 b256(256), b512(512), btc(32, 8);
  // grids: DxD gemm2 = 16x16 panels -> XGM=2,BYG=8,BXG=4 ; geglu2 = 16x128 -> XGM=2,BYG=8,BXG=32
  const int GRID_DD = 256, GRID_GG = 2048;

  // ---- self-attention ----
  k_cvt<<<(S * D) / 1024, b256, 0, stream>>>(video, xb, S * D);
  k_tc<<<dim3(D / 32, D / 32), btc, 0, stream>>>(wq, wbuf, D, D, D);
  k_gemm2<0><<<GRID_DD, b512, 0, stream>>>(xb, wbuf, pre, nullptr, nullptr, S, D, D, 2, 8, 4);
  k_rms<<<S, b256, 0, stream>>>(pre, qnw, qb);
  k_tc<<<dim3(D / 32, D / 32), btc, 0, stream>>>(wk, wbuf, D, D, D);
  k_gemm2<0><<<GRID_DD, b512, 0, stream>>>(xb, wbuf, pre, nullptr, nullptr, S, D, D, 2, 8, 4);
  k_rms<<<S, b256, 0, stream>>>(pre, knw, kb);
  k_tc<<<dim3(D / 32, D / 32), btc, 0, stream>>>(wv, wbuf, D, D, D);
  k_gemm2<1><<<GRID_DD, b512, 0, stream>>>(xb, wbuf, nullptr, vb, nullptr, S, D, D, 2, 8, 4);
  k_tb<<<dim3(D / 32, S / 32), btc, 0, stream>>>(vb, vt, S, D);
  k_attn<<<dim3(S / 64, H), b256, 0, stream>>>(qb, kb, vt, ab, S);
  k_tc<<<dim3(D / 32, D / 32), btc, 0, stream>>>(wo, wbuf, D, D, D);
  k_gemm2<2><<<GRID_DD, b512, 0, stream>>>(ab, wbuf, h1, nullptr, video, S, D, D, 2, 8, 4);

  // ---- cross-attention ----
  k_cvt<<<(S * D) / 1024, b256, 0, stream>>>(h1, xb, S * D);
  k_tc<<<dim3(D / 32, D / 32), btc, 0, stream>>>(cwq, wbuf, D, D, D);
  k_gemm2<0><<<GRID_DD, b512, 0, stream>>>(xb, wbuf, pre, nullptr, nullptr, S, D, D, 2, 8, 4);
  k_rms<<<S, b256, 0, stream>>>(pre, cqnw, qb);
  k_cvt<<<(T * D) / 1024, b256, 0, stream>>>(text, tbuf, T * D);
  k_tc<<<dim3(D / 32, D / 32), btc, 0, stream>>>(cwk, wbuf, D, D, D);
  k_gemm128<0><<<dim3(D / 128, T / 128), b256, 0, stream>>>(tbuf, wbuf, pre, nullptr, T, D, D);
  k_rms<<<T, b256, 0, stream>>>(pre, cknw, ckb);
  k_tc<<<dim3(D / 32, D / 32), btc, 0, stream>>>(cwv, wbuf, D, D, D);
  k_gemm128<1><<<dim3(D / 128, T / 128), b256, 0, stream>>>(tbuf, wbuf, nullptr, cvb, T, D, D);
  k_tb<<<dim3(D / 32, T / 32), btc, 0, stream>>>(cvb, cvt_, T, D);
  k_attn<<<dim3(S / 64, H), b256, 0, stream>>>(qb, ckb, cvt_, ab, T);
  k_tc<<<dim3(D / 32, D / 32), btc, 0, stream>>>(cwo, wbuf, D, D, D);
  k_gemm2<2><<<GRID_DD, b512, 0, stream>>>(ab, wbuf, h2, nullptr, h1, S, D, D, 2, 8, 4);

  // ---- GEGLU FFN (fused val+gate) ----
  k_cvt<<<(S * D) / 1024, b256, 0, stream>>>(h2, xb, S * D);
  k_tc<<<dim3((2 * F) / 32, D / 32), btc, 0, stream>>>(ffp, wbuf, D, 2 * F, 2 * F);
  k_geglu2<<<GRID_GG, b512, 0, stream>>>(xb, wbuf, Hval, F, D, 2, 8, 32);
  k_tc<<<dim3(D / 32, F / 32), btc, 0, stream>>>(ffd, wbuf, F, D, D);
  k_gemm2<2><<<GRID_DD, b512, 0, stream>>>(Hval, wbuf, out, nullptr, h2, S, D, F, 2, 8, 4);
}

// Round 6
// 4406.525 us; speedup vs baseline: 1.3932x; 1.1094x over previous
//
#include <hip/hip_runtime.h>
#include <cstdint>
#include <cstddef>

typedef __bf16 bf16;
typedef __bf16 bf16x8 __attribute__((ext_vector_type(8)));
typedef __bf16 bf16x4 __attribute__((ext_vector_type(4)));
typedef float f32x4 __attribute__((ext_vector_type(4)));

static constexpr int D = 4096;
static constexpr int S = 4096;
static constexpr int T = 256;
static constexpr int H = 32;
static constexpr int F = 16384;

__device__ __forceinline__ void gload16(const void* g, void* l) {
  __builtin_amdgcn_global_load_lds((const __attribute__((address_space(1))) void*)g,
                                   (__attribute__((address_space(3))) void*)l, 16, 0, 0);
}

#define MFMA16(a, b, c) __builtin_amdgcn_mfma_f32_16x16x32_bf16((a), (b), (c), 0, 0, 0)

// ---------------- elementwise f32 -> bf16 ----------------
__global__ __launch_bounds__(256) void k_cvt(const float* __restrict__ in, bf16* __restrict__ out, int n) {
  int i = (blockIdx.x * 256 + threadIdx.x) * 4;
  if (i >= n) return;
  float4 v = *(const float4*)(in + i);
  bf16x4 o = { (bf16)v.x, (bf16)v.y, (bf16)v.z, (bf16)v.w };
  *(bf16x4*)(out + i) = o;
}

// ---------------- transpose+cvt: f32 [R][C] (row stride ldin) -> bf16 [C][R] ----------------
__global__ __launch_bounds__(256) void k_tc(const float* __restrict__ in, bf16* __restrict__ out,
                                            int R, int C, int ldin) {
  __shared__ float tile[32][33];
  int c0 = blockIdx.x * 32, r0 = blockIdx.y * 32;
  int x = threadIdx.x, y = threadIdx.y;
  #pragma unroll
  for (int yy = y; yy < 32; yy += 8)
    tile[yy][x] = in[(size_t)(r0 + yy) * ldin + c0 + x];
  __syncthreads();
  #pragma unroll
  for (int yy = y; yy < 32; yy += 8)
    out[(size_t)(c0 + yy) * R + r0 + x] = (bf16)tile[x][yy];
}

// ---------------- transpose bf16 [R][C] -> [C][R] ----------------
__global__ __launch_bounds__(256) void k_tb(const bf16* __restrict__ in, bf16* __restrict__ out, int R, int C) {
  __shared__ bf16 tile[32][33];
  int c0 = blockIdx.x * 32, r0 = blockIdx.y * 32;
  int x = threadIdx.x, y = threadIdx.y;
  #pragma unroll
  for (int yy = y; yy < 32; yy += 8)
    tile[yy][x] = in[(size_t)(r0 + yy) * C + c0 + x];
  __syncthreads();
  #pragma unroll
  for (int yy = y; yy < 32; yy += 8)
    out[(size_t)(c0 + yy) * R + r0 + x] = tile[x][yy];
}

// ---------------- rmsnorm over 4096, f32 in -> bf16 out ----------------
__global__ __launch_bounds__(256) void k_rms(const float* __restrict__ in, const float* __restrict__ w,
                                             bf16* __restrict__ out) {
  const int row = blockIdx.x, t = threadIdx.x;
  const float* x = in + (size_t)row * 4096;
  float4 v[4];
  float ss = 0.f;
  #pragma unroll
  for (int i = 0; i < 4; i++) {
    v[i] = *(const float4*)(x + t * 4 + i * 1024);
    ss += v[i].x * v[i].x + v[i].y * v[i].y + v[i].z * v[i].z + v[i].w * v[i].w;
  }
  #pragma unroll
  for (int off = 1; off < 64; off <<= 1) ss += __shfl_xor(ss, off, 64);
  __shared__ float red[4];
  if ((t & 63) == 0) red[t >> 6] = ss;
  __syncthreads();
  float rms = rsqrtf((red[0] + red[1] + red[2] + red[3]) * (1.f / 4096.f) + 1e-6f);
  #pragma unroll
  for (int i = 0; i < 4; i++) {
    const float4 wv = *(const float4*)(w + t * 4 + i * 1024);
    bf16x4 ov = { (bf16)(v[i].x * rms * wv.x), (bf16)(v[i].y * rms * wv.y),
                  (bf16)(v[i].z * rms * wv.z), (bf16)(v[i].w * rms * wv.w) };
    *(bf16x4*)(out + (size_t)row * 4096 + t * 4 + i * 1024) = ov;
  }
}

// supertile XCD mapping (bijective): by = (xcd%XGM)*BYG + oidx%BYG ; bx = (xcd/XGM)*BXG + oidx/BYG
__device__ __forceinline__ void xcd_map(int orig, int XGM, int BYG, int BXG, int& by, int& bx) {
  const int xcd = orig & 7, oidx = orig >> 3;
  by = (xcd % XGM) * BYG + oidx % BYG;
  bx = (xcd / XGM) * BXG + oidx / BYG;
}

// ================= 256x256 single-barrier 4-phase GEMM: C[M,N] = A[M,K] @ BT[N,K] =================
// 8 waves (2Mx4N), BK=64 kh-panels [256][32]; staging 2 tiles deep, one vmcnt(6) + 4 barriers per
// K-tile. Phase = {stage; ds_reads; barrier; MFMA} -> reads of phase p+1 overlap MFMA of phase p.
// MODE 0: f32 out; 1: bf16 out; 2: f32 out + f32 residual
template <int MODE>
__global__ __launch_bounds__(512, 2) void k_gemm2(const bf16* __restrict__ A, const bf16* __restrict__ BT,
                                                  float* __restrict__ Cf, bf16* __restrict__ Cb,
                                                  const float* __restrict__ res,
                                                  int M, int N, int K, int XGM, int BYG, int BXG) {
  __shared__ bf16 LA[2][2][256 * 32];  // [dbuf][kh][row*32+col]
  __shared__ bf16 LB[2][2][256 * 32];
  int by, bx;
  xcd_map(blockIdx.x, XGM, BYG, BXG, by, bx);
  const size_t m0 = (size_t)by * 256, n0 = (size_t)bx * 256;
  const int t = threadIdx.x;
  const int w = t >> 6, lane = t & 63;
  const int wm = w >> 2, wn = w & 3;
  const int g = lane >> 4, r15 = lane & 15;
  const int nt = K >> 6;
  const int sr0 = t >> 2, ss0 = t & 3;
  const int sr1 = (t + 512) >> 2, ss1 = (t + 512) & 3;
  const int sc0 = ((ss0 ^ ((sr0 >> 1) & 3)) << 3);
  const int sc1 = ((ss1 ^ ((sr1 >> 1) & 3)) << 3);
  f32x4 acc[8][4] = {};

  auto stA = [&](int db, int kh, int st) {
    const bf16* src = A + m0 * K + (size_t)st * 64 + kh * 32;
    gload16(src + (size_t)sr0 * K + sc0, &LA[db][kh][t * 8]);
    gload16(src + (size_t)sr1 * K + sc1, &LA[db][kh][(t + 512) * 8]);
  };
  auto stB = [&](int db, int kh, int st) {
    const bf16* src = BT + n0 * K + (size_t)st * 64 + kh * 32;
    gload16(src + (size_t)sr0 * K + sc0, &LB[db][kh][t * 8]);
    gload16(src + (size_t)sr1 * K + sc1, &LB[db][kh][(t + 512) * 8]);
  };

  // prologue: T0 all 4 panels + T1 {A0,B0,A1} = 14 loads/thread
  stA(0, 0, 0); stB(0, 0, 0); stA(0, 1, 0); stB(0, 1, 0);
  stA(1, 0, 1); stB(1, 0, 1); stA(1, 1, 1);
  asm volatile("s_waitcnt vmcnt(6)" ::: "memory");  // T0 fully landed; T1's 6 in flight
  __builtin_amdgcn_s_barrier();

  const int arow = wm * 128;
  for (int tt = 0; tt < nt; ++tt) {
    const int d = tt & 1, e = d ^ 1;
    const int t1 = (tt + 1 < nt) ? tt + 1 : nt - 1;
    const int t2 = (tt + 2 < nt) ? tt + 2 : nt - 1;
    bf16x8 af[8], b0, b1;

    // ---- phase 0: kh=0, nh=0 ----
    stB(e, 1, t1);  // e:B-kh1 last read tile-1 p3
    #pragma unroll
    for (int mf = 0; mf < 8; ++mf) {
      const int rr = arow + mf * 16 + r15;
      af[mf] = *(const bf16x8*)&LA[d][0][rr * 32 + ((g ^ ((rr >> 1) & 3)) << 3)];
    }
    {
      const int rb0 = wn * 64 + r15, rb1 = wn * 64 + 16 + r15;
      b0 = *(const bf16x8*)&LB[d][0][rb0 * 32 + ((g ^ ((rb0 >> 1) & 3)) << 3)];
      b1 = *(const bf16x8*)&LB[d][0][rb1 * 32 + ((g ^ ((rb1 >> 1) & 3)) << 3)];
    }
    __builtin_amdgcn_s_barrier();
    __builtin_amdgcn_sched_barrier(0);
    __builtin_amdgcn_s_setprio(1);
    #pragma unroll
    for (int mf = 0; mf < 8; ++mf) {
      acc[mf][0] = MFMA16(af[mf], b0, acc[mf][0]);
      acc[mf][1] = MFMA16(af[mf], b1, acc[mf][1]);
    }
    __builtin_amdgcn_s_setprio(0);

    // ---- phase 1: kh=0, nh=1 (A regs reused) ----
    stA(d, 0, t2);  // d:A-kh0 last read p0
    {
      const int rb0 = wn * 64 + 32 + r15, rb1 = wn * 64 + 48 + r15;
      b0 = *(const bf16x8*)&LB[d][0][rb0 * 32 + ((g ^ ((rb0 >> 1) & 3)) << 3)];
      b1 = *(const bf16x8*)&LB[d][0][rb1 * 32 + ((g ^ ((rb1 >> 1) & 3)) << 3)];
    }
    __builtin_amdgcn_s_barrier();
    __builtin_amdgcn_sched_barrier(0);
    __builtin_amdgcn_s_setprio(1);
    #pragma unroll
    for (int mf = 0; mf < 8; ++mf) {
      acc[mf][2] = MFMA16(af[mf], b0, acc[mf][2]);
      acc[mf][3] = MFMA16(af[mf], b1, acc[mf][3]);
    }
    __builtin_amdgcn_s_setprio(0);

    // ---- phase 2: kh=1, nh=0 ----
    stB(d, 0, t2);  // d:B-kh0 last read p1
    #pragma unroll
    for (int mf = 0; mf < 8; ++mf) {
      const int rr = arow + mf * 16 + r15;
      af[mf] = *(const bf16x8*)&LA[d][1][rr * 32 + ((g ^ ((rr >> 1) & 3)) << 3)];
    }
    {
      const int rb0 = wn * 64 + r15, rb1 = wn * 64 + 16 + r15;
      b0 = *(const bf16x8*)&LB[d][1][rb0 * 32 + ((g ^ ((rb0 >> 1) & 3)) << 3)];
      b1 = *(const bf16x8*)&LB[d][1][rb1 * 32 + ((g ^ ((rb1 >> 1) & 3)) << 3)];
    }
    __builtin_amdgcn_s_barrier();
    __builtin_amdgcn_sched_barrier(0);
    __builtin_amdgcn_s_setprio(1);
    #pragma unroll
    for (int mf = 0; mf < 8; ++mf) {
      acc[mf][0] = MFMA16(af[mf], b0, acc[mf][0]);
      acc[mf][1] = MFMA16(af[mf], b1, acc[mf][1]);
    }
    __builtin_amdgcn_s_setprio(0);

    // ---- phase 3: kh=1, nh=1 (A regs reused) ----
    stA(d, 1, t2);  // d:A-kh1 last read p2
    {
      const int rb0 = wn * 64 + 32 + r15, rb1 = wn * 64 + 48 + r15;
      b0 = *(const bf16x8*)&LB[d][1][rb0 * 32 + ((g ^ ((rb0 >> 1) & 3)) << 3)];
      b1 = *(const bf16x8*)&LB[d][1][rb1 * 32 + ((g ^ ((rb1 >> 1) & 3)) << 3)];
    }
    asm volatile("s_waitcnt vmcnt(6)" ::: "memory");  // drain T(tt+1)'s 8; keep T(tt+2)'s 6 flying
    __builtin_amdgcn_s_barrier();
    __builtin_amdgcn_sched_barrier(0);
    __builtin_amdgcn_s_setprio(1);
    #pragma unroll
    for (int mf = 0; mf < 8; ++mf) {
      acc[mf][2] = MFMA16(af[mf], b0, acc[mf][2]);
      acc[mf][3] = MFMA16(af[mf], b1, acc[mf][3]);
    }
    __builtin_amdgcn_s_setprio(0);
  }

  #pragma unroll
  for (int mf = 0; mf < 8; ++mf)
    #pragma unroll
    for (int nf = 0; nf < 4; ++nf) {
      const size_t col = n0 + wn * 64 + nf * 16 + r15;
      #pragma unroll
      for (int rr = 0; rr < 4; ++rr) {
        const size_t row = m0 + wm * 128 + mf * 16 + g * 4 + rr;
        const size_t idx = row * (size_t)N + col;
        const float v = acc[mf][nf][rr];
        if (MODE == 0) Cf[idx] = v;
        else if (MODE == 1) Cb[idx] = (bf16)v;
        else Cf[idx] = v + res[idx];
      }
    }
}

// ================= fused GEGLU GEMM: G[M,N] = (A@BTv) * gelu(A@BTg), tile 256x128 =================
__global__ __launch_bounds__(512, 2) void k_geglu2(const bf16* __restrict__ A, const bf16* __restrict__ BT,
                                                   bf16* __restrict__ G, int N, int K,
                                                   int XGM, int BYG, int BXG) {
  __shared__ bf16 LA[2][2][256 * 32];
  __shared__ bf16 LBv[2][2][128 * 32];
  __shared__ bf16 LBg[2][2][128 * 32];
  int by, bx;
  xcd_map(blockIdx.x, XGM, BYG, BXG, by, bx);
  const size_t m0 = (size_t)by * 256, n0 = (size_t)bx * 128;
  const int t = threadIdx.x;
  const int w = t >> 6, lane = t & 63;
  const int wm = w >> 2, wn = w & 3;
  const int g = lane >> 4, r15 = lane & 15;
  const int nt = K >> 6;
  const int sr0 = t >> 2, ss0 = t & 3;
  const int sr1 = (t + 512) >> 2, ss1 = (t + 512) & 3;
  const int sc0 = ((ss0 ^ ((sr0 >> 1) & 3)) << 3);
  const int sc1 = ((ss1 ^ ((sr1 >> 1) & 3)) << 3);
  f32x4 av[8][2] = {}, ag[8][2] = {};

  auto stA = [&](int db, int kh, int st) {
    const bf16* src = A + m0 * K + (size_t)st * 64 + kh * 32;
    gload16(src + (size_t)sr0 * K + sc0, &LA[db][kh][t * 8]);
    gload16(src + (size_t)sr1 * K + sc1, &LA[db][kh][(t + 512) * 8]);
  };
  auto stBv = [&](int db, int kh, int st) {
    const bf16* src = BT + n0 * K + (size_t)st * 64 + kh * 32;
    gload16(src + (size_t)sr0 * K + sc0, &LBv[db][kh][t * 8]);
  };
  auto stBg = [&](int db, int kh, int st) {
    const bf16* src = BT + ((size_t)N + n0) * K + (size_t)st * 64 + kh * 32;
    gload16(src + (size_t)sr0 * K + sc0, &LBg[db][kh][t * 8]);
  };

  // prologue: T0 all 6 panels (8 loads) + T1 {A0,Bv0,Bg0,A1} (6 loads)
  stA(0, 0, 0); stBv(0, 0, 0); stBg(0, 0, 0); stA(0, 1, 0); stBv(0, 1, 0); stBg(0, 1, 0);
  stA(1, 0, 1); stBv(1, 0, 1); stBg(1, 0, 1); stA(1, 1, 1);
  asm volatile("s_waitcnt vmcnt(6)" ::: "memory");
  __builtin_amdgcn_s_barrier();

  const int arow = wm * 128;
  for (int tt = 0; tt < nt; ++tt) {
    const int d = tt & 1, e = d ^ 1;
    const int t1 = (tt + 1 < nt) ? tt + 1 : nt - 1;
    const int t2 = (tt + 2 < nt) ? tt + 2 : nt - 1;
    bf16x8 af[8], b0, b1;

    // ---- phase 0: kh=0, val ----
    stBv(e, 1, t1); stBg(e, 1, t1);
    #pragma unroll
    for (int mf = 0; mf < 8; ++mf) {
      const int rr = arow + mf * 16 + r15;
      af[mf] = *(const bf16x8*)&LA[d][0][rr * 32 + ((g ^ ((rr >> 1) & 3)) << 3)];
    }
    {
      const int rb0 = wn * 32 + r15, rb1 = wn * 32 + 16 + r15;
      b0 = *(const bf16x8*)&LBv[d][0][rb0 * 32 + ((g ^ ((rb0 >> 1) & 3)) << 3)];
      b1 = *(const bf16x8*)&LBv[d][0][rb1 * 32 + ((g ^ ((rb1 >> 1) & 3)) << 3)];
    }
    __builtin_amdgcn_s_barrier();
    __builtin_amdgcn_sched_barrier(0);
    __builtin_amdgcn_s_setprio(1);
    #pragma unroll
    for (int mf = 0; mf < 8; ++mf) {
      av[mf][0] = MFMA16(af[mf], b0, av[mf][0]);
      av[mf][1] = MFMA16(af[mf], b1, av[mf][1]);
    }
    __builtin_amdgcn_s_setprio(0);

    // ---- phase 1: kh=0, gate (A regs reused) ----
    stA(d, 0, t2);
    {
      const int rb0 = wn * 32 + r15, rb1 = wn * 32 + 16 + r15;
      b0 = *(const bf16x8*)&LBg[d][0][rb0 * 32 + ((g ^ ((rb0 >> 1) & 3)) << 3)];
      b1 = *(const bf16x8*)&LBg[d][0][rb1 * 32 + ((g ^ ((rb1 >> 1) & 3)) << 3)];
    }
    __builtin_amdgcn_s_barrier();
    __builtin_amdgcn_sched_barrier(0);
    __builtin_amdgcn_s_setprio(1);
    #pragma unroll
    for (int mf = 0; mf < 8; ++mf) {
      ag[mf][0] = MFMA16(af[mf], b0, ag[mf][0]);
      ag[mf][1] = MFMA16(af[mf], b1, ag[mf][1]);
    }
    __builtin_amdgcn_s_setprio(0);

    // ---- phase 2: kh=1, val ----
    stBv(d, 0, t2); stBg(d, 0, t2);
    #pragma unroll
    for (int mf = 0; mf < 8; ++mf) {
      const int rr = arow + mf * 16 + r15;
      af[mf] = *(const bf16x8*)&LA[d][1][rr * 32 + ((g ^ ((rr >> 1) & 3)) << 3)];
    }
    {
      const int rb0 = wn * 32 + r15, rb1 = wn * 32 + 16 + r15;
      b0 = *(const bf16x8*)&LBv[d][1][rb0 * 32 + ((g ^ ((rb0 >> 1) & 3)) << 3)];
      b1 = *(const bf16x8*)&LBv[d][1][rb1 * 32 + ((g ^ ((rb1 >> 1) & 3)) << 3)];
    }
    __builtin_amdgcn_s_barrier();
    __builtin_amdgcn_sched_barrier(0);
    __builtin_amdgcn_s_setprio(1);
    #pragma unroll
    for (int mf = 0; mf < 8; ++mf) {
      av[mf][0] = MFMA16(af[mf], b0, av[mf][0]);
      av[mf][1] = MFMA16(af[mf], b1, av[mf][1]);
    }
    __builtin_amdgcn_s_setprio(0);

    // ---- phase 3: kh=1, gate ----
    stA(d, 1, t2);
    {
      const int rb0 = wn * 32 + r15, rb1 = wn * 32 + 16 + r15;
      b0 = *(const bf16x8*)&LBg[d][1][rb0 * 32 + ((g ^ ((rb0 >> 1) & 3)) << 3)];
      b1 = *(const bf16x8*)&LBg[d][1][rb1 * 32 + ((g ^ ((rb1 >> 1) & 3)) << 3)];
    }
    asm volatile("s_waitcnt vmcnt(6)" ::: "memory");
    __builtin_amdgcn_s_barrier();
    __builtin_amdgcn_sched_barrier(0);
    __builtin_amdgcn_s_setprio(1);
    #pragma unroll
    for (int mf = 0; mf < 8; ++mf) {
      ag[mf][0] = MFMA16(af[mf], b0, ag[mf][0]);
      ag[mf][1] = MFMA16(af[mf], b1, ag[mf][1]);
    }
    __builtin_amdgcn_s_setprio(0);
  }

  #pragma unroll
  for (int mf = 0; mf < 8; ++mf)
    #pragma unroll
    for (int nf = 0; nf < 2; ++nf) {
      const size_t col = n0 + wn * 32 + nf * 16 + r15;
      #pragma unroll
      for (int rr = 0; rr < 4; ++rr) {
        const size_t row = m0 + wm * 128 + mf * 16 + g * 4 + rr;
        const float val = av[mf][nf][rr], gt = ag[mf][nf][rr];
        const float z = 1.595769122f * gt + 0.0713548162f * gt * gt * gt;
        const float gel = gt / (1.f + __expf(-z));
        G[row * (size_t)N + col] = (bf16)(val * gel);
      }
    }
}

// ---------------- 128x128 GEMM (m97 structure) for M=256 cases ----------------
template <int MODE>
__global__ __launch_bounds__(256) void k_gemm128(const bf16* __restrict__ A, const bf16* __restrict__ BT,
                                                 float* __restrict__ Cf, bf16* __restrict__ Cb,
                                                 int M, int N, int K) {
  __shared__ bf16 As[128 * 32];
  __shared__ bf16 Bs[128 * 32];
  const int t = threadIdx.x;
  const int lane = t & 63, w = t >> 6;
  const int wr = w >> 1, wc = w & 1;
  const int g = lane >> 4, r15 = lane & 15;
  const size_t m0 = (size_t)blockIdx.y * 128, n0 = (size_t)blockIdx.x * 128;
  f32x4 acc[4][4] = {};
  const int c0 = t, c1 = t + 256;
  const int ar0 = c0 >> 2, as0 = c0 & 3, ar1 = c1 >> 2, as1 = c1 & 3;
  const bf16* Ab = A + m0 * K;
  const bf16* Bb = BT + n0 * K;
  for (int k0 = 0; k0 < K; k0 += 32) {
    __syncthreads();
    gload16(Ab + (size_t)ar0 * K + k0 + ((as0 ^ (ar0 & 3)) << 3), &As[c0 * 8]);
    gload16(Ab + (size_t)ar1 * K + k0 + ((as1 ^ (ar1 & 3)) << 3), &As[c1 * 8]);
    gload16(Bb + (size_t)ar0 * K + k0 + ((as0 ^ (ar0 & 3)) << 3), &Bs[c0 * 8]);
    gload16(Bb + (size_t)ar1 * K + k0 + ((as1 ^ (ar1 & 3)) << 3), &Bs[c1 * 8]);
    __syncthreads();
    bf16x8 af[4], bfr[4];
    #pragma unroll
    for (int mi = 0; mi < 4; mi++) {
      int row = wr * 64 + mi * 16 + r15;
      af[mi] = *(const bf16x8*)&As[row * 32 + ((g ^ (row & 3)) << 3)];
    }
    #pragma unroll
    for (int ni = 0; ni < 4; ni++) {
      int row = wc * 64 + ni * 16 + r15;
      bfr[ni] = *(const bf16x8*)&Bs[row * 32 + ((g ^ (row & 3)) << 3)];
    }
    #pragma unroll
    for (int mi = 0; mi < 4; mi++)
      #pragma unroll
      for (int ni = 0; ni < 4; ni++)
        acc[mi][ni] = MFMA16(af[mi], bfr[ni], acc[mi][ni]);
  }
  #pragma unroll
  for (int mi = 0; mi < 4; mi++)
    #pragma unroll
    for (int ni = 0; ni < 4; ni++) {
      size_t col = n0 + wc * 64 + ni * 16 + r15;
      #pragma unroll
      for (int rr = 0; rr < 4; rr++) {
        size_t row = m0 + wr * 64 + mi * 16 + g * 4 + rr;
        size_t idx = row * (size_t)N + col;
        float v = acc[mi][ni][rr];
        if (MODE == 0) Cf[idx] = v;
        else Cb[idx] = (bf16)v;
      }
    }
}

// ---------------- flash attention: Q[S,D] x K[Skv,D] x VT[D,Skv] -> O[S,D] ----------------
__global__ __launch_bounds__(256) void k_attn(const bf16* __restrict__ Q, const bf16* __restrict__ Kb,
                                              const bf16* __restrict__ VT, bf16* __restrict__ O,
                                              int Skv) {
  __shared__ bf16 Kt[32 * 128];
  __shared__ bf16 Vt[128 * 32];
  __shared__ bf16 Pt[4][16 * 32];
  const int h = blockIdx.y;
  const int t = threadIdx.x, w = t >> 6, lane = t & 63;
  const int g = lane >> 4, r15 = lane & 15;
  const int q0 = blockIdx.x * 64 + w * 16;
  bf16x8 qf[4];
  #pragma unroll
  for (int c = 0; c < 4; c++)
    qf[c] = *(const bf16x8*)(Q + (size_t)(q0 + r15) * D + h * 128 + c * 32 + g * 8);
  f32x4 o[8] = {};
  float m_[4] = { -1e30f, -1e30f, -1e30f, -1e30f };
  float l_[4] = { 0.f, 0.f, 0.f, 0.f };
  const float scale = 0.08838834764831845f;
  for (int kt = 0; kt < Skv; kt += 32) {
    __syncthreads();
    #pragma unroll
    for (int cc = 0; cc < 2; cc++) {
      int c = t + cc * 256;
      int kr = c >> 4, ks = c & 15;
      gload16(Kb + (size_t)(kt + kr) * D + h * 128 + ((ks ^ (kr & 15)) << 3), &Kt[c * 8]);
      int vr = c >> 2, vs = c & 3;
      gload16(VT + (size_t)(h * 128 + vr) * Skv + kt + ((vs ^ (vr & 3)) << 3), &Vt[c * 8]);
    }
    __syncthreads();
    f32x4 s0 = {}, s1 = {};
    #pragma unroll
    for (int c = 0; c < 4; c++) {
      int row0 = r15, row1 = 16 + r15;
      bf16x8 kf0 = *(const bf16x8*)&Kt[row0 * 128 + (((4 * c + g) ^ (row0 & 15)) << 3)];
      bf16x8 kf1 = *(const bf16x8*)&Kt[row1 * 128 + (((4 * c + g) ^ (row1 & 15)) << 3)];
      s0 = MFMA16(qf[c], kf0, s0);
      s1 = MFMA16(qf[c], kf1, s1);
    }
    float al[4];
    #pragma unroll
    for (int rr = 0; rr < 4; rr++) {
      float v0 = s0[rr] * scale, v1 = s1[rr] * scale;
      float mx = fmaxf(v0, v1);
      #pragma unroll
      for (int off = 1; off < 16; off <<= 1) mx = fmaxf(mx, __shfl_xor(mx, off, 16));
      float mn = fmaxf(m_[rr], mx);
      al[rr] = __expf(m_[rr] - mn);
      float p0 = __expf(v0 - mn), p1 = __expf(v1 - mn);
      float sm = p0 + p1;
      #pragma unroll
      for (int off = 1; off < 16; off <<= 1) sm += __shfl_xor(sm, off, 16);
      l_[rr] = l_[rr] * al[rr] + sm;
      m_[rr] = mn;
      int prow = g * 4 + rr;
      int sl0 = r15 >> 3, sl1 = 2 + (r15 >> 3);
      Pt[w][prow * 32 + ((sl0 ^ (prow & 3)) << 3) + (r15 & 7)] = (bf16)p0;
      Pt[w][prow * 32 + ((sl1 ^ (prow & 3)) << 3) + (r15 & 7)] = (bf16)p1;
    }
    #pragma unroll
    for (int d = 0; d < 8; d++)
      #pragma unroll
      for (int rr = 0; rr < 4; rr++) o[d][rr] *= al[rr];
    bf16x8 pa = *(const bf16x8*)&Pt[w][r15 * 32 + ((g ^ (r15 & 3)) << 3)];
    #pragma unroll
    for (int d = 0; d < 8; d++) {
      int vrow = d * 16 + r15;
      bf16x8 vbf = *(const bf16x8*)&Vt[vrow * 32 + ((g ^ (vrow & 3)) << 3)];
      o[d] = MFMA16(pa, vbf, o[d]);
    }
  }
  #pragma unroll
  for (int rr = 0; rr < 4; rr++) {
    float inv = 1.f / l_[rr];
    #pragma unroll
    for (int d = 0; d < 8; d++)
      O[(size_t)(q0 + g * 4 + rr) * D + h * 128 + d * 16 + r15] = (bf16)(o[d][rr] * inv);
  }
}

extern "C" void kernel_launch(void* const* d_in, const int* in_sizes, int n_in,
                              void* d_out, int out_size, void* d_ws, size_t ws_size,
                              hipStream_t stream) {
  (void)in_sizes; (void)n_in; (void)out_size; (void)ws_size;
  const float* video = (const float*)d_in[0];
  const float* text  = (const float*)d_in[1];
  const float* wq    = (const float*)d_in[2];
  const float* wk    = (const float*)d_in[3];
  const float* wv    = (const float*)d_in[4];
  const float* wo    = (const float*)d_in[5];
  const float* qnw   = (const float*)d_in[6];
  const float* knw   = (const float*)d_in[7];
  const float* cwq   = (const float*)d_in[8];
  const float* cwk   = (const float*)d_in[9];
  const float* cwv   = (const float*)d_in[10];
  const float* cwo   = (const float*)d_in[11];
  const float* cqnw  = (const float*)d_in[12];
  const float* cknw  = (const float*)d_in[13];
  const float* ffp   = (const float*)d_in[14];
  const float* ffd   = (const float*)d_in[15];
  float* out = (float*)d_out;

  char* slab = (char*)d_ws;
  const size_t MB = 1024 * 1024;
  bf16*  wbuf  = (bf16*)slab;
  bf16*  vb    = (bf16*)(slab + 64 * MB);
  bf16*  vt    = (bf16*)(slab + 96 * MB);
  float* pre   = (float*)(slab + 128 * MB);
  bf16*  Hval  = (bf16*)(slab + 268 * MB);
  char* p = slab + 402 * MB;
  auto take = [&](size_t bytes) { char* r = p; p += (bytes + 255) & ~(size_t)255; return r; };
  bf16* xb   = (bf16*)take((size_t)S * D * 2);
  bf16* qb   = (bf16*)take((size_t)S * D * 2);
  bf16* kb   = (bf16*)take((size_t)S * D * 2);
  bf16* ab   = (bf16*)take((size_t)S * D * 2);
  float* h1  = (float*)take((size_t)S * D * 4);
  bf16* tbuf = (bf16*)take((size_t)T * D * 2);
  bf16* ckb  = (bf16*)take((size_t)T * D * 2);
  bf16* cvb  = (bf16*)take((size_t)T * D * 2);
  bf16* cvt_ = (bf16*)take((size_t)T * D * 2);
  float* h2  = out;

  dim3 b256(256), b512(512), btc(32, 8);
  const int GRID_DD = 256, GRID_GG = 2048;

  // ---- self-attention ----
  k_cvt<<<(S * D) / 1024, b256, 0, stream>>>(video, xb, S * D);
  k_tc<<<dim3(D / 32, D / 32), btc, 0, stream>>>(wq, wbuf, D, D, D);
  k_gemm2<0><<<GRID_DD, b512, 0, stream>>>(xb, wbuf, pre, nullptr, nullptr, S, D, D, 2, 8, 4);
  k_rms<<<S, b256, 0, stream>>>(pre, qnw, qb);
  k_tc<<<dim3(D / 32, D / 32), btc, 0, stream>>>(wk, wbuf, D, D, D);
  k_gemm2<0><<<GRID_DD, b512, 0, stream>>>(xb, wbuf, pre, nullptr, nullptr, S, D, D, 2, 8, 4);
  k_rms<<<S, b256, 0, stream>>>(pre, knw, kb);
  k_tc<<<dim3(D / 32, D / 32), btc, 0, stream>>>(wv, wbuf, D, D, D);
  k_gemm2<1><<<GRID_DD, b512, 0, stream>>>(xb, wbuf, nullptr, vb, nullptr, S, D, D, 2, 8, 4);
  k_tb<<<dim3(D / 32, S / 32), btc, 0, stream>>>(vb, vt, S, D);
  k_attn<<<dim3(S / 64, H), b256, 0, stream>>>(qb, kb, vt, ab, S);
  k_tc<<<dim3(D / 32, D / 32), btc, 0, stream>>>(wo, wbuf, D, D, D);
  k_gemm2<2><<<GRID_DD, b512, 0, stream>>>(ab, wbuf, h1, nullptr, video, S, D, D, 2, 8, 4);

  // ---- cross-attention ----
  k_cvt<<<(S * D) / 1024, b256, 0, stream>>>(h1, xb, S * D);
  k_tc<<<dim3(D / 32, D / 32), btc, 0, stream>>>(cwq, wbuf, D, D, D);
  k_gemm2<0><<<GRID_DD, b512, 0, stream>>>(xb, wbuf, pre, nullptr, nullptr, S, D, D, 2, 8, 4);
  k_rms<<<S, b256, 0, stream>>>(pre, cqnw, qb);
  k_cvt<<<(T * D) / 1024, b256, 0, stream>>>(text, tbuf, T * D);
  k_tc<<<dim3(D / 32, D / 32), btc, 0, stream>>>(cwk, wbuf, D, D, D);
  k_gemm128<0><<<dim3(D / 128, T / 128), b256, 0, stream>>>(tbuf, wbuf, pre, nullptr, T, D, D);
  k_rms<<<T, b256, 0, stream>>>(pre, cknw, ckb);
  k_tc<<<dim3(D / 32, D / 32), btc, 0, stream>>>(cwv, wbuf, D, D, D);
  k_gemm128<1><<<dim3(D / 128, T / 128), b256, 0, stream>>>(tbuf, wbuf, nullptr, cvb, T, D, D);
  k_tb<<<dim3(D / 32, T / 32), btc, 0, stream>>>(cvb, cvt_, T, D);
  k_attn<<<dim3(S / 64, H), b256, 0, stream>>>(qb, ckb, cvt_, ab, T);
  k_tc<<<dim3(D / 32, D / 32), btc, 0, stream>>>(cwo, wbuf, D, D, D);
  k_gemm2<2><<<GRID_DD, b512, 0, stream>>>(ab, wbuf, h2, nullptr, h1, S, D, D, 2, 8, 4);

  // ---- GEGLU FFN (fused val+gate) ----
  k_cvt<<<(S * D) / 1024, b256, 0, stream>>>(h2, xb, S * D);
  k_tc<<<dim3((2 * F) / 32, D / 32), btc, 0, stream>>>(ffp, wbuf, D, 2 * F, 2 * F);
  k_geglu2<<<GRID_GG, b512, 0, stream>>>(xb, wbuf, Hval, F, D, 2, 8, 32);
  k_tc<<<dim3(D / 32, F / 32), btc, 0, stream>>>(ffd, wbuf, F, D, D);
  k_gemm2<2><<<GRID_DD, b512, 0, stream>>>(Hval, wbuf, out, nullptr, h2, S, D, F, 2, 8, 4);
}

// Round 7
// 4050.984 us; speedup vs baseline: 1.5154x; 1.0878x over previous
//
#include <hip/hip_runtime.h>
#include <cstdint>
#include <cstddef>

typedef __bf16 bf16;
typedef __bf16 bf16x8 __attribute__((ext_vector_type(8)));
typedef __bf16 bf16x4 __attribute__((ext_vector_type(4)));
typedef float f32x4 __attribute__((ext_vector_type(4)));

static constexpr int D = 4096;
static constexpr int S = 4096;
static constexpr int T = 256;
static constexpr int H = 32;
static constexpr int F = 16384;

__device__ __forceinline__ void gload16(const void* g, void* l) {
  __builtin_amdgcn_global_load_lds((const __attribute__((address_space(1))) void*)g,
                                   (__attribute__((address_space(3))) void*)l, 16, 0, 0);
}

#define MFMA16(a, b, c) __builtin_amdgcn_mfma_f32_16x16x32_bf16((a), (b), (c), 0, 0, 0)

// ---------------- elementwise f32 -> bf16 ----------------
__global__ __launch_bounds__(256) void k_cvt(const float* __restrict__ in, bf16* __restrict__ out, int n) {
  int i = (blockIdx.x * 256 + threadIdx.x) * 4;
  if (i >= n) return;
  float4 v = *(const float4*)(in + i);
  bf16x4 o = { (bf16)v.x, (bf16)v.y, (bf16)v.z, (bf16)v.w };
  *(bf16x4*)(out + i) = o;
}

// ---------------- transpose+cvt: f32 [R][C] (row stride ldin) -> bf16 [C][R] ----------------
__global__ __launch_bounds__(256) void k_tc(const float* __restrict__ in, bf16* __restrict__ out,
                                            int R, int C, int ldin) {
  __shared__ float tile[32][33];
  int c0 = blockIdx.x * 32, r0 = blockIdx.y * 32;
  int x = threadIdx.x, y = threadIdx.y;
  #pragma unroll
  for (int yy = y; yy < 32; yy += 8)
    tile[yy][x] = in[(size_t)(r0 + yy) * ldin + c0 + x];
  __syncthreads();
  #pragma unroll
  for (int yy = y; yy < 32; yy += 8)
    out[(size_t)(c0 + yy) * R + r0 + x] = (bf16)tile[x][yy];
}

// ---------------- transpose bf16 [R][C] -> [C][R] ----------------
__global__ __launch_bounds__(256) void k_tb(const bf16* __restrict__ in, bf16* __restrict__ out, int R, int C) {
  __shared__ bf16 tile[32][33];
  int c0 = blockIdx.x * 32, r0 = blockIdx.y * 32;
  int x = threadIdx.x, y = threadIdx.y;
  #pragma unroll
  for (int yy = y; yy < 32; yy += 8)
    tile[yy][x] = in[(size_t)(r0 + yy) * C + c0 + x];
  __syncthreads();
  #pragma unroll
  for (int yy = y; yy < 32; yy += 8)
    out[(size_t)(c0 + yy) * R + r0 + x] = tile[x][yy];
}

// ---------------- rmsnorm over 4096, f32 in -> bf16 out ----------------
__global__ __launch_bounds__(256) void k_rms(const float* __restrict__ in, const float* __restrict__ w,
                                             bf16* __restrict__ out) {
  const int row = blockIdx.x, t = threadIdx.x;
  const float* x = in + (size_t)row * 4096;
  float4 v[4];
  float ss = 0.f;
  #pragma unroll
  for (int i = 0; i < 4; i++) {
    v[i] = *(const float4*)(x + t * 4 + i * 1024);
    ss += v[i].x * v[i].x + v[i].y * v[i].y + v[i].z * v[i].z + v[i].w * v[i].w;
  }
  #pragma unroll
  for (int off = 1; off < 64; off <<= 1) ss += __shfl_xor(ss, off, 64);
  __shared__ float red[4];
  if ((t & 63) == 0) red[t >> 6] = ss;
  __syncthreads();
  float rms = rsqrtf((red[0] + red[1] + red[2] + red[3]) * (1.f / 4096.f) + 1e-6f);
  #pragma unroll
  for (int i = 0; i < 4; i++) {
    const float4 wv = *(const float4*)(w + t * 4 + i * 1024);
    bf16x4 ov = { (bf16)(v[i].x * rms * wv.x), (bf16)(v[i].y * rms * wv.y),
                  (bf16)(v[i].z * rms * wv.z), (bf16)(v[i].w * rms * wv.w) };
    *(bf16x4*)(out + (size_t)row * 4096 + t * 4 + i * 1024) = ov;
  }
}

// supertile XCD mapping (bijective): by = (xcd%XGM)*BYG + oidx%BYG ; bx = (xcd/XGM)*BXG + oidx/BYG
__device__ __forceinline__ void xcd_map(int orig, int XGM, int BYG, int BXG, int& by, int& bx) {
  const int xcd = orig & 7, oidx = orig >> 3;
  by = (xcd % XGM) * BYG + oidx % BYG;
  bx = (xcd / XGM) * BXG + oidx / BYG;
}

// ================= 256x256 counted-vmcnt GEMM, tile-loop unrolled x2 (d compile-time) =============
// 8 waves (2Mx4N), BK=64 kh-panels [256][32]; 2-tile-deep staging, vmcnt(6) once per K-tile,
// 1 barrier per phase. MODE 0: f32 out; 1: bf16 out; 2: f32 out + f32 residual
template <int MODE>
__global__ __launch_bounds__(512, 2) void k_gemm2(const bf16* __restrict__ A, const bf16* __restrict__ BT,
                                                  float* __restrict__ Cf, bf16* __restrict__ Cb,
                                                  const float* __restrict__ res,
                                                  int M, int N, int K, int XGM, int BYG, int BXG) {
  __shared__ bf16 LA[2][2][256 * 32];  // [dbuf][kh][row*32+col]
  __shared__ bf16 LB[2][2][256 * 32];
  int by, bx;
  xcd_map(blockIdx.x, XGM, BYG, BXG, by, bx);
  const size_t m0 = (size_t)by * 256, n0 = (size_t)bx * 256;
  const int t = threadIdx.x;
  const int w = t >> 6, lane = t & 63;
  const int wm = w >> 2, wn = w & 3;
  const int g = lane >> 4, r15 = lane & 15;
  const int nt = K >> 6;  // always even here (64 or 256)
  const int sr0 = t >> 2, ss0 = t & 3;
  const int sr1 = (t + 512) >> 2, ss1 = (t + 512) & 3;
  const int sc0 = ((ss0 ^ ((sr0 >> 1) & 3)) << 3);
  const int sc1 = ((ss1 ^ ((sr1 >> 1) & 3)) << 3);
  f32x4 acc[8][4] = {};

  auto stA = [&](int db, int kh, int st) {
    const bf16* src = A + m0 * K + (size_t)st * 64 + kh * 32;
    gload16(src + (size_t)sr0 * K + sc0, &LA[db][kh][t * 8]);
    gload16(src + (size_t)sr1 * K + sc1, &LA[db][kh][(t + 512) * 8]);
  };
  auto stB = [&](int db, int kh, int st) {
    const bf16* src = BT + n0 * K + (size_t)st * 64 + kh * 32;
    gload16(src + (size_t)sr0 * K + sc0, &LB[db][kh][t * 8]);
    gload16(src + (size_t)sr1 * K + sc1, &LB[db][kh][(t + 512) * 8]);
  };

  // prologue: T0 all 4 panels + T1 {A0,B0,A1} = 14 loads/thread
  stA(0, 0, 0); stB(0, 0, 0); stA(0, 1, 0); stB(0, 1, 0);
  stA(1, 0, 1); stB(1, 0, 1); stA(1, 1, 1);
  asm volatile("s_waitcnt vmcnt(6)" ::: "memory");
  __builtin_amdgcn_s_barrier();

  const int arow = wm * 128;

#define GEMM_TILE(DD, TC)                                                                     \
  {                                                                                           \
    const int t1 = ((TC) + 1 < nt) ? (TC) + 1 : nt - 1;                                       \
    const int t2 = ((TC) + 2 < nt) ? (TC) + 2 : nt - 1;                                       \
    bf16x8 af[8], b0, b1;                                                                     \
    /* phase 0: kh=0, nh=0 */                                                                 \
    stB((DD) ^ 1, 1, t1);                                                                     \
    _Pragma("unroll")                                                                         \
    for (int mf = 0; mf < 8; ++mf) {                                                          \
      const int rr = arow + mf * 16 + r15;                                                    \
      af[mf] = *(const bf16x8*)&LA[DD][0][rr * 32 + ((g ^ ((rr >> 1) & 3)) << 3)];            \
    }                                                                                         \
    {                                                                                         \
      const int rb0 = wn * 64 + r15, rb1 = wn * 64 + 16 + r15;                                \
      b0 = *(const bf16x8*)&LB[DD][0][rb0 * 32 + ((g ^ ((rb0 >> 1) & 3)) << 3)];              \
      b1 = *(const bf16x8*)&LB[DD][0][rb1 * 32 + ((g ^ ((rb1 >> 1) & 3)) << 3)];              \
    }                                                                                         \
    __builtin_amdgcn_s_barrier();                                                             \
    __builtin_amdgcn_s_setprio(1);                                                            \
    _Pragma("unroll")                                                                         \
    for (int mf = 0; mf < 8; ++mf) {                                                          \
      acc[mf][0] = MFMA16(af[mf], b0, acc[mf][0]);                                            \
      acc[mf][1] = MFMA16(af[mf], b1, acc[mf][1]);                                            \
    }                                                                                         \
    __builtin_amdgcn_s_setprio(0);                                                            \
    /* phase 1: kh=0, nh=1 */                                                                 \
    stA(DD, 0, t2);                                                                           \
    {                                                                                         \
      const int rb0 = wn * 64 + 32 + r15, rb1 = wn * 64 + 48 + r15;                           \
      b0 = *(const bf16x8*)&LB[DD][0][rb0 * 32 + ((g ^ ((rb0 >> 1) & 3)) << 3)];              \
      b1 = *(const bf16x8*)&LB[DD][0][rb1 * 32 + ((g ^ ((rb1 >> 1) & 3)) << 3)];              \
    }                                                                                         \
    __builtin_amdgcn_s_barrier();                                                             \
    __builtin_amdgcn_s_setprio(1);                                                            \
    _Pragma("unroll")                                                                         \
    for (int mf = 0; mf < 8; ++mf) {                                                          \
      acc[mf][2] = MFMA16(af[mf], b0, acc[mf][2]);                                            \
      acc[mf][3] = MFMA16(af[mf], b1, acc[mf][3]);                                            \
    }                                                                                         \
    __builtin_amdgcn_s_setprio(0);                                                            \
    /* phase 2: kh=1, nh=0 */                                                                 \
    stB(DD, 0, t2);                                                                           \
    _Pragma("unroll")                                                                         \
    for (int mf = 0; mf < 8; ++mf) {                                                          \
      const int rr = arow + mf * 16 + r15;                                                    \
      af[mf] = *(const bf16x8*)&LA[DD][1][rr * 32 + ((g ^ ((rr >> 1) & 3)) << 3)];            \
    }                                                                                         \
    {                                                                                         \
      const int rb0 = wn * 64 + r15, rb1 = wn * 64 + 16 + r15;                                \
      b0 = *(const bf16x8*)&LB[DD][1][rb0 * 32 + ((g ^ ((rb0 >> 1) & 3)) << 3)];              \
      b1 = *(const bf16x8*)&LB[DD][1][rb1 * 32 + ((g ^ ((rb1 >> 1) & 3)) << 3)];              \
    }                                                                                         \
    __builtin_amdgcn_s_barrier();                                                             \
    __builtin_amdgcn_s_setprio(1);                                                            \
    _Pragma("unroll")                                                                         \
    for (int mf = 0; mf < 8; ++mf) {                                                          \
      acc[mf][0] = MFMA16(af[mf], b0, acc[mf][0]);                                            \
      acc[mf][1] = MFMA16(af[mf], b1, acc[mf][1]);                                            \
    }                                                                                         \
    __builtin_amdgcn_s_setprio(0);                                                            \
    /* phase 3: kh=1, nh=1 */                                                                 \
    stA(DD, 1, t2);                                                                           \
    {                                                                                         \
      const int rb0 = wn * 64 + 32 + r15, rb1 = wn * 64 + 48 + r15;                           \
      b0 = *(const bf16x8*)&LB[DD][1][rb0 * 32 + ((g ^ ((rb0 >> 1) & 3)) << 3)];              \
      b1 = *(const bf16x8*)&LB[DD][1][rb1 * 32 + ((g ^ ((rb1 >> 1) & 3)) << 3)];              \
    }                                                                                         \
    asm volatile("s_waitcnt vmcnt(6)" ::: "memory");                                          \
    __builtin_amdgcn_s_barrier();                                                             \
    __builtin_amdgcn_s_setprio(1);                                                            \
    _Pragma("unroll")                                                                         \
    for (int mf = 0; mf < 8; ++mf) {                                                          \
      acc[mf][2] = MFMA16(af[mf], b0, acc[mf][2]);                                            \
      acc[mf][3] = MFMA16(af[mf], b1, acc[mf][3]);                                            \
    }                                                                                         \
    __builtin_amdgcn_s_setprio(0);                                                            \
  }

  for (int tt = 0; tt < nt; tt += 2) {
    GEMM_TILE(0, tt);
    GEMM_TILE(1, tt + 1);
  }
#undef GEMM_TILE

  #pragma unroll
  for (int mf = 0; mf < 8; ++mf)
    #pragma unroll
    for (int nf = 0; nf < 4; ++nf) {
      const size_t col = n0 + wn * 64 + nf * 16 + r15;
      #pragma unroll
      for (int rr = 0; rr < 4; ++rr) {
        const size_t row = m0 + wm * 128 + mf * 16 + g * 4 + rr;
        const size_t idx = row * (size_t)N + col;
        const float v = acc[mf][nf][rr];
        if (MODE == 0) Cf[idx] = v;
        else if (MODE == 1) Cb[idx] = (bf16)v;
        else Cf[idx] = v + res[idx];
      }
    }
}

// ================= fused GEGLU GEMM: G[M,N] = (A@BTv) * gelu(A@BTg), tile 256x128, unrolled x2 ====
__global__ __launch_bounds__(512, 2) void k_geglu2(const bf16* __restrict__ A, const bf16* __restrict__ BT,
                                                   bf16* __restrict__ G, int N, int K,
                                                   int XGM, int BYG, int BXG) {
  __shared__ bf16 LA[2][2][256 * 32];
  __shared__ bf16 LBv[2][2][128 * 32];
  __shared__ bf16 LBg[2][2][128 * 32];
  int by, bx;
  xcd_map(blockIdx.x, XGM, BYG, BXG, by, bx);
  const size_t m0 = (size_t)by * 256, n0 = (size_t)bx * 128;
  const int t = threadIdx.x;
  const int w = t >> 6, lane = t & 63;
  const int wm = w >> 2, wn = w & 3;
  const int g = lane >> 4, r15 = lane & 15;
  const int nt = K >> 6;
  const int sr0 = t >> 2, ss0 = t & 3;
  const int sr1 = (t + 512) >> 2, ss1 = (t + 512) & 3;
  const int sc0 = ((ss0 ^ ((sr0 >> 1) & 3)) << 3);
  const int sc1 = ((ss1 ^ ((sr1 >> 1) & 3)) << 3);
  f32x4 av[8][2] = {}, ag[8][2] = {};

  auto stA = [&](int db, int kh, int st) {
    const bf16* src = A + m0 * K + (size_t)st * 64 + kh * 32;
    gload16(src + (size_t)sr0 * K + sc0, &LA[db][kh][t * 8]);
    gload16(src + (size_t)sr1 * K + sc1, &LA[db][kh][(t + 512) * 8]);
  };
  auto stBv = [&](int db, int kh, int st) {
    const bf16* src = BT + n0 * K + (size_t)st * 64 + kh * 32;
    gload16(src + (size_t)sr0 * K + sc0, &LBv[db][kh][t * 8]);
  };
  auto stBg = [&](int db, int kh, int st) {
    const bf16* src = BT + ((size_t)N + n0) * K + (size_t)st * 64 + kh * 32;
    gload16(src + (size_t)sr0 * K + sc0, &LBg[db][kh][t * 8]);
  };

  // prologue: T0 all 6 panels (8 loads) + T1 {A0,Bv0,Bg0,A1} (6 loads)
  stA(0, 0, 0); stBv(0, 0, 0); stBg(0, 0, 0); stA(0, 1, 0); stBv(0, 1, 0); stBg(0, 1, 0);
  stA(1, 0, 1); stBv(1, 0, 1); stBg(1, 0, 1); stA(1, 1, 1);
  asm volatile("s_waitcnt vmcnt(6)" ::: "memory");
  __builtin_amdgcn_s_barrier();

  const int arow = wm * 128;

#define GEGLU_TILE(DD, TC)                                                                    \
  {                                                                                           \
    const int t1 = ((TC) + 1 < nt) ? (TC) + 1 : nt - 1;                                       \
    const int t2 = ((TC) + 2 < nt) ? (TC) + 2 : nt - 1;                                       \
    bf16x8 af[8], b0, b1;                                                                     \
    /* phase 0: kh=0, val */                                                                  \
    stBv((DD) ^ 1, 1, t1); stBg((DD) ^ 1, 1, t1);                                             \
    _Pragma("unroll")                                                                         \
    for (int mf = 0; mf < 8; ++mf) {                                                          \
      const int rr = arow + mf * 16 + r15;                                                    \
      af[mf] = *(const bf16x8*)&LA[DD][0][rr * 32 + ((g ^ ((rr >> 1) & 3)) << 3)];            \
    }                                                                                         \
    {                                                                                         \
      const int rb0 = wn * 32 + r15, rb1 = wn * 32 + 16 + r15;                                \
      b0 = *(const bf16x8*)&LBv[DD][0][rb0 * 32 + ((g ^ ((rb0 >> 1) & 3)) << 3)];             \
      b1 = *(const bf16x8*)&LBv[DD][0][rb1 * 32 + ((g ^ ((rb1 >> 1) & 3)) << 3)];             \
    }                                                                                         \
    __builtin_amdgcn_s_barrier();                                                             \
    __builtin_amdgcn_s_setprio(1);                                                            \
    _Pragma("unroll")                                                                         \
    for (int mf = 0; mf < 8; ++mf) {                                                          \
      av[mf][0] = MFMA16(af[mf], b0, av[mf][0]);                                              \
      av[mf][1] = MFMA16(af[mf], b1, av[mf][1]);                                              \
    }                                                                                         \
    __builtin_amdgcn_s_setprio(0);                                                            \
    /* phase 1: kh=0, gate */                                                                 \
    stA(DD, 0, t2);                                                                           \
    {                                                                                         \
      const int rb0 = wn * 32 + r15, rb1 = wn * 32 + 16 + r15;                                \
      b0 = *(const bf16x8*)&LBg[DD][0][rb0 * 32 + ((g ^ ((rb0 >> 1) & 3)) << 3)];             \
      b1 = *(const bf16x8*)&LBg[DD][0][rb1 * 32 + ((g ^ ((rb1 >> 1) & 3)) << 3)];             \
    }                                                                                         \
    __builtin_amdgcn_s_barrier();                                                             \
    __builtin_amdgcn_s_setprio(1);                                                            \
    _Pragma("unroll")                                                                         \
    for (int mf = 0; mf < 8; ++mf) {                                                          \
      ag[mf][0] = MFMA16(af[mf], b0, ag[mf][0]);                                              \
      ag[mf][1] = MFMA16(af[mf], b1, ag[mf][1]);                                              \
    }                                                                                         \
    __builtin_amdgcn_s_setprio(0);                                                            \
    /* phase 2: kh=1, val */                                                                  \
    stBv(DD, 0, t2); stBg(DD, 0, t2);                                                         \
    _Pragma("unroll")                                                                         \
    for (int mf = 0; mf < 8; ++mf) {                                                          \
      const int rr = arow + mf * 16 + r15;                                                    \
      af[mf] = *(const bf16x8*)&LA[DD][1][rr * 32 + ((g ^ ((rr >> 1) & 3)) << 3)];            \
    }                                                                                         \
    {                                                                                         \
      const int rb0 = wn * 32 + r15, rb1 = wn * 32 + 16 + r15;                                \
      b0 = *(const bf16x8*)&LBv[DD][1][rb0 * 32 + ((g ^ ((rb0 >> 1) & 3)) << 3)];             \
      b1 = *(const bf16x8*)&LBv[DD][1][rb1 * 32 + ((g ^ ((rb1 >> 1) & 3)) << 3)];             \
    }                                                                                         \
    __builtin_amdgcn_s_barrier();                                                             \
    __builtin_amdgcn_s_setprio(1);                                                            \
    _Pragma("unroll")                                                                         \
    for (int mf = 0; mf < 8; ++mf) {                                                          \
      av[mf][0] = MFMA16(af[mf], b0, av[mf][0]);                                              \
      av[mf][1] = MFMA16(af[mf], b1, av[mf][1]);                                              \
    }                                                                                         \
    __builtin_amdgcn_s_setprio(0);                                                            \
    /* phase 3: kh=1, gate */                                                                 \
    stA(DD, 1, t2);                                                                           \
    {                                                                                         \
      const int rb0 = wn * 32 + r15, rb1 = wn * 32 + 16 + r15;                                \
      b0 = *(const bf16x8*)&LBg[DD][1][rb0 * 32 + ((g ^ ((rb0 >> 1) & 3)) << 3)];             \
      b1 = *(const bf16x8*)&LBg[DD][1][rb1 * 32 + ((g ^ ((rb1 >> 1) & 3)) << 3)];             \
    }                                                                                         \
    asm volatile("s_waitcnt vmcnt(6)" ::: "memory");                                          \
    __builtin_amdgcn_s_barrier();                                                             \
    __builtin_amdgcn_s_setprio(1);                                                            \
    _Pragma("unroll")                                                                         \
    for (int mf = 0; mf < 8; ++mf) {                                                          \
      ag[mf][0] = MFMA16(af[mf], b0, ag[mf][0]);                                              \
      ag[mf][1] = MFMA16(af[mf], b1, ag[mf][1]);                                              \
    }                                                                                         \
    __builtin_amdgcn_s_setprio(0);                                                            \
  }

  for (int tt = 0; tt < nt; tt += 2) {
    GEGLU_TILE(0, tt);
    GEGLU_TILE(1, tt + 1);
  }
#undef GEGLU_TILE

  #pragma unroll
  for (int mf = 0; mf < 8; ++mf)
    #pragma unroll
    for (int nf = 0; nf < 2; ++nf) {
      const size_t col = n0 + wn * 32 + nf * 16 + r15;
      #pragma unroll
      for (int rr = 0; rr < 4; ++rr) {
        const size_t row = m0 + wm * 128 + mf * 16 + g * 4 + rr;
        const float val = av[mf][nf][rr], gt = ag[mf][nf][rr];
        const float z = 1.595769122f * gt + 0.0713548162f * gt * gt * gt;
        const float gel = gt / (1.f + __expf(-z));
        G[row * (size_t)N + col] = (bf16)(val * gel);
      }
    }
}

// ---------------- 128x128 GEMM (m97 structure) for M=256 cases ----------------
template <int MODE>
__global__ __launch_bounds__(256) void k_gemm128(const bf16* __restrict__ A, const bf16* __restrict__ BT,
                                                 float* __restrict__ Cf, bf16* __restrict__ Cb,
                                                 int M, int N, int K) {
  __shared__ bf16 As[128 * 32];
  __shared__ bf16 Bs[128 * 32];
  const int t = threadIdx.x;
  const int lane = t & 63, w = t >> 6;
  const int wr = w >> 1, wc = w & 1;
  const int g = lane >> 4, r15 = lane & 15;
  const size_t m0 = (size_t)blockIdx.y * 128, n0 = (size_t)blockIdx.x * 128;
  f32x4 acc[4][4] = {};
  const int c0 = t, c1 = t + 256;
  const int ar0 = c0 >> 2, as0 = c0 & 3, ar1 = c1 >> 2, as1 = c1 & 3;
  const bf16* Ab = A + m0 * K;
  const bf16* Bb = BT + n0 * K;
  for (int k0 = 0; k0 < K; k0 += 32) {
    __syncthreads();
    gload16(Ab + (size_t)ar0 * K + k0 + ((as0 ^ (ar0 & 3)) << 3), &As[c0 * 8]);
    gload16(Ab + (size_t)ar1 * K + k0 + ((as1 ^ (ar1 & 3)) << 3), &As[c1 * 8]);
    gload16(Bb + (size_t)ar0 * K + k0 + ((as0 ^ (ar0 & 3)) << 3), &Bs[c0 * 8]);
    gload16(Bb + (size_t)ar1 * K + k0 + ((as1 ^ (ar1 & 3)) << 3), &Bs[c1 * 8]);
    __syncthreads();
    bf16x8 af[4], bfr[4];
    #pragma unroll
    for (int mi = 0; mi < 4; mi++) {
      int row = wr * 64 + mi * 16 + r15;
      af[mi] = *(const bf16x8*)&As[row * 32 + ((g ^ (row & 3)) << 3)];
    }
    #pragma unroll
    for (int ni = 0; ni < 4; ni++) {
      int row = wc * 64 + ni * 16 + r15;
      bfr[ni] = *(const bf16x8*)&Bs[row * 32 + ((g ^ (row & 3)) << 3)];
    }
    #pragma unroll
    for (int mi = 0; mi < 4; mi++)
      #pragma unroll
      for (int ni = 0; ni < 4; ni++)
        acc[mi][ni] = MFMA16(af[mi], bfr[ni], acc[mi][ni]);
  }
  #pragma unroll
  for (int mi = 0; mi < 4; mi++)
    #pragma unroll
    for (int ni = 0; ni < 4; ni++) {
      size_t col = n0 + wc * 64 + ni * 16 + r15;
      #pragma unroll
      for (int rr = 0; rr < 4; rr++) {
        size_t row = m0 + wr * 64 + mi * 16 + g * 4 + rr;
        size_t idx = row * (size_t)N + col;
        float v = acc[mi][ni][rr];
        if (MODE == 0) Cf[idx] = v;
        else Cb[idx] = (bf16)v;
      }
    }
}

// ---------------- flash attention: Q[S,D] x K[Skv,D] x VT[D,Skv] -> O[S,D] ----------------
__global__ __launch_bounds__(256) void k_attn(const bf16* __restrict__ Q, const bf16* __restrict__ Kb,
                                              const bf16* __restrict__ VT, bf16* __restrict__ O,
                                              int Skv) {
  __shared__ bf16 Kt[32 * 128];
  __shared__ bf16 Vt[128 * 32];
  __shared__ bf16 Pt[4][16 * 32];
  const int h = blockIdx.y;
  const int t = threadIdx.x, w = t >> 6, lane = t & 63;
  const int g = lane >> 4, r15 = lane & 15;
  const int q0 = blockIdx.x * 64 + w * 16;
  bf16x8 qf[4];
  #pragma unroll
  for (int c = 0; c < 4; c++)
    qf[c] = *(const bf16x8*)(Q + (size_t)(q0 + r15) * D + h * 128 + c * 32 + g * 8);
  f32x4 o[8] = {};
  float m_[4] = { -1e30f, -1e30f, -1e30f, -1e30f };
  float l_[4] = { 0.f, 0.f, 0.f, 0.f };
  const float scale = 0.08838834764831845f;
  for (int kt = 0; kt < Skv; kt += 32) {
    __syncthreads();
    #pragma unroll
    for (int cc = 0; cc < 2; cc++) {
      int c = t + cc * 256;
      int kr = c >> 4, ks = c & 15;
      gload16(Kb + (size_t)(kt + kr) * D + h * 128 + ((ks ^ (kr & 15)) << 3), &Kt[c * 8]);
      int vr = c >> 2, vs = c & 3;
      gload16(VT + (size_t)(h * 128 + vr) * Skv + kt + ((vs ^ (vr & 3)) << 3), &Vt[c * 8]);
    }
    __syncthreads();
    f32x4 s0 = {}, s1 = {};
    #pragma unroll
    for (int c = 0; c < 4; c++) {
      int row0 = r15, row1 = 16 + r15;
      bf16x8 kf0 = *(const bf16x8*)&Kt[row0 * 128 + (((4 * c + g) ^ (row0 & 15)) << 3)];
      bf16x8 kf1 = *(const bf16x8*)&Kt[row1 * 128 + (((4 * c + g) ^ (row1 & 15)) << 3)];
      s0 = MFMA16(qf[c], kf0, s0);
      s1 = MFMA16(qf[c], kf1, s1);
    }
    float al[4];
    #pragma unroll
    for (int rr = 0; rr < 4; rr++) {
      float v0 = s0[rr] * scale, v1 = s1[rr] * scale;
      float mx = fmaxf(v0, v1);
      #pragma unroll
      for (int off = 1; off < 16; off <<= 1) mx = fmaxf(mx, __shfl_xor(mx, off, 16));
      float mn = fmaxf(m_[rr], mx);
      al[rr] = __expf(m_[rr] - mn);
      float p0 = __expf(v0 - mn), p1 = __expf(v1 - mn);
      float sm = p0 + p1;
      #pragma unroll
      for (int off = 1; off < 16; off <<= 1) sm += __shfl_xor(sm, off, 16);
      l_[rr] = l_[rr] * al[rr] + sm;
      m_[rr] = mn;
      int prow = g * 4 + rr;
      int sl0 = r15 >> 3, sl1 = 2 + (r15 >> 3);
      Pt[w][prow * 32 + ((sl0 ^ (prow & 3)) << 3) + (r15 & 7)] = (bf16)p0;
      Pt[w][prow * 32 + ((sl1 ^ (prow & 3)) << 3) + (r15 & 7)] = (bf16)p1;
    }
    #pragma unroll
    for (int d = 0; d < 8; d++)
      #pragma unroll
      for (int rr = 0; rr < 4; rr++) o[d][rr] *= al[rr];
    bf16x8 pa = *(const bf16x8*)&Pt[w][r15 * 32 + ((g ^ (r15 & 3)) << 3)];
    #pragma unroll
    for (int d = 0; d < 8; d++) {
      int vrow = d * 16 + r15;
      bf16x8 vbf = *(const bf16x8*)&Vt[vrow * 32 + ((g ^ (vrow & 3)) << 3)];
      o[d] = MFMA16(pa, vbf, o[d]);
    }
  }
  #pragma unroll
  for (int rr = 0; rr < 4; rr++) {
    float inv = 1.f / l_[rr];
    #pragma unroll
    for (int d = 0; d < 8; d++)
      O[(size_t)(q0 + g * 4 + rr) * D + h * 128 + d * 16 + r15] = (bf16)(o[d][rr] * inv);
  }
}

extern "C" void kernel_launch(void* const* d_in, const int* in_sizes, int n_in,
                              void* d_out, int out_size, void* d_ws, size_t ws_size,
                              hipStream_t stream) {
  (void)in_sizes; (void)n_in; (void)out_size; (void)ws_size;
  const float* video = (const float*)d_in[0];
  const float* text  = (const float*)d_in[1];
  const float* wq    = (const float*)d_in[2];
  const float* wk    = (const float*)d_in[3];
  const float* wv    = (const float*)d_in[4];
  const float* wo    = (const float*)d_in[5];
  const float* qnw   = (const float*)d_in[6];
  const float* knw   = (const float*)d_in[7];
  const float* cwq   = (const float*)d_in[8];
  const float* cwk   = (const float*)d_in[9];
  const float* cwv   = (const float*)d_in[10];
  const float* cwo   = (const float*)d_in[11];
  const float* cqnw  = (const float*)d_in[12];
  const float* cknw  = (const float*)d_in[13];
  const float* ffp   = (const float*)d_in[14];
  const float* ffd   = (const float*)d_in[15];
  float* out = (float*)d_out;

  char* slab = (char*)d_ws;
  const size_t MB = 1024 * 1024;
  bf16*  wbuf  = (bf16*)slab;
  bf16*  vb    = (bf16*)(slab + 64 * MB);
  bf16*  vt    = (bf16*)(slab + 96 * MB);
  float* pre   = (float*)(slab + 128 * MB);
  bf16*  Hval  = (bf16*)(slab + 268 * MB);
  char* p = slab + 402 * MB;
  auto take = [&](size_t bytes) { char* r = p; p += (bytes + 255) & ~(size_t)255; return r; };
  bf16* xb   = (bf16*)take((size_t)S * D * 2);
  bf16* qb   = (bf16*)take((size_t)S * D * 2);
  bf16* kb   = (bf16*)take((size_t)S * D * 2);
  bf16* ab   = (bf16*)take((size_t)S * D * 2);
  float* h1  = (float*)take((size_t)S * D * 4);
  bf16* tbuf = (bf16*)take((size_t)T * D * 2);
  bf16* ckb  = (bf16*)take((size_t)T * D * 2);
  bf16* cvb  = (bf16*)take((size_t)T * D * 2);
  bf16* cvt_ = (bf16*)take((size_t)T * D * 2);
  float* h2  = out;

  dim3 b256(256), b512(512), btc(32, 8);
  const int GRID_DD = 256, GRID_GG = 2048;

  // ---- self-attention ----
  k_cvt<<<(S * D) / 1024, b256, 0, stream>>>(video, xb, S * D);
  k_tc<<<dim3(D / 32, D / 32), btc, 0, stream>>>(wq, wbuf, D, D, D);
  k_gemm2<0><<<GRID_DD, b512, 0, stream>>>(xb, wbuf, pre, nullptr, nullptr, S, D, D, 2, 8, 4);
  k_rms<<<S, b256, 0, stream>>>(pre, qnw, qb);
  k_tc<<<dim3(D / 32, D / 32), btc, 0, stream>>>(wk, wbuf, D, D, D);
  k_gemm2<0><<<GRID_DD, b512, 0, stream>>>(xb, wbuf, pre, nullptr, nullptr, S, D, D, 2, 8, 4);
  k_rms<<<S, b256, 0, stream>>>(pre, knw, kb);
  k_tc<<<dim3(D / 32, D / 32), btc, 0, stream>>>(wv, wbuf, D, D, D);
  k_gemm2<1><<<GRID_DD, b512, 0, stream>>>(xb, wbuf, nullptr, vb, nullptr, S, D, D, 2, 8, 4);
  k_tb<<<dim3(D / 32, S / 32), btc, 0, stream>>>(vb, vt, S, D);
  k_attn<<<dim3(S / 64, H), b256, 0, stream>>>(qb, kb, vt, ab, S);
  k_tc<<<dim3(D / 32, D / 32), btc, 0, stream>>>(wo, wbuf, D, D, D);
  k_gemm2<2><<<GRID_DD, b512, 0, stream>>>(ab, wbuf, h1, nullptr, video, S, D, D, 2, 8, 4);

  // ---- cross-attention ----
  k_cvt<<<(S * D) / 1024, b256, 0, stream>>>(h1, xb, S * D);
  k_tc<<<dim3(D / 32, D / 32), btc, 0, stream>>>(cwq, wbuf, D, D, D);
  k_gemm2<0><<<GRID_DD, b512, 0, stream>>>(xb, wbuf, pre, nullptr, nullptr, S, D, D, 2, 8, 4);
  k_rms<<<S, b256, 0, stream>>>(pre, cqnw, qb);
  k_cvt<<<(T * D) / 1024, b256, 0, stream>>>(text, tbuf, T * D);
  k_tc<<<dim3(D / 32, D / 32), btc, 0, stream>>>(cwk, wbuf, D, D, D);
  k_gemm128<0><<<dim3(D / 128, T / 128), b256, 0, stream>>>(tbuf, wbuf, pre, nullptr, T, D, D);
  k_rms<<<T, b256, 0, stream>>>(pre, cknw, ckb);
  k_tc<<<dim3(D / 32, D / 32), btc, 0, stream>>>(cwv, wbuf, D, D, D);
  k_gemm128<1><<<dim3(D / 128, T / 128), b256, 0, stream>>>(tbuf, wbuf, nullptr, cvb, T, D, D);
  k_tb<<<dim3(D / 32, T / 32), btc, 0, stream>>>(cvb, cvt_, T, D);
  k_attn<<<dim3(S / 64, H), b256, 0, stream>>>(qb, ckb, cvt_, ab, T);
  k_tc<<<dim3(D / 32, D / 32), btc, 0, stream>>>(cwo, wbuf, D, D, D);
  k_gemm2<2><<<GRID_DD, b512, 0, stream>>>(ab, wbuf, h2, nullptr, h1, S, D, D, 2, 8, 4);

  // ---- GEGLU FFN (fused val+gate) ----
  k_cvt<<<(S * D) / 1024, b256, 0, stream>>>(h2, xb, S * D);
  k_tc<<<dim3((2 * F) / 32, D / 32), btc, 0, stream>>>(ffp, wbuf, D, 2 * F, 2 * F);
  k_geglu2<<<GRID_GG, b512, 0, stream>>>(xb, wbuf, Hval, F, D, 2, 8, 32);
  k_tc<<<dim3(D / 32, F / 32), btc, 0, stream>>>(ffd, wbuf, F, D, D);
  k_gemm2<2><<<GRID_DD, b512, 0, stream>>>(Hval, wbuf, out, nullptr, h2, S, D, F, 2, 8, 4);
}

// Round 8
// 4024.086 us; speedup vs baseline: 1.5256x; 1.0067x over previous
//
#include <hip/hip_runtime.h>
#include <cstdint>
#include <cstddef>

typedef __bf16 bf16;
typedef __bf16 bf16x8 __attribute__((ext_vector_type(8)));
typedef __bf16 bf16x4 __attribute__((ext_vector_type(4)));
typedef float f32x4 __attribute__((ext_vector_type(4)));

static constexpr int D = 4096;
static constexpr int S = 4096;
static constexpr int T = 256;
static constexpr int H = 32;
static constexpr int F = 16384;

__device__ __forceinline__ void gload16(const void* g, void* l) {
  __builtin_amdgcn_global_load_lds((const __attribute__((address_space(1))) void*)g,
                                   (__attribute__((address_space(3))) void*)l, 16, 0, 0);
}

#define MFMA16(a, b, c) __builtin_amdgcn_mfma_f32_16x16x32_bf16((a), (b), (c), 0, 0, 0)

// ---------------- elementwise f32 -> bf16 ----------------
__global__ __launch_bounds__(256) void k_cvt(const float* __restrict__ in, bf16* __restrict__ out, int n) {
  int i = (blockIdx.x * 256 + threadIdx.x) * 4;
  if (i >= n) return;
  float4 v = *(const float4*)(in + i);
  bf16x4 o = { (bf16)v.x, (bf16)v.y, (bf16)v.z, (bf16)v.w };
  *(bf16x4*)(out + i) = o;
}

// ---------------- transpose+cvt: f32 [R][C] (row stride ldin) -> bf16 [C][R] ----------------
__global__ __launch_bounds__(256) void k_tc(const float* __restrict__ in, bf16* __restrict__ out,
                                            int R, int C, int ldin) {
  __shared__ float tile[32][33];
  int c0 = blockIdx.x * 32, r0 = blockIdx.y * 32;
  int x = threadIdx.x, y = threadIdx.y;
  #pragma unroll
  for (int yy = y; yy < 32; yy += 8)
    tile[yy][x] = in[(size_t)(r0 + yy) * ldin + c0 + x];
  __syncthreads();
  #pragma unroll
  for (int yy = y; yy < 32; yy += 8)
    out[(size_t)(c0 + yy) * R + r0 + x] = (bf16)tile[x][yy];
}

// ---------------- transpose bf16 [R][C] -> [C][R] ----------------
__global__ __launch_bounds__(256) void k_tb(const bf16* __restrict__ in, bf16* __restrict__ out, int R, int C) {
  __shared__ bf16 tile[32][33];
  int c0 = blockIdx.x * 32, r0 = blockIdx.y * 32;
  int x = threadIdx.x, y = threadIdx.y;
  #pragma unroll
  for (int yy = y; yy < 32; yy += 8)
    tile[yy][x] = in[(size_t)(r0 + yy) * C + c0 + x];
  __syncthreads();
  #pragma unroll
  for (int yy = y; yy < 32; yy += 8)
    out[(size_t)(c0 + yy) * R + r0 + x] = tile[x][yy];
}

// ---------------- rmsnorm over 4096, bf16 in -> bf16 out (f32 math) ----------------
__global__ __launch_bounds__(256) void k_rms(const bf16* __restrict__ in, const float* __restrict__ w,
                                             bf16* __restrict__ out) {
  const int row = blockIdx.x, t = threadIdx.x;
  const bf16* x = in + (size_t)row * 4096;
  float xv[16];
  float ss = 0.f;
  #pragma unroll
  for (int i = 0; i < 2; i++) {
    bf16x8 b = *(const bf16x8*)(x + t * 8 + i * 2048);
    #pragma unroll
    for (int j = 0; j < 8; j++) { xv[i * 8 + j] = (float)b[j]; ss += xv[i * 8 + j] * xv[i * 8 + j]; }
  }
  #pragma unroll
  for (int off = 1; off < 64; off <<= 1) ss += __shfl_xor(ss, off, 64);
  __shared__ float red[4];
  if ((t & 63) == 0) red[t >> 6] = ss;
  __syncthreads();
  float rms = rsqrtf((red[0] + red[1] + red[2] + red[3]) * (1.f / 4096.f) + 1e-6f);
  #pragma unroll
  for (int i = 0; i < 2; i++) {
    float4 w0 = *(const float4*)(w + t * 8 + i * 2048);
    float4 w1 = *(const float4*)(w + t * 8 + i * 2048 + 4);
    bf16x8 ov;
    ov[0] = (bf16)(xv[i * 8 + 0] * rms * w0.x); ov[1] = (bf16)(xv[i * 8 + 1] * rms * w0.y);
    ov[2] = (bf16)(xv[i * 8 + 2] * rms * w0.z); ov[3] = (bf16)(xv[i * 8 + 3] * rms * w0.w);
    ov[4] = (bf16)(xv[i * 8 + 4] * rms * w1.x); ov[5] = (bf16)(xv[i * 8 + 5] * rms * w1.y);
    ov[6] = (bf16)(xv[i * 8 + 6] * rms * w1.z); ov[7] = (bf16)(xv[i * 8 + 7] * rms * w1.w);
    *(bf16x8*)(out + (size_t)row * 4096 + t * 8 + i * 2048) = ov;
  }
}

// supertile XCD mapping (bijective): by = (xcd%XGM)*BYG + oidx%BYG ; bx = (xcd/XGM)*BXG + oidx/BYG
__device__ __forceinline__ void xcd_map(int orig, int XGM, int BYG, int BXG, int& by, int& bx) {
  const int xcd = orig & 7, oidx = orig >> 3;
  by = (xcd % XGM) * BYG + oidx % BYG;
  bx = (xcd / XGM) * BXG + oidx / BYG;
}

// ================= 256x256 counted-vmcnt GEMM, tile-loop unrolled x2, split waits ================
// 8 waves (2Mx4N), BK=64 kh-panels [256][32]; 2-tile-deep staging; vmcnt(10) at end of p1 AND p3
// (each drains only >=6-phase-old loads -> no latency stall). 1 barrier per phase.
// MODE 0: f32 out; 1: bf16 out; 2: f32 = v+res; 3: f32 = v+res AND bf16 dual write
template <int MODE>
__global__ __launch_bounds__(512, 2) void k_gemm2(const bf16* __restrict__ A, const bf16* __restrict__ BT,
                                                  float* __restrict__ Cf, bf16* __restrict__ Cb,
                                                  const float* __restrict__ res,
                                                  int M, int N, int K, int XGM, int BYG, int BXG) {
  __shared__ bf16 LA[2][2][256 * 32];  // [dbuf][kh][row*32+col]
  __shared__ bf16 LB[2][2][256 * 32];
  int by, bx;
  xcd_map(blockIdx.x, XGM, BYG, BXG, by, bx);
  const size_t m0 = (size_t)by * 256, n0 = (size_t)bx * 256;
  const int t = threadIdx.x;
  const int w = t >> 6, lane = t & 63;
  const int wm = w >> 2, wn = w & 3;
  const int g = lane >> 4, r15 = lane & 15;
  const int nt = K >> 6;  // always even here (64 or 256)
  const int sr0 = t >> 2, ss0 = t & 3;
  const int sr1 = (t + 512) >> 2, ss1 = (t + 512) & 3;
  const int sc0 = ((ss0 ^ ((sr0 >> 1) & 3)) << 3);
  const int sc1 = ((ss1 ^ ((sr1 >> 1) & 3)) << 3);
  f32x4 acc[8][4] = {};

  auto stA = [&](int db, int kh, int st) {
    const bf16* src = A + m0 * K + (size_t)st * 64 + kh * 32;
    gload16(src + (size_t)sr0 * K + sc0, &LA[db][kh][t * 8]);
    gload16(src + (size_t)sr1 * K + sc1, &LA[db][kh][(t + 512) * 8]);
  };
  auto stB = [&](int db, int kh, int st) {
    const bf16* src = BT + n0 * K + (size_t)st * 64 + kh * 32;
    gload16(src + (size_t)sr0 * K + sc0, &LB[db][kh][t * 8]);
    gload16(src + (size_t)sr1 * K + sc1, &LB[db][kh][(t + 512) * 8]);
  };

  // prologue: T0 all 4 panels + T1 {A0,B0,A1} = 14 loads/thread
  stA(0, 0, 0); stB(0, 0, 0); stA(0, 1, 0); stB(0, 1, 0);
  stA(1, 0, 1); stB(1, 0, 1); stA(1, 1, 1);
  asm volatile("s_waitcnt vmcnt(10)" ::: "memory");  // A0(0),B0(0) landed
  __builtin_amdgcn_s_barrier();

  const int arow = wm * 128;

#define GEMM_TILE(DD, TC)                                                                     \
  {                                                                                           \
    const int t1 = ((TC) + 1 < nt) ? (TC) + 1 : nt - 1;                                       \
    const int t2 = ((TC) + 2 < nt) ? (TC) + 2 : nt - 1;                                       \
    bf16x8 af[8], b0, b1;                                                                     \
    /* phase 0: kh=0, nh=0 */                                                                 \
    stB((DD) ^ 1, 1, t1);                                                                     \
    _Pragma("unroll")                                                                         \
    for (int mf = 0; mf < 8; ++mf) {                                                          \
      const int rr = arow + mf * 16 + r15;                                                    \
      af[mf] = *(const bf16x8*)&LA[DD][0][rr * 32 + ((g ^ ((rr >> 1) & 3)) << 3)];            \
    }                                                                                         \
    {                                                                                         \
      const int rb0 = wn * 64 + r15, rb1 = wn * 64 + 16 + r15;                                \
      b0 = *(const bf16x8*)&LB[DD][0][rb0 * 32 + ((g ^ ((rb0 >> 1) & 3)) << 3)];              \
      b1 = *(const bf16x8*)&LB[DD][0][rb1 * 32 + ((g ^ ((rb1 >> 1) & 3)) << 3)];              \
    }                                                                                         \
    __builtin_amdgcn_s_barrier();                                                             \
    __builtin_amdgcn_s_setprio(1);                                                            \
    _Pragma("unroll")                                                                         \
    for (int mf = 0; mf < 8; ++mf) {                                                          \
      acc[mf][0] = MFMA16(af[mf], b0, acc[mf][0]);                                            \
      acc[mf][1] = MFMA16(af[mf], b1, acc[mf][1]);                                            \
    }                                                                                         \
    __builtin_amdgcn_s_setprio(0);                                                            \
    /* phase 1: kh=0, nh=1 */                                                                 \
    stA(DD, 0, t2);                                                                           \
    {                                                                                         \
      const int rb0 = wn * 64 + 32 + r15, rb1 = wn * 64 + 48 + r15;                           \
      b0 = *(const bf16x8*)&LB[DD][0][rb0 * 32 + ((g ^ ((rb0 >> 1) & 3)) << 3)];              \
      b1 = *(const bf16x8*)&LB[DD][0][rb1 * 32 + ((g ^ ((rb1 >> 1) & 3)) << 3)];              \
    }                                                                                         \
    asm volatile("s_waitcnt vmcnt(10)" ::: "memory");                                         \
    __builtin_amdgcn_s_barrier();                                                             \
    __builtin_amdgcn_s_setprio(1);                                                            \
    _Pragma("unroll")                                                                         \
    for (int mf = 0; mf < 8; ++mf) {                                                          \
      acc[mf][2] = MFMA16(af[mf], b0, acc[mf][2]);                                            \
      acc[mf][3] = MFMA16(af[mf], b1, acc[mf][3]);                                            \
    }                                                                                         \
    __builtin_amdgcn_s_setprio(0);                                                            \
    /* phase 2: kh=1, nh=0 */                                                                 \
    stB(DD, 0, t2);                                                                           \
    _Pragma("unroll")                                                                         \
    for (int mf = 0; mf < 8; ++mf) {                                                          \
      const int rr = arow + mf * 16 + r15;                                                    \
      af[mf] = *(const bf16x8*)&LA[DD][1][rr * 32 + ((g ^ ((rr >> 1) & 3)) << 3)];            \
    }                                                                                         \
    {                                                                                         \
      const int rb0 = wn * 64 + r15, rb1 = wn * 64 + 16 + r15;                                \
      b0 = *(const bf16x8*)&LB[DD][1][rb0 * 32 + ((g ^ ((rb0 >> 1) & 3)) << 3)];              \
      b1 = *(const bf16x8*)&LB[DD][1][rb1 * 32 + ((g ^ ((rb1 >> 1) & 3)) << 3)];              \
    }                                                                                         \
    __builtin_amdgcn_s_barrier();                                                             \
    __builtin_amdgcn_s_setprio(1);                                                            \
    _Pragma("unroll")                                                                         \
    for (int mf = 0; mf < 8; ++mf) {                                                          \
      acc[mf][0] = MFMA16(af[mf], b0, acc[mf][0]);                                            \
      acc[mf][1] = MFMA16(af[mf], b1, acc[mf][1]);                                            \
    }                                                                                         \
    __builtin_amdgcn_s_setprio(0);                                                            \
    /* phase 3: kh=1, nh=1 */                                                                 \
    stA(DD, 1, t2);                                                                           \
    {                                                                                         \
      const int rb0 = wn * 64 + 32 + r15, rb1 = wn * 64 + 48 + r15;                           \
      b0 = *(const bf16x8*)&LB[DD][1][rb0 * 32 + ((g ^ ((rb0 >> 1) & 3)) << 3)];              \
      b1 = *(const bf16x8*)&LB[DD][1][rb1 * 32 + ((g ^ ((rb1 >> 1) & 3)) << 3)];              \
    }                                                                                         \
    asm volatile("s_waitcnt vmcnt(10)" ::: "memory");                                         \
    __builtin_amdgcn_s_barrier();                                                             \
    __builtin_amdgcn_s_setprio(1);                                                            \
    _Pragma("unroll")                                                                         \
    for (int mf = 0; mf < 8; ++mf) {                                                          \
      acc[mf][2] = MFMA16(af[mf], b0, acc[mf][2]);                                            \
      acc[mf][3] = MFMA16(af[mf], b1, acc[mf][3]);                                            \
    }                                                                                         \
    __builtin_amdgcn_s_setprio(0);                                                            \
  }

  for (int tt = 0; tt < nt; tt += 2) {
    GEMM_TILE(0, tt);
    GEMM_TILE(1, tt + 1);
  }
#undef GEMM_TILE

  #pragma unroll
  for (int mf = 0; mf < 8; ++mf)
    #pragma unroll
    for (int nf = 0; nf < 4; ++nf) {
      const size_t col = n0 + wn * 64 + nf * 16 + r15;
      #pragma unroll
      for (int rr = 0; rr < 4; ++rr) {
        const size_t row = m0 + wm * 128 + mf * 16 + g * 4 + rr;
        const size_t idx = row * (size_t)N + col;
        const float v = acc[mf][nf][rr];
        if (MODE == 0) Cf[idx] = v;
        else if (MODE == 1) Cb[idx] = (bf16)v;
        else if (MODE == 2) Cf[idx] = v + res[idx];
        else { const float s = v + res[idx]; Cf[idx] = s; Cb[idx] = (bf16)s; }
      }
    }
}

// ================= fused GEGLU GEMM: G[M,N] = (A@BTv) * gelu(A@BTg), tile 256x128 ================
__global__ __launch_bounds__(512, 2) void k_geglu2(const bf16* __restrict__ A, const bf16* __restrict__ BT,
                                                   bf16* __restrict__ G, int N, int K,
                                                   int XGM, int BYG, int BXG) {
  __shared__ bf16 LA[2][2][256 * 32];
  __shared__ bf16 LBv[2][2][128 * 32];
  __shared__ bf16 LBg[2][2][128 * 32];
  int by, bx;
  xcd_map(blockIdx.x, XGM, BYG, BXG, by, bx);
  const size_t m0 = (size_t)by * 256, n0 = (size_t)bx * 128;
  const int t = threadIdx.x;
  const int w = t >> 6, lane = t & 63;
  const int wm = w >> 2, wn = w & 3;
  const int g = lane >> 4, r15 = lane & 15;
  const int nt = K >> 6;
  const int sr0 = t >> 2, ss0 = t & 3;
  const int sr1 = (t + 512) >> 2, ss1 = (t + 512) & 3;
  const int sc0 = ((ss0 ^ ((sr0 >> 1) & 3)) << 3);
  const int sc1 = ((ss1 ^ ((sr1 >> 1) & 3)) << 3);
  f32x4 av[8][2] = {}, ag[8][2] = {};

  auto stA = [&](int db, int kh, int st) {
    const bf16* src = A + m0 * K + (size_t)st * 64 + kh * 32;
    gload16(src + (size_t)sr0 * K + sc0, &LA[db][kh][t * 8]);
    gload16(src + (size_t)sr1 * K + sc1, &LA[db][kh][(t + 512) * 8]);
  };
  auto stBv = [&](int db, int kh, int st) {
    const bf16* src = BT + n0 * K + (size_t)st * 64 + kh * 32;
    gload16(src + (size_t)sr0 * K + sc0, &LBv[db][kh][t * 8]);
  };
  auto stBg = [&](int db, int kh, int st) {
    const bf16* src = BT + ((size_t)N + n0) * K + (size_t)st * 64 + kh * 32;
    gload16(src + (size_t)sr0 * K + sc0, &LBg[db][kh][t * 8]);
  };

  // prologue: T0 all 6 panels (8 loads) + T1 {A0,Bv0,Bg0,A1} (6 loads)
  stA(0, 0, 0); stBv(0, 0, 0); stBg(0, 0, 0); stA(0, 1, 0); stBv(0, 1, 0); stBg(0, 1, 0);
  stA(1, 0, 1); stBv(1, 0, 1); stBg(1, 0, 1); stA(1, 1, 1);
  asm volatile("s_waitcnt vmcnt(10)" ::: "memory");
  __builtin_amdgcn_s_barrier();

  const int arow = wm * 128;

#define GEGLU_TILE(DD, TC)                                                                    \
  {                                                                                           \
    const int t1 = ((TC) + 1 < nt) ? (TC) + 1 : nt - 1;                                       \
    const int t2 = ((TC) + 2 < nt) ? (TC) + 2 : nt - 1;                                       \
    bf16x8 af[8], b0, b1;                                                                     \
    /* phase 0: kh=0, val */                                                                  \
    stBv((DD) ^ 1, 1, t1); stBg((DD) ^ 1, 1, t1);                                             \
    _Pragma("unroll")                                                                         \
    for (int mf = 0; mf < 8; ++mf) {                                                          \
      const int rr = arow + mf * 16 + r15;                                                    \
      af[mf] = *(const bf16x8*)&LA[DD][0][rr * 32 + ((g ^ ((rr >> 1) & 3)) << 3)];            \
    }                                                                                         \
    {                                                                                         \
      const int rb0 = wn * 32 + r15, rb1 = wn * 32 + 16 + r15;                                \
      b0 = *(const bf16x8*)&LBv[DD][0][rb0 * 32 + ((g ^ ((rb0 >> 1) & 3)) << 3)];             \
      b1 = *(const bf16x8*)&LBv[DD][0][rb1 * 32 + ((g ^ ((rb1 >> 1) & 3)) << 3)];             \
    }                                                                                         \
    __builtin_amdgcn_s_barrier();                                                             \
    __builtin_amdgcn_s_setprio(1);                                                            \
    _Pragma("unroll")                                                                         \
    for (int mf = 0; mf < 8; ++mf) {                                                          \
      av[mf][0] = MFMA16(af[mf], b0, av[mf][0]);                                              \
      av[mf][1] = MFMA16(af[mf], b1, av[mf][1]);                                              \
    }                                                                                         \
    __builtin_amdgcn_s_setprio(0);                                                            \
    /* phase 1: kh=0, gate */                                                                 \
    stA(DD, 0, t2);                                                                           \
    {                                                                                         \
      const int rb0 = wn * 32 + r15, rb1 = wn * 32 + 16 + r15;                                \
      b0 = *(const bf16x8*)&LBg[DD][0][rb0 * 32 + ((g ^ ((rb0 >> 1) & 3)) << 3)];             \
      b1 = *(const bf16x8*)&LBg[DD][0][rb1 * 32 + ((g ^ ((rb1 >> 1) & 3)) << 3)];             \
    }                                                                                         \
    asm volatile("s_waitcnt vmcnt(10)" ::: "memory");                                         \
    __builtin_amdgcn_s_barrier();                                                             \
    __builtin_amdgcn_s_setprio(1);                                                            \
    _Pragma("unroll")                                                                         \
    for (int mf = 0; mf < 8; ++mf) {                                                          \
      ag[mf][0] = MFMA16(af[mf], b0, ag[mf][0]);                                              \
      ag[mf][1] = MFMA16(af[mf], b1, ag[mf][1]);                                              \
    }                                                                                         \
    __builtin_amdgcn_s_setprio(0);                                                            \
    /* phase 2: kh=1, val */                                                                  \
    stBv(DD, 0, t2); stBg(DD, 0, t2);                                                         \
    _Pragma("unroll")                                                                         \
    for (int mf = 0; mf < 8; ++mf) {                                                          \
      const int rr = arow + mf * 16 + r15;                                                    \
      af[mf] = *(const bf16x8*)&LA[DD][1][rr * 32 + ((g ^ ((rr >> 1) & 3)) << 3)];            \
    }                                                                                         \
    {                                                                                         \
      const int rb0 = wn * 32 + r15, rb1 = wn * 32 + 16 + r15;                                \
      b0 = *(const bf16x8*)&LBv[DD][1][rb0 * 32 + ((g ^ ((rb0 >> 1) & 3)) << 3)];             \
      b1 = *(const bf16x8*)&LBv[DD][1][rb1 * 32 + ((g ^ ((rb1 >> 1) & 3)) << 3)];             \
    }                                                                                         \
    __builtin_amdgcn_s_barrier();                                                             \
    __builtin_amdgcn_s_setprio(1);                                                            \
    _Pragma("unroll")                                                                         \
    for (int mf = 0; mf < 8; ++mf) {                                                          \
      av[mf][0] = MFMA16(af[mf], b0, av[mf][0]);                                              \
      av[mf][1] = MFMA16(af[mf], b1, av[mf][1]);                                              \
    }                                                                                         \
    __builtin_amdgcn_s_setprio(0);                                                            \
    /* phase 3: kh=1, gate */                                                                 \
    stA(DD, 1, t2);                                                                           \
    {                                                                                         \
      const int rb0 = wn * 32 + r15, rb1 = wn * 32 + 16 + r15;                                \
      b0 = *(const bf16x8*)&LBg[DD][1][rb0 * 32 + ((g ^ ((rb0 >> 1) & 3)) << 3)];             \
      b1 = *(const bf16x8*)&LBg[DD][1][rb1 * 32 + ((g ^ ((rb1 >> 1) & 3)) << 3)];             \
    }                                                                                         \
    asm volatile("s_waitcnt vmcnt(10)" ::: "memory");                                         \
    __builtin_amdgcn_s_barrier();                                                             \
    __builtin_amdgcn_s_setprio(1);                                                            \
    _Pragma("unroll")                                                                         \
    for (int mf = 0; mf < 8; ++mf) {                                                          \
      ag[mf][0] = MFMA16(af[mf], b0, ag[mf][0]);                                              \
      ag[mf][1] = MFMA16(af[mf], b1, ag[mf][1]);                                              \
    }                                                                                         \
    __builtin_amdgcn_s_setprio(0);                                                            \
  }

  for (int tt = 0; tt < nt; tt += 2) {
    GEGLU_TILE(0, tt);
    GEGLU_TILE(1, tt + 1);
  }
#undef GEGLU_TILE

  #pragma unroll
  for (int mf = 0; mf < 8; ++mf)
    #pragma unroll
    for (int nf = 0; nf < 2; ++nf) {
      const size_t col = n0 + wn * 32 + nf * 16 + r15;
      #pragma unroll
      for (int rr = 0; rr < 4; ++rr) {
        const size_t row = m0 + wm * 128 + mf * 16 + g * 4 + rr;
        const float val = av[mf][nf][rr], gt = ag[mf][nf][rr];
        const float z = 1.595769122f * gt + 0.0713548162f * gt * gt * gt;
        const float gel = gt / (1.f + __expf(-z));
        G[row * (size_t)N + col] = (bf16)(val * gel);
      }
    }
}

// ---------------- 128x128 GEMM (m97 structure) for M=256 cases ----------------
template <int MODE>
__global__ __launch_bounds__(256) void k_gemm128(const bf16* __restrict__ A, const bf16* __restrict__ BT,
                                                 float* __restrict__ Cf, bf16* __restrict__ Cb,
                                                 int M, int N, int K) {
  __shared__ bf16 As[128 * 32];
  __shared__ bf16 Bs[128 * 32];
  const int t = threadIdx.x;
  const int lane = t & 63, w = t >> 6;
  const int wr = w >> 1, wc = w & 1;
  const int g = lane >> 4, r15 = lane & 15;
  const size_t m0 = (size_t)blockIdx.y * 128, n0 = (size_t)blockIdx.x * 128;
  f32x4 acc[4][4] = {};
  const int c0 = t, c1 = t + 256;
  const int ar0 = c0 >> 2, as0 = c0 & 3, ar1 = c1 >> 2, as1 = c1 & 3;
  const bf16* Ab = A + m0 * K;
  const bf16* Bb = BT + n0 * K;
  for (int k0 = 0; k0 < K; k0 += 32) {
    __syncthreads();
    gload16(Ab + (size_t)ar0 * K + k0 + ((as0 ^ (ar0 & 3)) << 3), &As[c0 * 8]);
    gload16(Ab + (size_t)ar1 * K + k0 + ((as1 ^ (ar1 & 3)) << 3), &As[c1 * 8]);
    gload16(Bb + (size_t)ar0 * K + k0 + ((as0 ^ (ar0 & 3)) << 3), &Bs[c0 * 8]);
    gload16(Bb + (size_t)ar1 * K + k0 + ((as1 ^ (ar1 & 3)) << 3), &Bs[c1 * 8]);
    __syncthreads();
    bf16x8 af[4], bfr[4];
    #pragma unroll
    for (int mi = 0; mi < 4; mi++) {
      int row = wr * 64 + mi * 16 + r15;
      af[mi] = *(const bf16x8*)&As[row * 32 + ((g ^ (row & 3)) << 3)];
    }
    #pragma unroll
    for (int ni = 0; ni < 4; ni++) {
      int row = wc * 64 + ni * 16 + r15;
      bfr[ni] = *(const bf16x8*)&Bs[row * 32 + ((g ^ (row & 3)) << 3)];
    }
    #pragma unroll
    for (int mi = 0; mi < 4; mi++)
      #pragma unroll
      for (int ni = 0; ni < 4; ni++)
        acc[mi][ni] = MFMA16(af[mi], bfr[ni], acc[mi][ni]);
  }
  #pragma unroll
  for (int mi = 0; mi < 4; mi++)
    #pragma unroll
    for (int ni = 0; ni < 4; ni++) {
      size_t col = n0 + wc * 64 + ni * 16 + r15;
      #pragma unroll
      for (int rr = 0; rr < 4; rr++) {
        size_t row = m0 + wr * 64 + mi * 16 + g * 4 + rr;
        size_t idx = row * (size_t)N + col;
        float v = acc[mi][ni][rr];
        if (MODE == 0) Cf[idx] = v;
        else Cb[idx] = (bf16)v;
      }
    }
}

// ---------------- flash attention: Q[S,D] x K[Skv,D] x VT[D,Skv] -> O[S,D] ----------------
__global__ __launch_bounds__(256) void k_attn(const bf16* __restrict__ Q, const bf16* __restrict__ Kb,
                                              const bf16* __restrict__ VT, bf16* __restrict__ O,
                                              int Skv) {
  __shared__ bf16 Kt[32 * 128];
  __shared__ bf16 Vt[128 * 32];
  __shared__ bf16 Pt[4][16 * 32];
  const int h = blockIdx.y;
  const int t = threadIdx.x, w = t >> 6, lane = t & 63;
  const int g = lane >> 4, r15 = lane & 15;
  const int q0 = blockIdx.x * 64 + w * 16;
  bf16x8 qf[4];
  #pragma unroll
  for (int c = 0; c < 4; c++)
    qf[c] = *(const bf16x8*)(Q + (size_t)(q0 + r15) * D + h * 128 + c * 32 + g * 8);
  f32x4 o[8] = {};
  float m_[4] = { -1e30f, -1e30f, -1e30f, -1e30f };
  float l_[4] = { 0.f, 0.f, 0.f, 0.f };
  const float scale = 0.08838834764831845f;
  for (int kt = 0; kt < Skv; kt += 32) {
    __syncthreads();
    #pragma unroll
    for (int cc = 0; cc < 2; cc++) {
      int c = t + cc * 256;
      int kr = c >> 4, ks = c & 15;
      gload16(Kb + (size_t)(kt + kr) * D + h * 128 + ((ks ^ (kr & 15)) << 3), &Kt[c * 8]);
      int vr = c >> 2, vs = c & 3;
      gload16(VT + (size_t)(h * 128 + vr) * Skv + kt + ((vs ^ (vr & 3)) << 3), &Vt[c * 8]);
    }
    __syncthreads();
    f32x4 s0 = {}, s1 = {};
    #pragma unroll
    for (int c = 0; c < 4; c++) {
      int row0 = r15, row1 = 16 + r15;
      bf16x8 kf0 = *(const bf16x8*)&Kt[row0 * 128 + (((4 * c + g) ^ (row0 & 15)) << 3)];
      bf16x8 kf1 = *(const bf16x8*)&Kt[row1 * 128 + (((4 * c + g) ^ (row1 & 15)) << 3)];
      s0 = MFMA16(qf[c], kf0, s0);
      s1 = MFMA16(qf[c], kf1, s1);
    }
    float al[4];
    #pragma unroll
    for (int rr = 0; rr < 4; rr++) {
      float v0 = s0[rr] * scale, v1 = s1[rr] * scale;
      float mx = fmaxf(v0, v1);
      #pragma unroll
      for (int off = 1; off < 16; off <<= 1) mx = fmaxf(mx, __shfl_xor(mx, off, 16));
      float mn = fmaxf(m_[rr], mx);
      al[rr] = __expf(m_[rr] - mn);
      float p0 = __expf(v0 - mn), p1 = __expf(v1 - mn);
      float sm = p0 + p1;
      #pragma unroll
      for (int off = 1; off < 16; off <<= 1) sm += __shfl_xor(sm, off, 16);
      l_[rr] = l_[rr] * al[rr] + sm;
      m_[rr] = mn;
      int prow = g * 4 + rr;
      int sl0 = r15 >> 3, sl1 = 2 + (r15 >> 3);
      Pt[w][prow * 32 + ((sl0 ^ (prow & 3)) << 3) + (r15 & 7)] = (bf16)p0;
      Pt[w][prow * 32 + ((sl1 ^ (prow & 3)) << 3) + (r15 & 7)] = (bf16)p1;
    }
    #pragma unroll
    for (int d = 0; d < 8; d++)
      #pragma unroll
      for (int rr = 0; rr < 4; rr++) o[d][rr] *= al[rr];
    bf16x8 pa = *(const bf16x8*)&Pt[w][r15 * 32 + ((g ^ (r15 & 3)) << 3)];
    #pragma unroll
    for (int d = 0; d < 8; d++) {
      int vrow = d * 16 + r15;
      bf16x8 vbf = *(const bf16x8*)&Vt[vrow * 32 + ((g ^ (vrow & 3)) << 3)];
      o[d] = MFMA16(pa, vbf, o[d]);
    }
  }
  #pragma unroll
  for (int rr = 0; rr < 4; rr++) {
    float inv = 1.f / l_[rr];
    #pragma unroll
    for (int d = 0; d < 8; d++)
      O[(size_t)(q0 + g * 4 + rr) * D + h * 128 + d * 16 + r15] = (bf16)(o[d][rr] * inv);
  }
}

extern "C" void kernel_launch(void* const* d_in, const int* in_sizes, int n_in,
                              void* d_out, int out_size, void* d_ws, size_t ws_size,
                              hipStream_t stream) {
  (void)in_sizes; (void)n_in; (void)out_size; (void)ws_size;
  const float* video = (const float*)d_in[0];
  const float* text  = (const float*)d_in[1];
  const float* wq    = (const float*)d_in[2];
  const float* wk    = (const float*)d_in[3];
  const float* wv    = (const float*)d_in[4];
  const float* wo    = (const float*)d_in[5];
  const float* qnw   = (const float*)d_in[6];
  const float* knw   = (const float*)d_in[7];
  const float* cwq   = (const float*)d_in[8];
  const float* cwk   = (const float*)d_in[9];
  const float* cwv   = (const float*)d_in[10];
  const float* cwo   = (const float*)d_in[11];
  const float* cqnw  = (const float*)d_in[12];
  const float* cknw  = (const float*)d_in[13];
  const float* ffp   = (const float*)d_in[14];
  const float* ffd   = (const float*)d_in[15];
  float* out = (float*)d_out;

  char* slab = (char*)d_ws;
  const size_t MB = 1024 * 1024;
  bf16*  wbuf  = (bf16*)slab;
  bf16*  vb    = (bf16*)(slab + 64 * MB);
  bf16*  vt    = (bf16*)(slab + 96 * MB);
  bf16*  preb  = (bf16*)(slab + 128 * MB);
  bf16*  Hval  = (bf16*)(slab + 268 * MB);
  char* p = slab + 402 * MB;
  auto take = [&](size_t bytes) { char* r = p; p += (bytes + 255) & ~(size_t)255; return r; };
  bf16* xb   = (bf16*)take((size_t)S * D * 2);
  bf16* qb   = (bf16*)take((size_t)S * D * 2);
  bf16* kb   = (bf16*)take((size_t)S * D * 2);
  bf16* ab   = (bf16*)take((size_t)S * D * 2);
  float* h1  = (float*)take((size_t)S * D * 4);
  bf16* tbuf = (bf16*)take((size_t)T * D * 2);
  bf16* ckb  = (bf16*)take((size_t)T * D * 2);
  bf16* cvb  = (bf16*)take((size_t)T * D * 2);
  bf16* cvt_ = (bf16*)take((size_t)T * D * 2);
  float* h2  = out;

  dim3 b256(256), b512(512), btc(32, 8);
  const int GRID_DD = 256, GRID_GG = 2048;

  // ---- self-attention ----
  k_cvt<<<(S * D) / 1024, b256, 0, stream>>>(video, xb, S * D);
  k_tc<<<dim3(D / 32, D / 32), btc, 0, stream>>>(wq, wbuf, D, D, D);
  k_gemm2<1><<<GRID_DD, b512, 0, stream>>>(xb, wbuf, nullptr, preb, nullptr, S, D, D, 2, 8, 4);
  k_rms<<<S, b256, 0, stream>>>(preb, qnw, qb);
  k_tc<<<dim3(D / 32, D / 32), btc, 0, stream>>>(wk, wbuf, D, D, D);
  k_gemm2<1><<<GRID_DD, b512, 0, stream>>>(xb, wbuf, nullptr, preb, nullptr, S, D, D, 2, 8, 4);
  k_rms<<<S, b256, 0, stream>>>(preb, knw, kb);
  k_tc<<<dim3(D / 32, D / 32), btc, 0, stream>>>(wv, wbuf, D, D, D);
  k_gemm2<1><<<GRID_DD, b512, 0, stream>>>(xb, wbuf, nullptr, vb, nullptr, S, D, D, 2, 8, 4);
  k_tb<<<dim3(D / 32, S / 32), btc, 0, stream>>>(vb, vt, S, D);
  k_attn<<<dim3(S / 64, H), b256, 0, stream>>>(qb, kb, vt, ab, S);
  k_tc<<<dim3(D / 32, D / 32), btc, 0, stream>>>(wo, wbuf, D, D, D);
  // o-proj: h1 = ab@wo + video (f32) AND xb = bf16(h1) fused
  k_gemm2<3><<<GRID_DD, b512, 0, stream>>>(ab, wbuf, h1, xb, video, S, D, D, 2, 8, 4);

  // ---- cross-attention ----
  k_tc<<<dim3(D / 32, D / 32), btc, 0, stream>>>(cwq, wbuf, D, D, D);
  k_gemm2<1><<<GRID_DD, b512, 0, stream>>>(xb, wbuf, nullptr, preb, nullptr, S, D, D, 2, 8, 4);
  k_rms<<<S, b256, 0, stream>>>(preb, cqnw, qb);
  k_cvt<<<(T * D) / 1024, b256, 0, stream>>>(text, tbuf, T * D);
  k_tc<<<dim3(D / 32, D / 32), btc, 0, stream>>>(cwk, wbuf, D, D, D);
  k_gemm128<1><<<dim3(D / 128, T / 128), b256, 0, stream>>>(tbuf, wbuf, nullptr, preb, T, D, D);
  k_rms<<<T, b256, 0, stream>>>(preb, cknw, ckb);
  k_tc<<<dim3(D / 32, D / 32), btc, 0, stream>>>(cwv, wbuf, D, D, D);
  k_gemm128<1><<<dim3(D / 128, T / 128), b256, 0, stream>>>(tbuf, wbuf, nullptr, cvb, T, D, D);
  k_tb<<<dim3(D / 32, T / 32), btc, 0, stream>>>(cvb, cvt_, T, D);
  k_attn<<<dim3(S / 64, H), b256, 0, stream>>>(qb, ckb, cvt_, ab, T);
  k_tc<<<dim3(D / 32, D / 32), btc, 0, stream>>>(cwo, wbuf, D, D, D);
  // cross o-proj: h2 = ab@cwo + h1 (f32) AND xb = bf16(h2) fused
  k_gemm2<3><<<GRID_DD, b512, 0, stream>>>(ab, wbuf, h2, xb, h1, S, D, D, 2, 8, 4);

  // ---- GEGLU FFN (fused val+gate) ----
  k_tc<<<dim3((2 * F) / 32, D / 32), btc, 0, stream>>>(ffp, wbuf, D, 2 * F, 2 * F);
  k_geglu2<<<GRID_GG, b512, 0, stream>>>(xb, wbuf, Hval, F, D, 2, 8, 32);
  k_tc<<<dim3(D / 32, F / 32), btc, 0, stream>>>(ffd, wbuf, F, D, D);
  k_gemm2<2><<<GRID_DD, b512, 0, stream>>>(Hval, wbuf, out, nullptr, h2, S, D, F, 2, 8, 4);
}

// Round 9
// 3645.820 us; speedup vs baseline: 1.6838x; 1.1038x over previous
//
#include <hip/hip_runtime.h>
#include <cstdint>
#include <cstddef>

typedef __bf16 bf16;
typedef __bf16 bf16x8 __attribute__((ext_vector_type(8)));
typedef __bf16 bf16x4 __attribute__((ext_vector_type(4)));
typedef float f32x4 __attribute__((ext_vector_type(4)));

static constexpr int D = 4096;
static constexpr int S = 4096;
static constexpr int T = 256;
static constexpr int H = 32;
static constexpr int F = 16384;

__device__ __forceinline__ void gload16(const void* g, void* l) {
  __builtin_amdgcn_global_load_lds((const __attribute__((address_space(1))) void*)g,
                                   (__attribute__((address_space(3))) void*)l, 16, 0, 0);
}

#define MFMA16(a, b, c) __builtin_amdgcn_mfma_f32_16x16x32_bf16((a), (b), (c), 0, 0, 0)

// ---------------- elementwise f32 -> bf16 ----------------
__global__ __launch_bounds__(256) void k_cvt(const float* __restrict__ in, bf16* __restrict__ out, int n) {
  int i = (blockIdx.x * 256 + threadIdx.x) * 4;
  if (i >= n) return;
  float4 v = *(const float4*)(in + i);
  bf16x4 o = { (bf16)v.x, (bf16)v.y, (bf16)v.z, (bf16)v.w };
  *(bf16x4*)(out + i) = o;
}

// ---------------- transpose+cvt: f32 [R][C] (row stride ldin) -> bf16 [C][R], 64x64 tiles --------
__global__ __launch_bounds__(256) void k_tc(const float* __restrict__ in, bf16* __restrict__ out,
                                            int R, int C, int ldin) {
  __shared__ float tile[64][65];
  const int c0 = blockIdx.x * 64, r0 = blockIdx.y * 64;
  const int x = threadIdx.x, y = threadIdx.y;  // block (64,4)
  #pragma unroll
  for (int i = 0; i < 16; i++) {
    const int yy = y + 4 * i;
    tile[yy][x] = in[(size_t)(r0 + yy) * ldin + c0 + x];
  }
  __syncthreads();
  #pragma unroll
  for (int i = 0; i < 16; i++) {
    const int yy = y + 4 * i;
    out[(size_t)(c0 + yy) * R + r0 + x] = (bf16)tile[x][yy];
  }
}

// ---------------- transpose bf16 [R][C] -> [C][R] ----------------
__global__ __launch_bounds__(256) void k_tb(const bf16* __restrict__ in, bf16* __restrict__ out, int R, int C) {
  __shared__ bf16 tile[32][33];
  int c0 = blockIdx.x * 32, r0 = blockIdx.y * 32;
  int x = threadIdx.x, y = threadIdx.y;
  #pragma unroll
  for (int yy = y; yy < 32; yy += 8)
    tile[yy][x] = in[(size_t)(r0 + yy) * C + c0 + x];
  __syncthreads();
  #pragma unroll
  for (int yy = y; yy < 32; yy += 8)
    out[(size_t)(c0 + yy) * R + r0 + x] = tile[x][yy];
}

// ---------------- rmsnorm over 4096, bf16 in -> bf16 out (f32 math) ----------------
__global__ __launch_bounds__(256) void k_rms(const bf16* __restrict__ in, const float* __restrict__ w,
                                             bf16* __restrict__ out) {
  const int row = blockIdx.x, t = threadIdx.x;
  const bf16* x = in + (size_t)row * 4096;
  float xv[16];
  float ss = 0.f;
  #pragma unroll
  for (int i = 0; i < 2; i++) {
    bf16x8 b = *(const bf16x8*)(x + t * 8 + i * 2048);
    #pragma unroll
    for (int j = 0; j < 8; j++) { xv[i * 8 + j] = (float)b[j]; ss += xv[i * 8 + j] * xv[i * 8 + j]; }
  }
  #pragma unroll
  for (int off = 1; off < 64; off <<= 1) ss += __shfl_xor(ss, off, 64);
  __shared__ float red[4];
  if ((t & 63) == 0) red[t >> 6] = ss;
  __syncthreads();
  float rms = rsqrtf((red[0] + red[1] + red[2] + red[3]) * (1.f / 4096.f) + 1e-6f);
  #pragma unroll
  for (int i = 0; i < 2; i++) {
    float4 w0 = *(const float4*)(w + t * 8 + i * 2048);
    float4 w1 = *(const float4*)(w + t * 8 + i * 2048 + 4);
    bf16x8 ov;
    ov[0] = (bf16)(xv[i * 8 + 0] * rms * w0.x); ov[1] = (bf16)(xv[i * 8 + 1] * rms * w0.y);
    ov[2] = (bf16)(xv[i * 8 + 2] * rms * w0.z); ov[3] = (bf16)(xv[i * 8 + 3] * rms * w0.w);
    ov[4] = (bf16)(xv[i * 8 + 4] * rms * w1.x); ov[5] = (bf16)(xv[i * 8 + 5] * rms * w1.y);
    ov[6] = (bf16)(xv[i * 8 + 6] * rms * w1.z); ov[7] = (bf16)(xv[i * 8 + 7] * rms * w1.w);
    *(bf16x8*)(out + (size_t)row * 4096 + t * 8 + i * 2048) = ov;
  }
}

// supertile XCD mapping (bijective): by = (xcd%XGM)*BYG + oidx%BYG ; bx = (xcd/XGM)*BXG + oidx/BYG
__device__ __forceinline__ void xcd_map(int orig, int XGM, int BYG, int BXG, int& by, int& bx) {
  const int xcd = orig & 7, oidx = orig >> 3;
  by = (xcd % XGM) * BYG + oidx % BYG;
  bx = (xcd / XGM) * BXG + oidx / BYG;
}

// ================= 256x256 counted-vmcnt GEMM, tile-loop unrolled x2, split waits ================
// MODE 0: f32 out; 1: bf16 out; 2: f32 = v+res; 3: f32 = v+res AND bf16 dual write
template <int MODE>
__global__ __launch_bounds__(512, 2) void k_gemm2(const bf16* __restrict__ A, const bf16* __restrict__ BT,
                                                  float* __restrict__ Cf, bf16* __restrict__ Cb,
                                                  const float* __restrict__ res,
                                                  int M, int N, int K, int XGM, int BYG, int BXG) {
  __shared__ bf16 LA[2][2][256 * 32];  // [dbuf][kh][row*32+col]
  __shared__ bf16 LB[2][2][256 * 32];
  int by, bx;
  xcd_map(blockIdx.x, XGM, BYG, BXG, by, bx);
  const size_t m0 = (size_t)by * 256, n0 = (size_t)bx * 256;
  const int t = threadIdx.x;
  const int w = t >> 6, lane = t & 63;
  const int wm = w >> 2, wn = w & 3;
  const int g = lane >> 4, r15 = lane & 15;
  const int nt = K >> 6;
  const int sr0 = t >> 2, ss0 = t & 3;
  const int sr1 = (t + 512) >> 2, ss1 = (t + 512) & 3;
  const int sc0 = ((ss0 ^ ((sr0 >> 1) & 3)) << 3);
  const int sc1 = ((ss1 ^ ((sr1 >> 1) & 3)) << 3);
  f32x4 acc[8][4] = {};

  auto stA = [&](int db, int kh, int st) {
    const bf16* src = A + m0 * K + (size_t)st * 64 + kh * 32;
    gload16(src + (size_t)sr0 * K + sc0, &LA[db][kh][t * 8]);
    gload16(src + (size_t)sr1 * K + sc1, &LA[db][kh][(t + 512) * 8]);
  };
  auto stB = [&](int db, int kh, int st) {
    const bf16* src = BT + n0 * K + (size_t)st * 64 + kh * 32;
    gload16(src + (size_t)sr0 * K + sc0, &LB[db][kh][t * 8]);
    gload16(src + (size_t)sr1 * K + sc1, &LB[db][kh][(t + 512) * 8]);
  };

  stA(0, 0, 0); stB(0, 0, 0); stA(0, 1, 0); stB(0, 1, 0);
  stA(1, 0, 1); stB(1, 0, 1); stA(1, 1, 1);
  asm volatile("s_waitcnt vmcnt(10)" ::: "memory");
  __builtin_amdgcn_s_barrier();

  const int arow = wm * 128;

#define GEMM_TILE(DD, TC)                                                                     \
  {                                                                                           \
    const int t1 = ((TC) + 1 < nt) ? (TC) + 1 : nt - 1;                                       \
    const int t2 = ((TC) + 2 < nt) ? (TC) + 2 : nt - 1;                                       \
    bf16x8 af[8], b0, b1;                                                                     \
    stB((DD) ^ 1, 1, t1);                                                                     \
    _Pragma("unroll")                                                                         \
    for (int mf = 0; mf < 8; ++mf) {                                                          \
      const int rr = arow + mf * 16 + r15;                                                    \
      af[mf] = *(const bf16x8*)&LA[DD][0][rr * 32 + ((g ^ ((rr >> 1) & 3)) << 3)];            \
    }                                                                                         \
    {                                                                                         \
      const int rb0 = wn * 64 + r15, rb1 = wn * 64 + 16 + r15;                                \
      b0 = *(const bf16x8*)&LB[DD][0][rb0 * 32 + ((g ^ ((rb0 >> 1) & 3)) << 3)];              \
      b1 = *(const bf16x8*)&LB[DD][0][rb1 * 32 + ((g ^ ((rb1 >> 1) & 3)) << 3)];              \
    }                                                                                         \
    __builtin_amdgcn_s_barrier();                                                             \
    __builtin_amdgcn_s_setprio(1);                                                            \
    _Pragma("unroll")                                                                         \
    for (int mf = 0; mf < 8; ++mf) {                                                          \
      acc[mf][0] = MFMA16(af[mf], b0, acc[mf][0]);                                            \
      acc[mf][1] = MFMA16(af[mf], b1, acc[mf][1]);                                            \
    }                                                                                         \
    __builtin_amdgcn_s_setprio(0);                                                            \
    stA(DD, 0, t2);                                                                           \
    {                                                                                         \
      const int rb0 = wn * 64 + 32 + r15, rb1 = wn * 64 + 48 + r15;                           \
      b0 = *(const bf16x8*)&LB[DD][0][rb0 * 32 + ((g ^ ((rb0 >> 1) & 3)) << 3)];              \
      b1 = *(const bf16x8*)&LB[DD][0][rb1 * 32 + ((g ^ ((rb1 >> 1) & 3)) << 3)];              \
    }                                                                                         \
    asm volatile("s_waitcnt vmcnt(10)" ::: "memory");                                         \
    __builtin_amdgcn_s_barrier();                                                             \
    __builtin_amdgcn_s_setprio(1);                                                            \
    _Pragma("unroll")                                                                         \
    for (int mf = 0; mf < 8; ++mf) {                                                          \
      acc[mf][2] = MFMA16(af[mf], b0, acc[mf][2]);                                            \
      acc[mf][3] = MFMA16(af[mf], b1, acc[mf][3]);                                            \
    }                                                                                         \
    __builtin_amdgcn_s_setprio(0);                                                            \
    stB(DD, 0, t2);                                                                           \
    _Pragma("unroll")                                                                         \
    for (int mf = 0; mf < 8; ++mf) {                                                          \
      const int rr = arow + mf * 16 + r15;                                                    \
      af[mf] = *(const bf16x8*)&LA[DD][1][rr * 32 + ((g ^ ((rr >> 1) & 3)) << 3)];            \
    }                                                                                         \
    {                                                                                         \
      const int rb0 = wn * 64 + r15, rb1 = wn * 64 + 16 + r15;                                \
      b0 = *(const bf16x8*)&LB[DD][1][rb0 * 32 + ((g ^ ((rb0 >> 1) & 3)) << 3)];              \
      b1 = *(const bf16x8*)&LB[DD][1][rb1 * 32 + ((g ^ ((rb1 >> 1) & 3)) << 3)];              \
    }                                                                                         \
    __builtin_amdgcn_s_barrier();                                                             \
    __builtin_amdgcn_s_setprio(1);                                                            \
    _Pragma("unroll")                                                                         \
    for (int mf = 0; mf < 8; ++mf) {                                                          \
      acc[mf][0] = MFMA16(af[mf], b0, acc[mf][0]);                                            \
      acc[mf][1] = MFMA16(af[mf], b1, acc[mf][1]);                                            \
    }                                                                                         \
    __builtin_amdgcn_s_setprio(0);                                                            \
    stA(DD, 1, t2);                                                                           \
    {                                                                                         \
      const int rb0 = wn * 64 + 32 + r15, rb1 = wn * 64 + 48 + r15;                           \
      b0 = *(const bf16x8*)&LB[DD][1][rb0 * 32 + ((g ^ ((rb0 >> 1) & 3)) << 3)];              \
      b1 = *(const bf16x8*)&LB[DD][1][rb1 * 32 + ((g ^ ((rb1 >> 1) & 3)) << 3)];              \
    }                                                                                         \
    asm volatile("s_waitcnt vmcnt(10)" ::: "memory");                                         \
    __builtin_amdgcn_s_barrier();                                                             \
    __builtin_amdgcn_s_setprio(1);                                                            \
    _Pragma("unroll")                                                                         \
    for (int mf = 0; mf < 8; ++mf) {                                                          \
      acc[mf][2] = MFMA16(af[mf], b0, acc[mf][2]);                                            \
      acc[mf][3] = MFMA16(af[mf], b1, acc[mf][3]);                                            \
    }                                                                                         \
    __builtin_amdgcn_s_setprio(0);                                                            \
  }

  for (int tt = 0; tt < nt; tt += 2) {
    GEMM_TILE(0, tt);
    GEMM_TILE(1, tt + 1);
  }
#undef GEMM_TILE

  #pragma unroll
  for (int mf = 0; mf < 8; ++mf)
    #pragma unroll
    for (int nf = 0; nf < 4; ++nf) {
      const size_t col = n0 + wn * 64 + nf * 16 + r15;
      #pragma unroll
      for (int rr = 0; rr < 4; ++rr) {
        const size_t row = m0 + wm * 128 + mf * 16 + g * 4 + rr;
        const size_t idx = row * (size_t)N + col;
        const float v = acc[mf][nf][rr];
        if (MODE == 0) Cf[idx] = v;
        else if (MODE == 1) Cb[idx] = (bf16)v;
        else if (MODE == 2) Cf[idx] = v + res[idx];
        else { const float s = v + res[idx]; Cf[idx] = s; Cb[idx] = (bf16)s; }
      }
    }
}

// ================= fused GEGLU GEMM: G[M,N] = (A@BTv) * gelu(A@BTg), tile 256x128 ================
__global__ __launch_bounds__(512, 2) void k_geglu2(const bf16* __restrict__ A, const bf16* __restrict__ BT,
                                                   bf16* __restrict__ G, int N, int K,
                                                   int XGM, int BYG, int BXG) {
  __shared__ bf16 LA[2][2][256 * 32];
  __shared__ bf16 LBv[2][2][128 * 32];
  __shared__ bf16 LBg[2][2][128 * 32];
  int by, bx;
  xcd_map(blockIdx.x, XGM, BYG, BXG, by, bx);
  const size_t m0 = (size_t)by * 256, n0 = (size_t)bx * 128;
  const int t = threadIdx.x;
  const int w = t >> 6, lane = t & 63;
  const int wm = w >> 2, wn = w & 3;
  const int g = lane >> 4, r15 = lane & 15;
  const int nt = K >> 6;
  const int sr0 = t >> 2, ss0 = t & 3;
  const int sr1 = (t + 512) >> 2, ss1 = (t + 512) & 3;
  const int sc0 = ((ss0 ^ ((sr0 >> 1) & 3)) << 3);
  const int sc1 = ((ss1 ^ ((sr1 >> 1) & 3)) << 3);
  f32x4 av[8][2] = {}, ag[8][2] = {};

  auto stA = [&](int db, int kh, int st) {
    const bf16* src = A + m0 * K + (size_t)st * 64 + kh * 32;
    gload16(src + (size_t)sr0 * K + sc0, &LA[db][kh][t * 8]);
    gload16(src + (size_t)sr1 * K + sc1, &LA[db][kh][(t + 512) * 8]);
  };
  auto stBv = [&](int db, int kh, int st) {
    const bf16* src = BT + n0 * K + (size_t)st * 64 + kh * 32;
    gload16(src + (size_t)sr0 * K + sc0, &LBv[db][kh][t * 8]);
  };
  auto stBg = [&](int db, int kh, int st) {
    const bf16* src = BT + ((size_t)N + n0) * K + (size_t)st * 64 + kh * 32;
    gload16(src + (size_t)sr0 * K + sc0, &LBg[db][kh][t * 8]);
  };

  stA(0, 0, 0); stBv(0, 0, 0); stBg(0, 0, 0); stA(0, 1, 0); stBv(0, 1, 0); stBg(0, 1, 0);
  stA(1, 0, 1); stBv(1, 0, 1); stBg(1, 0, 1); stA(1, 1, 1);
  asm volatile("s_waitcnt vmcnt(10)" ::: "memory");
  __builtin_amdgcn_s_barrier();

  const int arow = wm * 128;

#define GEGLU_TILE(DD, TC)                                                                    \
  {                                                                                           \
    const int t1 = ((TC) + 1 < nt) ? (TC) + 1 : nt - 1;                                       \
    const int t2 = ((TC) + 2 < nt) ? (TC) + 2 : nt - 1;                                       \
    bf16x8 af[8], b0, b1;                                                                     \
    stBv((DD) ^ 1, 1, t1); stBg((DD) ^ 1, 1, t1);                                             \
    _Pragma("unroll")                                                                         \
    for (int mf = 0; mf < 8; ++mf) {                                                          \
      const int rr = arow + mf * 16 + r15;                                                    \
      af[mf] = *(const bf16x8*)&LA[DD][0][rr * 32 + ((g ^ ((rr >> 1) & 3)) << 3)];            \
    }                                                                                         \
    {                                                                                         \
      const int rb0 = wn * 32 + r15, rb1 = wn * 32 + 16 + r15;                                \
      b0 = *(const bf16x8*)&LBv[DD][0][rb0 * 32 + ((g ^ ((rb0 >> 1) & 3)) << 3)];             \
      b1 = *(const bf16x8*)&LBv[DD][0][rb1 * 32 + ((g ^ ((rb1 >> 1) & 3)) << 3)];             \
    }                                                                                         \
    __builtin_amdgcn_s_barrier();                                                             \
    __builtin_amdgcn_s_setprio(1);                                                            \
    _Pragma("unroll")                                                                         \
    for (int mf = 0; mf < 8; ++mf) {                                                          \
      av[mf][0] = MFMA16(af[mf], b0, av[mf][0]);                                              \
      av[mf][1] = MFMA16(af[mf], b1, av[mf][1]);                                              \
    }                                                                                         \
    __builtin_amdgcn_s_setprio(0);                                                            \
    stA(DD, 0, t2);                                                                           \
    {                                                                                         \
      const int rb0 = wn * 32 + r15, rb1 = wn * 32 + 16 + r15;                                \
      b0 = *(const bf16x8*)&LBg[DD][0][rb0 * 32 + ((g ^ ((rb0 >> 1) & 3)) << 3)];             \
      b1 = *(const bf16x8*)&LBg[DD][0][rb1 * 32 + ((g ^ ((rb1 >> 1) & 3)) << 3)];             \
    }                                                                                         \
    asm volatile("s_waitcnt vmcnt(10)" ::: "memory");                                         \
    __builtin_amdgcn_s_barrier();                                                             \
    __builtin_amdgcn_s_setprio(1);                                                            \
    _Pragma("unroll")                                                                         \
    for (int mf = 0; mf < 8; ++mf) {                                                          \
      ag[mf][0] = MFMA16(af[mf], b0, ag[mf][0]);                                              \
      ag[mf][1] = MFMA16(af[mf], b1, ag[mf][1]);                                              \
    }                                                                                         \
    __builtin_amdgcn_s_setprio(0);                                                            \
    stBv(DD, 0, t2); stBg(DD, 0, t2);                                                         \
    _Pragma("unroll")                                                                         \
    for (int mf = 0; mf < 8; ++mf) {                                                          \
      const int rr = arow + mf * 16 + r15;                                                    \
      af[mf] = *(const bf16x8*)&LA[DD][1][rr * 32 + ((g ^ ((rr >> 1) & 3)) << 3)];            \
    }                                                                                         \
    {                                                                                         \
      const int rb0 = wn * 32 + r15, rb1 = wn * 32 + 16 + r15;                                \
      b0 = *(const bf16x8*)&LBv[DD][1][rb0 * 32 + ((g ^ ((rb0 >> 1) & 3)) << 3)];             \
      b1 = *(const bf16x8*)&LBv[DD][1][rb1 * 32 + ((g ^ ((rb1 >> 1) & 3)) << 3)];             \
    }                                                                                         \
    __builtin_amdgcn_s_barrier();                                                             \
    __builtin_amdgcn_s_setprio(1);                                                            \
    _Pragma("unroll")                                                                         \
    for (int mf = 0; mf < 8; ++mf) {                                                          \
      av[mf][0] = MFMA16(af[mf], b0, av[mf][0]);                                              \
      av[mf][1] = MFMA16(af[mf], b1, av[mf][1]);                                              \
    }                                                                                         \
    __builtin_amdgcn_s_setprio(0);                                                            \
    stA(DD, 1, t2);                                                                           \
    {                                                                                         \
      const int rb0 = wn * 32 + r15, rb1 = wn * 32 + 16 + r15;                                \
      b0 = *(const bf16x8*)&LBg[DD][1][rb0 * 32 + ((g ^ ((rb0 >> 1) & 3)) << 3)];             \
      b1 = *(const bf16x8*)&LBg[DD][1][rb1 * 32 + ((g ^ ((rb1 >> 1) & 3)) << 3)];             \
    }                                                                                         \
    asm volatile("s_waitcnt vmcnt(10)" ::: "memory");                                         \
    __builtin_amdgcn_s_barrier();                                                             \
    __builtin_amdgcn_s_setprio(1);                                                            \
    _Pragma("unroll")                                                                         \
    for (int mf = 0; mf < 8; ++mf) {                                                          \
      ag[mf][0] = MFMA16(af[mf], b0, ag[mf][0]);                                              \
      ag[mf][1] = MFMA16(af[mf], b1, ag[mf][1]);                                              \
    }                                                                                         \
    __builtin_amdgcn_s_setprio(0);                                                            \
  }

  for (int tt = 0; tt < nt; tt += 2) {
    GEGLU_TILE(0, tt);
    GEGLU_TILE(1, tt + 1);
  }
#undef GEGLU_TILE

  #pragma unroll
  for (int mf = 0; mf < 8; ++mf)
    #pragma unroll
    for (int nf = 0; nf < 2; ++nf) {
      const size_t col = n0 + wn * 32 + nf * 16 + r15;
      #pragma unroll
      for (int rr = 0; rr < 4; ++rr) {
        const size_t row = m0 + wm * 128 + mf * 16 + g * 4 + rr;
        const float val = av[mf][nf][rr], gt = ag[mf][nf][rr];
        const float z = 1.595769122f * gt + 0.0713548162f * gt * gt * gt;
        const float gel = gt / (1.f + __expf(-z));
        G[row * (size_t)N + col] = (bf16)(val * gel);
      }
    }
}

// ---------------- 128x128 GEMM (m97 structure) for M=256 cases ----------------
template <int MODE>
__global__ __launch_bounds__(256) void k_gemm128(const bf16* __restrict__ A, const bf16* __restrict__ BT,
                                                 float* __restrict__ Cf, bf16* __restrict__ Cb,
                                                 int M, int N, int K) {
  __shared__ bf16 As[128 * 32];
  __shared__ bf16 Bs[128 * 32];
  const int t = threadIdx.x;
  const int lane = t & 63, w = t >> 6;
  const int wr = w >> 1, wc = w & 1;
  const int g = lane >> 4, r15 = lane & 15;
  const size_t m0 = (size_t)blockIdx.y * 128, n0 = (size_t)blockIdx.x * 128;
  f32x4 acc[4][4] = {};
  const int c0 = t, c1 = t + 256;
  const int ar0 = c0 >> 2, as0 = c0 & 3, ar1 = c1 >> 2, as1 = c1 & 3;
  const bf16* Ab = A + m0 * K;
  const bf16* Bb = BT + n0 * K;
  for (int k0 = 0; k0 < K; k0 += 32) {
    __syncthreads();
    gload16(Ab + (size_t)ar0 * K + k0 + ((as0 ^ (ar0 & 3)) << 3), &As[c0 * 8]);
    gload16(Ab + (size_t)ar1 * K + k0 + ((as1 ^ (ar1 & 3)) << 3), &As[c1 * 8]);
    gload16(Bb + (size_t)ar0 * K + k0 + ((as0 ^ (ar0 & 3)) << 3), &Bs[c0 * 8]);
    gload16(Bb + (size_t)ar1 * K + k0 + ((as1 ^ (ar1 & 3)) << 3), &Bs[c1 * 8]);
    __syncthreads();
    bf16x8 af[4], bfr[4];
    #pragma unroll
    for (int mi = 0; mi < 4; mi++) {
      int row = wr * 64 + mi * 16 + r15;
      af[mi] = *(const bf16x8*)&As[row * 32 + ((g ^ (row & 3)) << 3)];
    }
    #pragma unroll
    for (int ni = 0; ni < 4; ni++) {
      int row = wc * 64 + ni * 16 + r15;
      bfr[ni] = *(const bf16x8*)&Bs[row * 32 + ((g ^ (row & 3)) << 3)];
    }
    #pragma unroll
    for (int mi = 0; mi < 4; mi++)
      #pragma unroll
      for (int ni = 0; ni < 4; ni++)
        acc[mi][ni] = MFMA16(af[mi], bfr[ni], acc[mi][ni]);
  }
  #pragma unroll
  for (int mi = 0; mi < 4; mi++)
    #pragma unroll
    for (int ni = 0; ni < 4; ni++) {
      size_t col = n0 + wc * 64 + ni * 16 + r15;
      #pragma unroll
      for (int rr = 0; rr < 4; rr++) {
        size_t row = m0 + wr * 64 + mi * 16 + g * 4 + rr;
        size_t idx = row * (size_t)N + col;
        float v = acc[mi][ni][rr];
        if (MODE == 0) Cf[idx] = v;
        else Cb[idx] = (bf16)v;
      }
    }
}

// ---------------- flash attention: Q[S,D] x K[Skv,D] x VT[D,Skv] -> O[S,D], KVBLK=64 -------------
// grid (S/64, H), 4 waves x 16 q-rows. K/V staged 16KB each, Pt 2KB/wave; 40KB LDS -> 4 blocks/CU.
__global__ __launch_bounds__(256) void k_attn(const bf16* __restrict__ Q, const bf16* __restrict__ Kb,
                                              const bf16* __restrict__ VT, bf16* __restrict__ O,
                                              int Skv) {
  __shared__ bf16 Kt[64 * 128];   // [key][d], 16 slots/row, slot ^= (key&15)
  __shared__ bf16 Vt[128 * 64];   // [d][key], 8 slots/row, slot ^= (d&7)
  __shared__ bf16 Pt[4][16 * 64]; // per-wave P, 8 slots/row, slot ^= (q&7)
  const int h = blockIdx.y;
  const int t = threadIdx.x, w = t >> 6, lane = t & 63;
  const int g = lane >> 4, r15 = lane & 15;
  const int q0 = blockIdx.x * 64 + w * 16;
  bf16x8 qf[4];
  #pragma unroll
  for (int c = 0; c < 4; c++)
    qf[c] = *(const bf16x8*)(Q + (size_t)(q0 + r15) * D + h * 128 + c * 32 + g * 8);
  f32x4 o[8] = {};
  float m_[4] = { -1e30f, -1e30f, -1e30f, -1e30f };
  float l_[4] = { 0.f, 0.f, 0.f, 0.f };
  const float scale = 0.08838834764831845f;
  for (int kt = 0; kt < Skv; kt += 64) {
    __syncthreads();
    #pragma unroll
    for (int cc = 0; cc < 4; cc++) {
      int c = t + cc * 256;
      int kr = c >> 4, ks = c & 15;
      gload16(Kb + (size_t)(kt + kr) * D + h * 128 + ((ks ^ (kr & 15)) << 3), &Kt[c * 8]);
      int vr = c >> 3, vs = c & 7;
      gload16(VT + (size_t)(h * 128 + vr) * Skv + kt + ((vs ^ (vr & 7)) << 3), &Vt[c * 8]);
    }
    __syncthreads();
    f32x4 s[4] = {};
    __builtin_amdgcn_s_setprio(1);
    #pragma unroll
    for (int c = 0; c < 4; c++) {
      #pragma unroll
      for (int j = 0; j < 4; j++) {
        const int row = j * 16 + r15;
        bf16x8 kf = *(const bf16x8*)&Kt[row * 128 + (((4 * c + g) ^ (row & 15)) << 3)];
        s[j] = MFMA16(qf[c], kf, s[j]);
      }
    }
    __builtin_amdgcn_s_setprio(0);
    float al[4];
    #pragma unroll
    for (int rr = 0; rr < 4; rr++) {
      float v0 = s[0][rr] * scale, v1 = s[1][rr] * scale;
      float v2 = s[2][rr] * scale, v3 = s[3][rr] * scale;
      float mx = fmaxf(fmaxf(v0, v1), fmaxf(v2, v3));
      #pragma unroll
      for (int off = 1; off < 16; off <<= 1) mx = fmaxf(mx, __shfl_xor(mx, off, 16));
      float mn = fmaxf(m_[rr], mx);
      al[rr] = __expf(m_[rr] - mn);
      float p0 = __expf(v0 - mn), p1 = __expf(v1 - mn);
      float p2 = __expf(v2 - mn), p3 = __expf(v3 - mn);
      float sm = p0 + p1 + p2 + p3;
      #pragma unroll
      for (int off = 1; off < 16; off <<= 1) sm += __shfl_xor(sm, off, 16);
      l_[rr] = l_[rr] * al[rr] + sm;
      m_[rr] = mn;
      const int prow = g * 4 + rr;
      const int sbase = prow * 64, sx = prow & 7, e = r15 & 7, hi = r15 >> 3;
      Pt[w][sbase + (((0 + hi) ^ sx) << 3) + e] = (bf16)p0;
      Pt[w][sbase + (((2 + hi) ^ sx) << 3) + e] = (bf16)p1;
      Pt[w][sbase + (((4 + hi) ^ sx) << 3) + e] = (bf16)p2;
      Pt[w][sbase + (((6 + hi) ^ sx) << 3) + e] = (bf16)p3;
    }
    #pragma unroll
    for (int d = 0; d < 8; d++)
      #pragma unroll
      for (int rr = 0; rr < 4; rr++) o[d][rr] *= al[rr];
    bf16x8 pa[2];
    #pragma unroll
    for (int kk = 0; kk < 2; kk++)
      pa[kk] = *(const bf16x8*)&Pt[w][r15 * 64 + (((kk * 4 + g) ^ (r15 & 7)) << 3)];
    __builtin_amdgcn_s_setprio(1);
    #pragma unroll
    for (int d = 0; d < 8; d++) {
      const int vrow = d * 16 + r15;
      #pragma unroll
      for (int kk = 0; kk < 2; kk++) {
        bf16x8 vbf = *(const bf16x8*)&Vt[vrow * 64 + (((kk * 4 + g) ^ (vrow & 7)) << 3)];
        o[d] = MFMA16(pa[kk], vbf, o[d]);
      }
    }
    __builtin_amdgcn_s_setprio(0);
  }
  #pragma unroll
  for (int rr = 0; rr < 4; rr++) {
    float inv = 1.f / l_[rr];
    #pragma unroll
    for (int d = 0; d < 8; d++)
      O[(size_t)(q0 + g * 4 + rr) * D + h * 128 + d * 16 + r15] = (bf16)(o[d][rr] * inv);
  }
}

extern "C" void kernel_launch(void* const* d_in, const int* in_sizes, int n_in,
                              void* d_out, int out_size, void* d_ws, size_t ws_size,
                              hipStream_t stream) {
  (void)in_sizes; (void)n_in; (void)out_size; (void)ws_size;
  const float* video = (const float*)d_in[0];
  const float* text  = (const float*)d_in[1];
  const float* wq    = (const float*)d_in[2];
  const float* wk    = (const float*)d_in[3];
  const float* wv    = (const float*)d_in[4];
  const float* wo    = (const float*)d_in[5];
  const float* qnw   = (const float*)d_in[6];
  const float* knw   = (const float*)d_in[7];
  const float* cwq   = (const float*)d_in[8];
  const float* cwk   = (const float*)d_in[9];
  const float* cwv   = (const float*)d_in[10];
  const float* cwo   = (const float*)d_in[11];
  const float* cqnw  = (const float*)d_in[12];
  const float* cknw  = (const float*)d_in[13];
  const float* ffp   = (const float*)d_in[14];
  const float* ffd   = (const float*)d_in[15];
  float* out = (float*)d_out;

  char* slab = (char*)d_ws;
  const size_t MB = 1024 * 1024;
  bf16*  wbuf  = (bf16*)slab;
  bf16*  vb    = (bf16*)(slab + 64 * MB);
  bf16*  vt    = (bf16*)(slab + 96 * MB);
  bf16*  preb  = (bf16*)(slab + 128 * MB);
  bf16*  Hval  = (bf16*)(slab + 268 * MB);
  char* p = slab + 402 * MB;
  auto take = [&](size_t bytes) { char* r = p; p += (bytes + 255) & ~(size_t)255; return r; };
  bf16* xb   = (bf16*)take((size_t)S * D * 2);
  bf16* qb   = (bf16*)take((size_t)S * D * 2);
  bf16* kb   = (bf16*)take((size_t)S * D * 2);
  bf16* ab   = (bf16*)take((size_t)S * D * 2);
  float* h1  = (float*)take((size_t)S * D * 4);
  bf16* tbuf = (bf16*)take((size_t)T * D * 2);
  bf16* ckb  = (bf16*)take((size_t)T * D * 2);
  bf16* cvb  = (bf16*)take((size_t)T * D * 2);
  bf16* cvt_ = (bf16*)take((size_t)T * D * 2);
  float* h2  = out;

  dim3 b256(256), b512(512), btc(64, 4), btb(32, 8);
  const int GRID_DD = 256, GRID_GG = 2048;

  // ---- self-attention ----
  k_cvt<<<(S * D) / 1024, b256, 0, stream>>>(video, xb, S * D);
  k_tc<<<dim3(D / 64, D / 64), btc, 0, stream>>>(wq, wbuf, D, D, D);
  k_gemm2<1><<<GRID_DD, b512, 0, stream>>>(xb, wbuf, nullptr, preb, nullptr, S, D, D, 2, 8, 4);
  k_rms<<<S, b256, 0, stream>>>(preb, qnw, qb);
  k_tc<<<dim3(D / 64, D / 64), btc, 0, stream>>>(wk, wbuf, D, D, D);
  k_gemm2<1><<<GRID_DD, b512, 0, stream>>>(xb, wbuf, nullptr, preb, nullptr, S, D, D, 2, 8, 4);
  k_rms<<<S, b256, 0, stream>>>(preb, knw, kb);
  k_tc<<<dim3(D / 64, D / 64), btc, 0, stream>>>(wv, wbuf, D, D, D);
  k_gemm2<1><<<GRID_DD, b512, 0, stream>>>(xb, wbuf, nullptr, vb, nullptr, S, D, D, 2, 8, 4);
  k_tb<<<dim3(D / 32, S / 32), btb, 0, stream>>>(vb, vt, S, D);
  k_attn<<<dim3(S / 64, H), b256, 0, stream>>>(qb, kb, vt, ab, S);
  k_tc<<<dim3(D / 64, D / 64), btc, 0, stream>>>(wo, wbuf, D, D, D);
  k_gemm2<3><<<GRID_DD, b512, 0, stream>>>(ab, wbuf, h1, xb, video, S, D, D, 2, 8, 4);

  // ---- cross-attention ----
  k_tc<<<dim3(D / 64, D / 64), btc, 0, stream>>>(cwq, wbuf, D, D, D);
  k_gemm2<1><<<GRID_DD, b512, 0, stream>>>(xb, wbuf, nullptr, preb, nullptr, S, D, D, 2, 8, 4);
  k_rms<<<S, b256, 0, stream>>>(preb, cqnw, qb);
  k_cvt<<<(T * D) / 1024, b256, 0, stream>>>(text, tbuf, T * D);
  k_tc<<<dim3(D / 64, D / 64), btc, 0, stream>>>(cwk, wbuf, D, D, D);
  k_gemm128<1><<<dim3(D / 128, T / 128), b256, 0, stream>>>(tbuf, wbuf, nullptr, preb, T, D, D);
  k_rms<<<T, b256, 0, stream>>>(preb, cknw, ckb);
  k_tc<<<dim3(D / 64, D / 64), btc, 0, stream>>>(cwv, wbuf, D, D, D);
  k_gemm128<1><<<dim3(D / 128, T / 128), b256, 0, stream>>>(tbuf, wbuf, nullptr, cvb, T, D, D);
  k_tb<<<dim3(D / 32, T / 32), btb, 0, stream>>>(cvb, cvt_, T, D);
  k_attn<<<dim3(S / 64, H), b256, 0, stream>>>(qb, ckb, cvt_, ab, T);
  k_tc<<<dim3(D / 64, D / 64), btc, 0, stream>>>(cwo, wbuf, D, D, D);
  k_gemm2<3><<<GRID_DD, b512, 0, stream>>>(ab, wbuf, h2, xb, h1, S, D, D, 2, 8, 4);

  // ---- GEGLU FFN (fused val+gate) ----
  k_tc<<<dim3((2 * F) / 64, D / 64), btc, 0, stream>>>(ffp, wbuf, D, 2 * F, 2 * F);
  k_geglu2<<<GRID_GG, b512, 0, stream>>>(xb, wbuf, Hval, F, D, 2, 8, 32);
  k_tc<<<dim3(D / 64, F / 64), btc, 0, stream>>>(ffd, wbuf, F, D, D);
  k_gemm2<2><<<GRID_DD, b512, 0, stream>>>(Hval, wbuf, out, nullptr, h2, S, D, F, 2, 8, 4);
}